// Round 7
// baseline (2380.408 us; speedup 1.0000x reference)
//
#include <hip/hip_runtime.h>
#include <hip/hip_bf16.h>

#define B_ 256
#define T_ 200
#define D_ 256
#define H_ 4
#define BT_ (B_*T_)
#define DD_ (D_*D_)
#define GS_ 72     // gemm LDS stride (64 + 8 pad)
#define TP_ 208    // padded token rows per batch for qbf/kbf
#define VTP_ 224   // vtbf row length (7*32)

typedef __attribute__((ext_vector_type(4))) float  f32x4;
typedef __attribute__((ext_vector_type(8))) __bf16 bf16x8;
typedef __attribute__((ext_vector_type(4))) int    i32x4;

union frag8 { unsigned u[4]; bf16x8 v; };

__device__ __forceinline__ unsigned short f2bf(float f) {
    unsigned u = __float_as_uint(f);
    u += 0x7FFFu + ((u >> 16) & 1u);          // RNE to bf16
    return (unsigned short)(u >> 16);
}
__device__ __forceinline__ unsigned pk2(float lo, float hi) {
    return (unsigned)f2bf(lo) | ((unsigned)f2bf(hi) << 16);
}

__device__ __forceinline__ float wave_sum(float v) {
#pragma unroll
    for (int o = 32; o >= 1; o >>= 1) v += __shfl_xor(v, o);
    return v;
}

// ---------------- embed ----------------
__global__ void embed_kernel(const int* __restrict__ ls,
                             const float* __restrict__ itab,
                             const float* __restrict__ ptab,
                             float* __restrict__ seqs) {
    int bt = blockIdx.x;
    int t = bt % T_;
    int lane = threadIdx.x;
    int idx = ls[bt];
    int pos = idx ? (t + 1) : 0;
    float4 a = ((const float4*)(itab + (size_t)idx * D_))[lane];
    float4 p = ((const float4*)(ptab + (size_t)pos * D_))[lane];
    float4 r = { a.x*16.f+p.x, a.y*16.f+p.y, a.z*16.f+p.z, a.w*16.f+p.w };
    ((float4*)(seqs + (size_t)bt * D_))[lane] = r;
}

// ---------------- layernorm (4 rows / 256-thread block) ----------------
__global__ __launch_bounds__(256) void ln_kernel(const float* __restrict__ X,
                                                 const float* __restrict__ sc,
                                                 const float* __restrict__ bi,
                                                 float* __restrict__ Y) {
    int row = blockIdx.x * 4 + (threadIdx.x >> 6);
    int lane = threadIdx.x & 63;
    float4 x = ((const float4*)(X + (size_t)row * D_))[lane];
    float m = wave_sum(x.x + x.y + x.z + x.w) * (1.f / D_);
    float d0 = x.x - m, d1 = x.y - m, d2 = x.z - m, d3 = x.w - m;
    float v = wave_sum(d0*d0 + d1*d1 + d2*d2 + d3*d3) * (1.f / D_);
    float inv = rsqrtf(v + 1e-8f);
    float4 s4 = ((const float4*)sc)[lane];
    float4 b4 = ((const float4*)bi)[lane];
    float4 r = { d0*inv*s4.x + b4.x, d1*inv*s4.y + b4.y,
                 d2*inv*s4.z + b4.z, d3*inv*s4.w + b4.w };
    ((float4*)(Y + (size_t)row * D_))[lane] = r;
}

// ---------------- weight transpose: Wt[n][k] = bf16(W[k][n]) ----------------
__global__ __launch_bounds__(256) void wtrans_kernel(const float* __restrict__ W,
                                                     unsigned short* __restrict__ Wt) {
    __shared__ float tile[64][65];
    int c0 = blockIdx.x * 64, r0 = blockIdx.y * 64, l = blockIdx.z;
    const float* src = W + (size_t)l * DD_;
    unsigned short* dst = Wt + (size_t)l * DD_;
    int tid = threadIdx.x;
#pragma unroll
    for (int rep = 0; rep < 16; ++rep) {
        int idx = rep * 256 + tid;
        int r = idx >> 6, c = idx & 63;
        tile[r][c] = src[(size_t)(r0 + r) * D_ + c0 + c];
    }
    __syncthreads();
#pragma unroll
    for (int rep = 0; rep < 16; ++rep) {
        int idx = rep * 256 + tid;
        int r2 = idx >> 6, c2 = idx & 63;
        dst[(size_t)(c0 + r2) * D_ + r0 + c2] = f2bf(tile[c2][r2]);
    }
}

// zero vtbf pad cols [200,224) once per launch (NaN x 0 guard)
__global__ void vtpad_kernel(unsigned short* __restrict__ vt) {
    if (threadIdx.x < VTP_ - T_)
        vt[(size_t)blockIdx.x * VTP_ + T_ + threadIdx.x] = 0;
}

// ---------------- MFMA GEMM ----------------
// C[M,256] = A[M,256] @ W + bias (+res)(relu); Wt bf16 [n][k] pre-transposed.
// AM: 0 = A fp32, 1 = A bf16 flat.
// OM: 0 = C fp32 [m][256]; 1 = bf16 row-padded [b][208][256]; 2 = bf16 V^T [g][64][224].
template<int AM, int OM, bool RELU, bool RES>
__global__ __launch_bounds__(256) void gemm_mfma(
    const void* __restrict__ Ap, const unsigned short* __restrict__ Wt,
    const float* __restrict__ bias, const float* res, void* Cout) {
    __shared__ unsigned short As[128 * GS_];
    __shared__ unsigned short Ws[128 * GS_];
    int t = threadIdx.x, lane = t & 63, wv = t >> 6;
    int wm = wv >> 1, wn = wv & 1;
    int l15 = lane & 15, l4 = lane >> 4;
    int m0 = blockIdx.y * 128, n0 = blockIdx.x * 128;

    f32x4 acc[4][4];
#pragma unroll
    for (int m = 0; m < 4; ++m)
#pragma unroll
        for (int n = 0; n < 4; ++n)
            acc[m][n] = f32x4{0.f, 0.f, 0.f, 0.f};

    for (int k0 = 0; k0 < D_; k0 += 64) {
        if (AM == 0) {
            const float* A = (const float*)Ap;
#pragma unroll
            for (int rep = 0; rep < 8; ++rep) {
                int idx = rep * 256 + t;
                int r = idx >> 4, c4 = (idx & 15) * 4;
                float4 a = *(const float4*)(A + (size_t)(m0 + r) * D_ + k0 + c4);
                unsigned* p = (unsigned*)&As[r * GS_ + c4];
                p[0] = pk2(a.x, a.y);
                p[1] = pk2(a.z, a.w);
            }
        } else {
            const unsigned short* A = (const unsigned short*)Ap;
#pragma unroll
            for (int rep = 0; rep < 4; ++rep) {
                int idx = rep * 256 + t;
                int r = idx >> 3, c8 = (idx & 7) * 8;
                *(i32x4*)&As[r * GS_ + c8] =
                    *(const i32x4*)(A + (size_t)(m0 + r) * D_ + k0 + c8);
            }
        }
#pragma unroll
        for (int rep = 0; rep < 4; ++rep) {
            int idx = rep * 256 + t;
            int r = idx >> 3, c8 = (idx & 7) * 8;
            *(i32x4*)&Ws[r * GS_ + c8] =
                *(const i32x4*)(Wt + (size_t)(n0 + r) * D_ + k0 + c8);
        }
        __syncthreads();
#pragma unroll
        for (int kk = 0; kk < 2; ++kk) {
            bf16x8 af[4], bf[4];
#pragma unroll
            for (int m = 0; m < 4; ++m)
                af[m] = *(const bf16x8*)&As[(wm*64 + m*16 + l15) * GS_ + kk*32 + l4*8];
#pragma unroll
            for (int n = 0; n < 4; ++n)
                bf[n] = *(const bf16x8*)&Ws[(wn*64 + n*16 + l15) * GS_ + kk*32 + l4*8];
#pragma unroll
            for (int m = 0; m < 4; ++m)
#pragma unroll
                for (int n = 0; n < 4; ++n)
                    acc[m][n] = __builtin_amdgcn_mfma_f32_16x16x32_bf16(af[m], bf[n], acc[m][n], 0, 0, 0);
        }
        __syncthreads();
    }
#pragma unroll
    for (int n = 0; n < 4; ++n) {
        int gn = n0 + wn*64 + n*16 + l15;
        float bn = bias[gn];
#pragma unroll
        for (int m = 0; m < 4; ++m) {
#pragma unroll
            for (int i = 0; i < 4; ++i) {
                int gm = m0 + wm*64 + m*16 + l4*4 + i;
                float v = acc[m][n][i] + bn;
                if (RES) v += res[(size_t)gm * D_ + gn];
                if (RELU) v = fmaxf(v, 0.f);
                if (OM == 0) {
                    ((float*)Cout)[(size_t)gm * D_ + gn] = v;
                } else if (OM == 1) {
                    int b = gm / 200, tt = gm - b * 200;
                    ((unsigned short*)Cout)[((size_t)b * TP_ + tt) * D_ + gn] = f2bf(v);
                } else {
                    int b = gm / 200, tt = gm - b * 200;
                    int hh = gn >> 6, dk = gn & 63;
                    ((unsigned short*)Cout)[(((size_t)b * H_ + hh) * 64 + dk) * VTP_ + tt] = f2bf(v);
                }
            }
        }
    }
}

// ---------------- MFMA attention: 1 wave per (qt, h, b), no LDS ----------------
// Swapped QK^T: S^T = mfma(A=K, B=Q) -> lane owns softmax row qr = q0 + (lane&15).
// cm read via symmetry cm[kk][qr] == cm[qr][kk]. P redistributed to PV A-frags by shfl.
template<bool DEC>
__global__ __launch_bounds__(64) void attn_mfma(
    const unsigned short* __restrict__ qbf,   // [b][208][256]
    const unsigned short* __restrict__ kbf,   // [b][208][256]
    const unsigned short* __restrict__ vtbf,  // [b*4+h][64][224]
    const float* __restrict__ cm,
    unsigned short* __restrict__ obf) {       // [bt][256]
    int qt = blockIdx.x, h = blockIdx.y, b = blockIdx.z;
    int lane = threadIdx.x;
    int l15 = lane & 15, l4 = lane >> 4;
    int q0 = qt * 16;
    int qr = q0 + l15;
    const f32x4 zero = {0.f, 0.f, 0.f, 0.f};

    size_t qkb = ((size_t)b * TP_) * D_ + h * 64;
    const unsigned short* qp = qbf + qkb + (size_t)(q0 + l15) * D_ + l4 * 8;
    bf16x8 bq0 = *(const bf16x8*)qp;
    bf16x8 bq1 = *(const bf16x8*)(qp + 32);

    f32x4 S[13];
    float mx = -3e38f;
#pragma unroll
    for (int kt = 0; kt < 13; ++kt) {
        if (kt <= qt) {
            const unsigned short* kp = kbf + qkb + (size_t)(kt * 16 + l15) * D_ + l4 * 8;
            bf16x8 ak0 = *(const bf16x8*)kp;
            bf16x8 ak1 = *(const bf16x8*)(kp + 32);
            f32x4 acc = __builtin_amdgcn_mfma_f32_16x16x32_bf16(ak0, bq0, zero, 0, 0, 0);
            acc = __builtin_amdgcn_mfma_f32_16x16x32_bf16(ak1, bq1, acc, 0, 0, 0);
            f32x4 sv;
#pragma unroll
            for (int i = 0; i < 4; ++i) {
                int kk = kt * 16 + l4 * 4 + i;
                float s = acc[i] * 0.125f;
                bool vld = (qr < T_) && (kk < T_);
                if (!vld) s = -1e9f;
                else {
                    if (kk > qr) s = -1e9f;   // mask BEFORE cm multiply (as reference)
                    if (DEC) s *= (1.0f + 0.5f * cm[((size_t)(b * T_) + kk) * T_ + qr]);
                }
                sv[i] = s;
                mx = fmaxf(mx, s);
            }
            S[kt] = sv;
        }
    }
    mx = fmaxf(mx, __shfl_xor(mx, 16));
    mx = fmaxf(mx, __shfl_xor(mx, 32));
    float sum = 0.f;
#pragma unroll
    for (int kt = 0; kt < 13; ++kt) {
        if (kt <= qt) {
#pragma unroll
            for (int i = 0; i < 4; ++i) {
                float e = __expf(S[kt][i] - mx);
                S[kt][i] = e;
                sum += e;
            }
        }
    }
    sum += __shfl_xor(sum, 16);
    sum += __shfl_xor(sum, 32);
    float inv = 1.f / sum;

    unsigned pk[14][2];
#pragma unroll
    for (int kt = 0; kt < 13; ++kt) {
        if (kt <= qt) {
            pk[kt][0] = pk2(S[kt][0] * inv, S[kt][1] * inv);
            pk[kt][1] = pk2(S[kt][2] * inv, S[kt][3] * inv);
        } else { pk[kt][0] = 0u; pk[kt][1] = 0u; }
    }
    pk[13][0] = 0u; pk[13][1] = 0u;

    f32x4 O[4] = {zero, zero, zero, zero};
    int nch = (qt >> 1) + 1;
    bool lo4 = (l4 < 2);
    int sA = l15 + ((l4 & 1) << 5);   // l15 + 16*((l4&1)*2)
    int sB = sA + 16;
    size_t vbase = ((size_t)(b * H_ + h)) * 64 * VTP_;
#pragma unroll
    for (int t = 0; t < 7; ++t) {
        if (t < nch) {
            unsigned e0A = (unsigned)__shfl((int)pk[2*t][0], sA);
            unsigned e1A = (unsigned)__shfl((int)pk[2*t][1], sA);
            unsigned e0B = (unsigned)__shfl((int)pk[2*t][0], sB);
            unsigned e1B = (unsigned)__shfl((int)pk[2*t][1], sB);
            unsigned o0A = (unsigned)__shfl((int)pk[2*t+1][0], sA);
            unsigned o1A = (unsigned)__shfl((int)pk[2*t+1][1], sA);
            unsigned o0B = (unsigned)__shfl((int)pk[2*t+1][0], sB);
            unsigned o1B = (unsigned)__shfl((int)pk[2*t+1][1], sB);
            frag8 pa;
            pa.u[0] = lo4 ? e0A : o0A;
            pa.u[1] = lo4 ? e1A : o1A;
            pa.u[2] = lo4 ? e0B : o0B;
            pa.u[3] = lo4 ? e1B : o1B;
#pragma unroll
            for (int dt = 0; dt < 4; ++dt) {
                bf16x8 vf = *(const bf16x8*)&vtbf[vbase + (size_t)(dt * 16 + l15) * VTP_ + t * 32 + l4 * 8];
                O[dt] = __builtin_amdgcn_mfma_f32_16x16x32_bf16(pa.v, vf, O[dt], 0, 0, 0);
            }
        }
    }
#pragma unroll
    for (int dt = 0; dt < 4; ++dt) {
#pragma unroll
        for (int i = 0; i < 4; ++i) {
            int qrow = q0 + l4 * 4 + i;
            if (qrow < T_)
                obf[((size_t)(b * T_) + qrow) * D_ + h * 64 + dt * 16 + l15] = f2bf(O[dt][i]);
        }
    }
}

// ---------------- cov ----------------
__global__ void rowmean_kernel(const float* __restrict__ Z, float* __restrict__ m) {
    int row = blockIdx.x, lane = threadIdx.x;
    float4 x = ((const float4*)(Z + (size_t)row * D_))[lane];
    float s = wave_sum(x.x + x.y + x.z + x.w);
    if (lane == 0) m[row] = s * (1.f / D_);
}

#define ZS_ 264
__global__ __launch_bounds__(512) void cov_mfma(const float* __restrict__ Z,
                                                const float* __restrict__ rm,
                                                float* __restrict__ cm) {
    __shared__ unsigned short Zb[208 * ZS_];
    int b = blockIdx.x;
    int tid = threadIdx.x, lane = tid & 63, wv = tid >> 6;
    int l15 = lane & 15, l4 = lane >> 4;

    for (int i = tid; i < T_ * 64; i += 512) {
        int t = i >> 6, c4 = (i & 63) << 2;
        float4 z = *(const float4*)(Z + ((size_t)b * T_ + t) * D_ + c4);
        float m = rm[b * T_ + t];
        unsigned* p = (unsigned*)&Zb[t * ZS_ + c4];
        p[0] = pk2(z.x - m, z.y - m);
        p[1] = pk2(z.z - m, z.w - m);
    }
    for (int i = tid; i < 8 * ZS_; i += 512) Zb[T_ * ZS_ + i] = 0;
    __syncthreads();

    for (int job = wv; job < 91; job += 8) {
        int ti = 0;
        while ((ti + 1) * (ti + 2) / 2 <= job) ++ti;
        int tj = job - ti * (ti + 1) / 2;
        f32x4 acc = {0.f, 0.f, 0.f, 0.f};
#pragma unroll
        for (int s = 0; s < 8; ++s) {
            bf16x8 a  = *(const bf16x8*)&Zb[(ti * 16 + l15) * ZS_ + s * 32 + l4 * 8];
            bf16x8 bb = *(const bf16x8*)&Zb[(tj * 16 + l15) * ZS_ + s * 32 + l4 * 8];
            acc = __builtin_amdgcn_mfma_f32_16x16x32_bf16(a, bb, acc, 0, 0, 0);
        }
#pragma unroll
        for (int i = 0; i < 4; ++i) {
            int t = ti * 16 + l4 * 4 + i, s2 = tj * 16 + l15;
            float vv = fminf(acc[i] * (1.f / 255.f), 3.0f);
            if (t < T_ && s2 < T_) {
                cm[((size_t)b * T_ + t) * T_ + s2] = vv;
                cm[((size_t)b * T_ + s2) * T_ + t] = vv;
            }
        }
    }
}

extern "C" void kernel_launch(void* const* d_in, const int* in_sizes, int n_in,
                              void* d_out, int out_size, void* d_ws, size_t ws_size,
                              hipStream_t stream) {
    const int*   log_seqs = (const int*)  d_in[0];
    const float* item_tab = (const float*)d_in[1];
    const float* pos_tab  = (const float*)d_in[2];
    const float* ln1_s = (const float*)d_in[3];
    const float* ln1_b = (const float*)d_in[4];
    const float* Wq = (const float*)d_in[5];
    const float* bq = (const float*)d_in[6];
    const float* Wk = (const float*)d_in[7];
    const float* bk = (const float*)d_in[8];
    const float* Wv = (const float*)d_in[9];
    const float* bv = (const float*)d_in[10];
    const float* Wo = (const float*)d_in[11];
    const float* bo = (const float*)d_in[12];
    const float* ln2_s = (const float*)d_in[13];
    const float* ln2_b = (const float*)d_in[14];
    const float* W1 = (const float*)d_in[15];
    const float* b1 = (const float*)d_in[16];
    const float* W2 = (const float*)d_in[17];
    const float* b2 = (const float*)d_in[18];
    const float* last_s = (const float*)d_in[19];
    const float* last_b = (const float*)d_in[20];

    float* ws = (float*)d_ws;
    const size_t NTD = (size_t)BT_ * D_;
    float* s0    = ws;              // seqs / layer-3 out
    float* s1    = s0 + NTD;        // causal_z / layer-2 out
    float* Qn    = s1 + NTD;        // ln1 out (residual), then s (in-place)
    float* qb    = Qn + NTD;        // qbf overlay, then y (ln2 out)
    float* vb    = qb + NTD;        // obf overlay, then ffn tmp
    float* cmask = vb + NTD;
    float* rmean = cmask + (size_t)B_ * T_ * T_;
    unsigned short* wtb  = (unsigned short*)(rmean + BT_);       // 24 x DD bf16
    unsigned short* kbf  = wtb + 24 * (size_t)DD_;               // [B][208][256]
    unsigned short* vtbf = kbf + (size_t)B_ * TP_ * D_;          // [B*H][64][224]
    unsigned short* qbf  = (unsigned short*)qb;
    unsigned short* obf  = (unsigned short*)vb;

    unsigned short* wtq = wtb;
    unsigned short* wtk = wtb + 4 * (size_t)DD_;
    unsigned short* wtv = wtb + 8 * (size_t)DD_;
    unsigned short* wto = wtb + 12 * (size_t)DD_;
    unsigned short* wt1 = wtb + 16 * (size_t)DD_;
    unsigned short* wt2 = wtb + 20 * (size_t)DD_;

    dim3 tg(4, 4, 4);
    wtrans_kernel<<<tg, 256, 0, stream>>>(Wq, wtq);
    wtrans_kernel<<<tg, 256, 0, stream>>>(Wk, wtk);
    wtrans_kernel<<<tg, 256, 0, stream>>>(Wv, wtv);
    wtrans_kernel<<<tg, 256, 0, stream>>>(Wo, wto);
    wtrans_kernel<<<tg, 256, 0, stream>>>(W1, wt1);
    wtrans_kernel<<<tg, 256, 0, stream>>>(W2, wt2);
    vtpad_kernel<<<B_ * H_ * 64, 32, 0, stream>>>(vtbf);

    dim3 gg(2, 400);   // N/128, M/128

    auto encoder = [&](const float* X, float* OUT, int i, const float* cmp) {
        ln_kernel<<<BT_/4, 256, 0, stream>>>(X, ln1_s + i*D_, ln1_b + i*D_, Qn);
        gemm_mfma<0,1,false,false><<<gg, 256, 0, stream>>>(Qn, wtq + (size_t)i*DD_, bq + i*D_, nullptr, qbf);
        gemm_mfma<0,1,false,false><<<gg, 256, 0, stream>>>(X,  wtk + (size_t)i*DD_, bk + i*D_, nullptr, kbf);
        gemm_mfma<0,2,false,false><<<gg, 256, 0, stream>>>(X,  wtv + (size_t)i*DD_, bv + i*D_, nullptr, vtbf);
        if (cmp) attn_mfma<true ><<<dim3(13, H_, B_), 64, 0, stream>>>(qbf, kbf, vtbf, cmp, obf);
        else     attn_mfma<false><<<dim3(13, H_, B_), 64, 0, stream>>>(qbf, kbf, vtbf, nullptr, obf);
        // s = Qn + obf @ Wo + bo   (in-place into Qn; element-exclusive)
        gemm_mfma<1,0,false,true><<<gg, 256, 0, stream>>>(obf, wto + (size_t)i*DD_, bo + i*D_, Qn, Qn);
        ln_kernel<<<BT_/4, 256, 0, stream>>>(Qn, ln2_s + i*D_, ln2_b + i*D_, qb);   // y
        gemm_mfma<0,0,true,false><<<gg, 256, 0, stream>>>(qb, wt1 + (size_t)i*DD_, b1 + i*D_, nullptr, vb);
        gemm_mfma<0,0,false,true><<<gg, 256, 0, stream>>>(vb, wt2 + (size_t)i*DD_, b2 + i*D_, qb, OUT);
    };

    embed_kernel<<<BT_, 64, 0, stream>>>(log_seqs, item_tab, pos_tab, s0);

    // causal loop applies each layer to ORIGINAL seqs -> only layer 1 survives
    encoder(s0, s1, 1, nullptr);

    rowmean_kernel<<<BT_, 64, 0, stream>>>(s1, rmean);
    cov_mfma<<<B_, 512, 0, stream>>>(s1, rmean, cmask);

    encoder(s0, s1, 2, cmask);
    encoder(s1, s0, 3, cmask);

    ln_kernel<<<BT_/4, 256, 0, stream>>>(s0, last_s, last_b, (float*)d_out);
}

// Round 8
// 1248.101 us; speedup vs baseline: 1.9072x; 1.9072x over previous
//
#include <hip/hip_runtime.h>
#include <hip/hip_bf16.h>

#define B_ 256
#define T_ 200
#define D_ 256
#define H_ 4
#define BT_ (B_*T_)
#define DD_ (D_*D_)
#define GS_ 72     // gemm LDS stride (64 + 8 pad)
#define TP_ 208    // padded token rows per batch for qbf/kbf
#define VTP_ 224   // vtbf row length (7*32)

typedef __attribute__((ext_vector_type(4))) float  f32x4;
typedef __attribute__((ext_vector_type(8))) __bf16 bf16x8;
typedef __attribute__((ext_vector_type(4))) int    i32x4;

union frag8 { unsigned u[4]; bf16x8 v; };

__device__ __forceinline__ unsigned short f2bf(float f) {
    unsigned u = __float_as_uint(f);
    u += 0x7FFFu + ((u >> 16) & 1u);          // RNE to bf16
    return (unsigned short)(u >> 16);
}
__device__ __forceinline__ unsigned pk2(float lo, float hi) {
    return (unsigned)f2bf(lo) | ((unsigned)f2bf(hi) << 16);
}

__device__ __forceinline__ float wave_sum(float v) {
#pragma unroll
    for (int o = 32; o >= 1; o >>= 1) v += __shfl_xor(v, o);
    return v;
}

// ---------------- embed ----------------
__global__ void embed_kernel(const int* __restrict__ ls,
                             const float* __restrict__ itab,
                             const float* __restrict__ ptab,
                             float* __restrict__ seqs) {
    int bt = blockIdx.x;
    int t = bt % T_;
    int lane = threadIdx.x;
    int idx = ls[bt];
    int pos = idx ? (t + 1) : 0;
    float4 a = ((const float4*)(itab + (size_t)idx * D_))[lane];
    float4 p = ((const float4*)(ptab + (size_t)pos * D_))[lane];
    float4 r = { a.x*16.f+p.x, a.y*16.f+p.y, a.z*16.f+p.z, a.w*16.f+p.w };
    ((float4*)(seqs + (size_t)bt * D_))[lane] = r;
}

// ---------------- layernorm (4 rows / 256-thread block) ----------------
__global__ __launch_bounds__(256) void ln_kernel(const float* __restrict__ X,
                                                 const float* __restrict__ sc,
                                                 const float* __restrict__ bi,
                                                 float* __restrict__ Y) {
    int row = blockIdx.x * 4 + (threadIdx.x >> 6);
    int lane = threadIdx.x & 63;
    float4 x = ((const float4*)(X + (size_t)row * D_))[lane];
    float m = wave_sum(x.x + x.y + x.z + x.w) * (1.f / D_);
    float d0 = x.x - m, d1 = x.y - m, d2 = x.z - m, d3 = x.w - m;
    float v = wave_sum(d0*d0 + d1*d1 + d2*d2 + d3*d3) * (1.f / D_);
    float inv = rsqrtf(v + 1e-8f);
    float4 s4 = ((const float4*)sc)[lane];
    float4 b4 = ((const float4*)bi)[lane];
    float4 r = { d0*inv*s4.x + b4.x, d1*inv*s4.y + b4.y,
                 d2*inv*s4.z + b4.z, d3*inv*s4.w + b4.w };
    ((float4*)(Y + (size_t)row * D_))[lane] = r;
}

// ---------------- weight transpose: Wt[n][k] = bf16(W[k][n]) ----------------
__global__ __launch_bounds__(256) void wtrans_kernel(const float* __restrict__ W,
                                                     unsigned short* __restrict__ Wt) {
    __shared__ float tile[64][65];
    int c0 = blockIdx.x * 64, r0 = blockIdx.y * 64, l = blockIdx.z;
    const float* src = W + (size_t)l * DD_;
    unsigned short* dst = Wt + (size_t)l * DD_;
    int tid = threadIdx.x;
#pragma unroll
    for (int rep = 0; rep < 16; ++rep) {
        int idx = rep * 256 + tid;
        int r = idx >> 6, c = idx & 63;
        tile[r][c] = src[(size_t)(r0 + r) * D_ + c0 + c];
    }
    __syncthreads();
#pragma unroll
    for (int rep = 0; rep < 16; ++rep) {
        int idx = rep * 256 + tid;
        int r2 = idx >> 6, c2 = idx & 63;
        dst[(size_t)(c0 + r2) * D_ + r0 + c2] = f2bf(tile[c2][r2]);
    }
}

// zero vtbf pad cols [200,224) once per launch (NaN x 0 guard)
__global__ void vtpad_kernel(unsigned short* __restrict__ vt) {
    if (threadIdx.x < VTP_ - T_)
        vt[(size_t)blockIdx.x * VTP_ + T_ + threadIdx.x] = 0;
}

// ---------------- MFMA GEMM ----------------
// C[M,256] = A[M,256] @ W + bias (+res)(relu); Wt bf16 [n][k] pre-transposed.
// AM: 0 = A fp32, 1 = A bf16 flat.
// OM: 0 = C fp32 [m][256]; 1 = bf16 row-padded [b][208][256]; 2 = bf16 V^T [g][64][224].
template<int AM, int OM, bool RELU, bool RES>
__global__ __launch_bounds__(256) void gemm_mfma(
    const void* __restrict__ Ap, const unsigned short* __restrict__ Wt,
    const float* __restrict__ bias, const float* res, void* Cout) {
    __shared__ unsigned short As[128 * GS_];
    __shared__ unsigned short Ws[128 * GS_];
    int t = threadIdx.x, lane = t & 63, wv = t >> 6;
    int wm = wv >> 1, wn = wv & 1;
    int l15 = lane & 15, l4 = lane >> 4;
    int m0 = blockIdx.y * 128, n0 = blockIdx.x * 128;

    f32x4 acc[4][4];
#pragma unroll
    for (int m = 0; m < 4; ++m)
#pragma unroll
        for (int n = 0; n < 4; ++n)
            acc[m][n] = f32x4{0.f, 0.f, 0.f, 0.f};

    for (int k0 = 0; k0 < D_; k0 += 64) {
        if (AM == 0) {
            const float* A = (const float*)Ap;
#pragma unroll
            for (int rep = 0; rep < 8; ++rep) {
                int idx = rep * 256 + t;
                int r = idx >> 4, c4 = (idx & 15) * 4;
                float4 a = *(const float4*)(A + (size_t)(m0 + r) * D_ + k0 + c4);
                unsigned* p = (unsigned*)&As[r * GS_ + c4];
                p[0] = pk2(a.x, a.y);
                p[1] = pk2(a.z, a.w);
            }
        } else {
            const unsigned short* A = (const unsigned short*)Ap;
#pragma unroll
            for (int rep = 0; rep < 4; ++rep) {
                int idx = rep * 256 + t;
                int r = idx >> 3, c8 = (idx & 7) * 8;
                *(i32x4*)&As[r * GS_ + c8] =
                    *(const i32x4*)(A + (size_t)(m0 + r) * D_ + k0 + c8);
            }
        }
#pragma unroll
        for (int rep = 0; rep < 4; ++rep) {
            int idx = rep * 256 + t;
            int r = idx >> 3, c8 = (idx & 7) * 8;
            *(i32x4*)&Ws[r * GS_ + c8] =
                *(const i32x4*)(Wt + (size_t)(n0 + r) * D_ + k0 + c8);
        }
        __syncthreads();
#pragma unroll
        for (int kk = 0; kk < 2; ++kk) {
            bf16x8 af[4], bf[4];
#pragma unroll
            for (int m = 0; m < 4; ++m)
                af[m] = *(const bf16x8*)&As[(wm*64 + m*16 + l15) * GS_ + kk*32 + l4*8];
#pragma unroll
            for (int n = 0; n < 4; ++n)
                bf[n] = *(const bf16x8*)&Ws[(wn*64 + n*16 + l15) * GS_ + kk*32 + l4*8];
#pragma unroll
            for (int m = 0; m < 4; ++m)
#pragma unroll
                for (int n = 0; n < 4; ++n)
                    acc[m][n] = __builtin_amdgcn_mfma_f32_16x16x32_bf16(af[m], bf[n], acc[m][n], 0, 0, 0);
        }
        __syncthreads();
    }
#pragma unroll
    for (int n = 0; n < 4; ++n) {
        int gn = n0 + wn*64 + n*16 + l15;
        float bn = bias[gn];
#pragma unroll
        for (int m = 0; m < 4; ++m) {
#pragma unroll
            for (int i = 0; i < 4; ++i) {
                int gm = m0 + wm*64 + m*16 + l4*4 + i;
                float v = acc[m][n][i] + bn;
                if (RES) v += res[(size_t)gm * D_ + gn];
                if (RELU) v = fmaxf(v, 0.f);
                if (OM == 0) {
                    ((float*)Cout)[(size_t)gm * D_ + gn] = v;
                } else if (OM == 1) {
                    int b = gm / 200, tt = gm - b * 200;
                    ((unsigned short*)Cout)[((size_t)b * TP_ + tt) * D_ + gn] = f2bf(v);
                } else {
                    int b = gm / 200, tt = gm - b * 200;
                    int hh = gn >> 6, dk = gn & 63;
                    ((unsigned short*)Cout)[(((size_t)b * H_ + hh) * 64 + dk) * VTP_ + tt] = f2bf(v);
                }
            }
        }
    }
}

// ---------------- MFMA attention: 1 wave per (qt, h, b), no LDS, online softmax ----
// Swapped QK^T: S^T = mfma(A=K, B=Q) -> lane owns softmax row qr = q0 + (lane&15).
// Per kt-PAIR: QK^T -> rescale m/l/O -> exp -> shfl-redistribute P -> 4 PV K=32 MFMAs.
// Tiny live set (~70 VGPR) -> no spills (round-7 lesson).
template<bool DEC>
__global__ __launch_bounds__(64) void attn_mfma(
    const unsigned short* __restrict__ qbf,   // [b][208][256]
    const unsigned short* __restrict__ kbf,   // [b][208][256]
    const unsigned short* __restrict__ vtbf,  // [b*4+h][64][224]
    const float* __restrict__ cm,
    unsigned short* __restrict__ obf) {       // [bt][256]
    int qt = blockIdx.x, h = blockIdx.y, b = blockIdx.z;
    int lane = threadIdx.x;
    int l15 = lane & 15, l4 = lane >> 4;
    int q0 = qt * 16;
    int qr = q0 + l15;                         // this lane's softmax row
    const f32x4 zero = {0.f, 0.f, 0.f, 0.f};

    size_t qkb = ((size_t)b * TP_) * D_ + h * 64;
    const unsigned short* qp = qbf + qkb + (size_t)(q0 + l15) * D_ + l4 * 8;
    bf16x8 bq0 = *(const bf16x8*)qp;
    bf16x8 bq1 = *(const bf16x8*)(qp + 32);

    size_t vbase = ((size_t)(b * H_ + h)) * 64 * VTP_;
    int sA = l15 + ((l4 & 1) << 5);
    int sB = sA + 16;
    bool lo4 = (l4 < 2);

    float m = -3e38f, l = 0.f;
    f32x4 O[4] = {zero, zero, zero, zero};

    int npair = (qt >> 1) + 1;
    for (int p = 0; p < npair; ++p) {
        int kt0 = 2 * p;
        bool hasOdd = (kt0 + 1 <= qt);

        // --- QK^T for even tile (always) and odd tile (if present) ---
        f32x4 sv0, sv1;
        {
            const unsigned short* kp = kbf + qkb + (size_t)(kt0 * 16 + l15) * D_ + l4 * 8;
            bf16x8 ak0 = *(const bf16x8*)kp;
            bf16x8 ak1 = *(const bf16x8*)(kp + 32);
            f32x4 acc = __builtin_amdgcn_mfma_f32_16x16x32_bf16(ak0, bq0, zero, 0, 0, 0);
            acc = __builtin_amdgcn_mfma_f32_16x16x32_bf16(ak1, bq1, acc, 0, 0, 0);
#pragma unroll
            for (int i = 0; i < 4; ++i) {
                int kk = kt0 * 16 + l4 * 4 + i;
                float s = acc[i] * 0.125f;
                bool vld = (qr < T_) && (kk < T_);
                float cmv = (DEC && vld) ? cm[((size_t)(b * T_) + kk) * T_ + qr] : 0.f;
                if (!vld) s = -1e9f;
                else {
                    if (kk > qr) s = -1e9f;   // mask BEFORE cm multiply (as reference)
                    if (DEC) s *= (1.0f + 0.5f * cmv);
                }
                sv0[i] = s;
            }
        }
        if (hasOdd) {
            const unsigned short* kp = kbf + qkb + (size_t)((kt0 + 1) * 16 + l15) * D_ + l4 * 8;
            bf16x8 ak0 = *(const bf16x8*)kp;
            bf16x8 ak1 = *(const bf16x8*)(kp + 32);
            f32x4 acc = __builtin_amdgcn_mfma_f32_16x16x32_bf16(ak0, bq0, zero, 0, 0, 0);
            acc = __builtin_amdgcn_mfma_f32_16x16x32_bf16(ak1, bq1, acc, 0, 0, 0);
#pragma unroll
            for (int i = 0; i < 4; ++i) {
                int kk = (kt0 + 1) * 16 + l4 * 4 + i;
                float s = acc[i] * 0.125f;
                bool vld = (qr < T_) && (kk < T_);
                float cmv = (DEC && vld) ? cm[((size_t)(b * T_) + kk) * T_ + qr] : 0.f;
                if (!vld) s = -1e9f;
                else {
                    if (kk > qr) s = -1e9f;
                    if (DEC) s *= (1.0f + 0.5f * cmv);
                }
                sv1[i] = s;
            }
        }

        // --- online max / rescale (per qr = per l15 group) ---
        float tm = fmaxf(fmaxf(sv0[0], sv0[1]), fmaxf(sv0[2], sv0[3]));
        if (hasOdd) {
            float tm1 = fmaxf(fmaxf(sv1[0], sv1[1]), fmaxf(sv1[2], sv1[3]));
            tm = fmaxf(tm, tm1);
        }
        tm = fmaxf(tm, __shfl_xor(tm, 16));
        tm = fmaxf(tm, __shfl_xor(tm, 32));
        float m_new = fmaxf(m, tm);
        float sc = __expf(m - m_new);
        m = m_new;
        l *= sc;
        // rescale O rows (O row index = l4*4+i; its factor lives at lane l4*4+i)
#pragma unroll
        for (int i = 0; i < 4; ++i) {
            float osc = __shfl(sc, l4 * 4 + i);
#pragma unroll
            for (int dt = 0; dt < 4; ++dt) O[dt][i] *= osc;
        }

        // --- exp + partial sum ---
        float p0[4], p1[4];
#pragma unroll
        for (int i = 0; i < 4; ++i) {
            p0[i] = __expf(sv0[i] - m);
            l += p0[i];
        }
        if (hasOdd) {
#pragma unroll
            for (int i = 0; i < 4; ++i) {
                p1[i] = __expf(sv1[i] - m);
                l += p1[i];
            }
        } else {
#pragma unroll
            for (int i = 0; i < 4; ++i) p1[i] = 0.f;
        }

        // --- pack + shfl-redistribute P into PV A-fragment (K=32 over the pair) ---
        unsigned pk0a = pk2(p0[0], p0[1]), pk0b = pk2(p0[2], p0[3]);
        unsigned pk1a = pk2(p1[0], p1[1]), pk1b = pk2(p1[2], p1[3]);
        unsigned e0 = (unsigned)__shfl((int)pk0a, sA);
        unsigned e1 = (unsigned)__shfl((int)pk0b, sA);
        unsigned e2 = (unsigned)__shfl((int)pk0a, sB);
        unsigned e3 = (unsigned)__shfl((int)pk0b, sB);
        unsigned o0 = (unsigned)__shfl((int)pk1a, sA);
        unsigned o1 = (unsigned)__shfl((int)pk1b, sA);
        unsigned o2 = (unsigned)__shfl((int)pk1a, sB);
        unsigned o3 = (unsigned)__shfl((int)pk1b, sB);
        frag8 pa;
        pa.u[0] = lo4 ? e0 : o0;
        pa.u[1] = lo4 ? e1 : o1;
        pa.u[2] = lo4 ? e2 : o2;
        pa.u[3] = lo4 ? e3 : o3;

        // --- PV: O += P_pair @ V[kk32 block p] ---
#pragma unroll
        for (int dt = 0; dt < 4; ++dt) {
            bf16x8 vf = *(const bf16x8*)&vtbf[vbase + (size_t)(dt * 16 + l15) * VTP_ + p * 32 + l4 * 8];
            O[dt] = __builtin_amdgcn_mfma_f32_16x16x32_bf16(pa.v, vf, O[dt], 0, 0, 0);
        }
    }

    // --- final normalization ---
    float L = l;
    L += __shfl_xor(L, 16);
    L += __shfl_xor(L, 32);
    float inv = 1.f / L;
#pragma unroll
    for (int i = 0; i < 4; ++i) {
        float oin = __shfl(inv, l4 * 4 + i);
        int qrow = q0 + l4 * 4 + i;
        if (qrow < T_) {
#pragma unroll
            for (int dt = 0; dt < 4; ++dt)
                obf[((size_t)(b * T_) + qrow) * D_ + h * 64 + dt * 16 + l15] = f2bf(O[dt][i] * oin);
        }
    }
}

// ---------------- cov ----------------
__global__ void rowmean_kernel(const float* __restrict__ Z, float* __restrict__ m) {
    int row = blockIdx.x, lane = threadIdx.x;
    float4 x = ((const float4*)(Z + (size_t)row * D_))[lane];
    float s = wave_sum(x.x + x.y + x.z + x.w);
    if (lane == 0) m[row] = s * (1.f / D_);
}

#define ZS_ 264
__global__ __launch_bounds__(512) void cov_mfma(const float* __restrict__ Z,
                                                const float* __restrict__ rm,
                                                float* __restrict__ cm) {
    __shared__ unsigned short Zb[208 * ZS_];
    int b = blockIdx.x;
    int tid = threadIdx.x, lane = tid & 63, wv = tid >> 6;
    int l15 = lane & 15, l4 = lane >> 4;

    for (int i = tid; i < T_ * 64; i += 512) {
        int t = i >> 6, c4 = (i & 63) << 2;
        float4 z = *(const float4*)(Z + ((size_t)b * T_ + t) * D_ + c4);
        float m = rm[b * T_ + t];
        unsigned* p = (unsigned*)&Zb[t * ZS_ + c4];
        p[0] = pk2(z.x - m, z.y - m);
        p[1] = pk2(z.z - m, z.w - m);
    }
    for (int i = tid; i < 8 * ZS_; i += 512) Zb[T_ * ZS_ + i] = 0;
    __syncthreads();

    for (int job = wv; job < 91; job += 8) {
        int ti = 0;
        while ((ti + 1) * (ti + 2) / 2 <= job) ++ti;
        int tj = job - ti * (ti + 1) / 2;
        f32x4 acc = {0.f, 0.f, 0.f, 0.f};
#pragma unroll
        for (int s = 0; s < 8; ++s) {
            bf16x8 a  = *(const bf16x8*)&Zb[(ti * 16 + l15) * ZS_ + s * 32 + l4 * 8];
            bf16x8 bb = *(const bf16x8*)&Zb[(tj * 16 + l15) * ZS_ + s * 32 + l4 * 8];
            acc = __builtin_amdgcn_mfma_f32_16x16x32_bf16(a, bb, acc, 0, 0, 0);
        }
#pragma unroll
        for (int i = 0; i < 4; ++i) {
            int t = ti * 16 + l4 * 4 + i, s2 = tj * 16 + l15;
            float vv = fminf(acc[i] * (1.f / 255.f), 3.0f);
            if (t < T_ && s2 < T_) {
                cm[((size_t)b * T_ + t) * T_ + s2] = vv;
                cm[((size_t)b * T_ + s2) * T_ + t] = vv;
            }
        }
    }
}

extern "C" void kernel_launch(void* const* d_in, const int* in_sizes, int n_in,
                              void* d_out, int out_size, void* d_ws, size_t ws_size,
                              hipStream_t stream) {
    const int*   log_seqs = (const int*)  d_in[0];
    const float* item_tab = (const float*)d_in[1];
    const float* pos_tab  = (const float*)d_in[2];
    const float* ln1_s = (const float*)d_in[3];
    const float* ln1_b = (const float*)d_in[4];
    const float* Wq = (const float*)d_in[5];
    const float* bq = (const float*)d_in[6];
    const float* Wk = (const float*)d_in[7];
    const float* bk = (const float*)d_in[8];
    const float* Wv = (const float*)d_in[9];
    const float* bv = (const float*)d_in[10];
    const float* Wo = (const float*)d_in[11];
    const float* bo = (const float*)d_in[12];
    const float* ln2_s = (const float*)d_in[13];
    const float* ln2_b = (const float*)d_in[14];
    const float* W1 = (const float*)d_in[15];
    const float* b1 = (const float*)d_in[16];
    const float* W2 = (const float*)d_in[17];
    const float* b2 = (const float*)d_in[18];
    const float* last_s = (const float*)d_in[19];
    const float* last_b = (const float*)d_in[20];

    float* ws = (float*)d_ws;
    const size_t NTD = (size_t)BT_ * D_;
    float* s0    = ws;              // seqs / layer-3 out
    float* s1    = s0 + NTD;        // causal_z / layer-2 out
    float* Qn    = s1 + NTD;        // ln1 out (residual), then s (in-place)
    float* qb    = Qn + NTD;        // qbf overlay, then y (ln2 out)
    float* vb    = qb + NTD;        // obf overlay, then ffn tmp
    float* cmask = vb + NTD;
    float* rmean = cmask + (size_t)B_ * T_ * T_;
    unsigned short* wtb  = (unsigned short*)(rmean + BT_);       // 24 x DD bf16
    unsigned short* kbf  = wtb + 24 * (size_t)DD_;               // [B][208][256]
    unsigned short* vtbf = kbf + (size_t)B_ * TP_ * D_;          // [B*H][64][224]
    unsigned short* qbf  = (unsigned short*)qb;
    unsigned short* obf  = (unsigned short*)vb;

    unsigned short* wtq = wtb;
    unsigned short* wtk = wtb + 4 * (size_t)DD_;
    unsigned short* wtv = wtb + 8 * (size_t)DD_;
    unsigned short* wto = wtb + 12 * (size_t)DD_;
    unsigned short* wt1 = wtb + 16 * (size_t)DD_;
    unsigned short* wt2 = wtb + 20 * (size_t)DD_;

    dim3 tg(4, 4, 4);
    wtrans_kernel<<<tg, 256, 0, stream>>>(Wq, wtq);
    wtrans_kernel<<<tg, 256, 0, stream>>>(Wk, wtk);
    wtrans_kernel<<<tg, 256, 0, stream>>>(Wv, wtv);
    wtrans_kernel<<<tg, 256, 0, stream>>>(Wo, wto);
    wtrans_kernel<<<tg, 256, 0, stream>>>(W1, wt1);
    wtrans_kernel<<<tg, 256, 0, stream>>>(W2, wt2);
    vtpad_kernel<<<B_ * H_ * 64, 32, 0, stream>>>(vtbf);

    dim3 gg(2, 400);   // N/128, M/128

    auto encoder = [&](const float* X, float* OUT, int i, const float* cmp) {
        ln_kernel<<<BT_/4, 256, 0, stream>>>(X, ln1_s + i*D_, ln1_b + i*D_, Qn);
        gemm_mfma<0,1,false,false><<<gg, 256, 0, stream>>>(Qn, wtq + (size_t)i*DD_, bq + i*D_, nullptr, qbf);
        gemm_mfma<0,1,false,false><<<gg, 256, 0, stream>>>(X,  wtk + (size_t)i*DD_, bk + i*D_, nullptr, kbf);
        gemm_mfma<0,2,false,false><<<gg, 256, 0, stream>>>(X,  wtv + (size_t)i*DD_, bv + i*D_, nullptr, vtbf);
        if (cmp) attn_mfma<true ><<<dim3(13, H_, B_), 64, 0, stream>>>(qbf, kbf, vtbf, cmp, obf);
        else     attn_mfma<false><<<dim3(13, H_, B_), 64, 0, stream>>>(qbf, kbf, vtbf, nullptr, obf);
        // s = Qn + obf @ Wo + bo   (in-place into Qn; element-exclusive)
        gemm_mfma<1,0,false,true><<<gg, 256, 0, stream>>>(obf, wto + (size_t)i*DD_, bo + i*D_, Qn, Qn);
        ln_kernel<<<BT_/4, 256, 0, stream>>>(Qn, ln2_s + i*D_, ln2_b + i*D_, qb);   // y
        gemm_mfma<0,0,true,false><<<gg, 256, 0, stream>>>(qb, wt1 + (size_t)i*DD_, b1 + i*D_, nullptr, vb);
        gemm_mfma<0,0,false,true><<<gg, 256, 0, stream>>>(vb, wt2 + (size_t)i*DD_, b2 + i*D_, qb, OUT);
    };

    embed_kernel<<<BT_, 64, 0, stream>>>(log_seqs, item_tab, pos_tab, s0);

    // causal loop applies each layer to ORIGINAL seqs -> only layer 1 survives
    encoder(s0, s1, 1, nullptr);

    rowmean_kernel<<<BT_, 64, 0, stream>>>(s1, rmean);
    cov_mfma<<<B_, 512, 0, stream>>>(s1, rmean, cmask);

    encoder(s0, s1, 2, cmask);
    encoder(s1, s0, 3, cmask);

    ln_kernel<<<BT_/4, 256, 0, stream>>>(s0, last_s, last_b, (float*)d_out);
}

// Round 10
// 1134.511 us; speedup vs baseline: 2.0982x; 1.1001x over previous
//
#include <hip/hip_runtime.h>
#include <hip/hip_bf16.h>

#define B_ 256
#define T_ 200
#define D_ 256
#define H_ 4
#define BT_ (B_*T_)
#define DD_ (D_*D_)
#define GS_ 72     // gemm LDS stride (64 + 8 pad)
#define TP_ 208    // padded token rows per batch for qbf/kbf
#define VTP_ 224   // vtbf row length (7*32)
#define ZS_ 264    // cov Zb stride

typedef __attribute__((ext_vector_type(4))) float  f32x4;
typedef __attribute__((ext_vector_type(8))) __bf16 bf16x8;
typedef __attribute__((ext_vector_type(4))) int    i32x4;
typedef __attribute__((ext_vector_type(2))) int    i32x2;

union frag8 { unsigned u[4]; bf16x8 v; };

__device__ __forceinline__ unsigned short f2bf(float f) {
    unsigned u = __float_as_uint(f);
    u += 0x7FFFu + ((u >> 16) & 1u);          // RNE to bf16
    return (unsigned short)(u >> 16);
}
__device__ __forceinline__ unsigned pk2(float lo, float hi) {
    return (unsigned)f2bf(lo) | ((unsigned)f2bf(hi) << 16);
}
__device__ __forceinline__ float bflo(unsigned u) { return __uint_as_float(u << 16); }
__device__ __forceinline__ float bfhi(unsigned u) { return __uint_as_float(u & 0xFFFF0000u); }

__device__ __forceinline__ float wave_sum(float v) {
#pragma unroll
    for (int o = 32; o >= 1; o >>= 1) v += __shfl_xor(v, o);
    return v;
}

// ---------------- embed (bf16 out) ----------------
__global__ void embed_kernel(const int* __restrict__ ls,
                             const float* __restrict__ itab,
                             const float* __restrict__ ptab,
                             unsigned short* __restrict__ seqs) {
    int bt = blockIdx.x;
    int t = bt % T_;
    int lane = threadIdx.x;
    int idx = ls[bt];
    int pos = idx ? (t + 1) : 0;
    float4 a = ((const float4*)(itab + (size_t)idx * D_))[lane];
    float4 p = ((const float4*)(ptab + (size_t)pos * D_))[lane];
    i32x2 r;
    r[0] = (int)pk2(a.x*16.f+p.x, a.y*16.f+p.y);
    r[1] = (int)pk2(a.z*16.f+p.z, a.w*16.f+p.w);
    ((i32x2*)(seqs + (size_t)bt * D_))[lane] = r;
}

// ---------------- layernorm (bf16 in; bf16 or fp32 out), 4 rows/block ----------------
template<bool F32OUT>
__global__ __launch_bounds__(256) void ln_kernel(const unsigned short* __restrict__ X,
                                                 const float* __restrict__ sc,
                                                 const float* __restrict__ bi,
                                                 void* __restrict__ Y) {
    int row = blockIdx.x * 4 + (threadIdx.x >> 6);
    int lane = threadIdx.x & 63;
    i32x2 xv = ((const i32x2*)(X + (size_t)row * D_))[lane];
    float x0 = bflo((unsigned)xv[0]), x1 = bfhi((unsigned)xv[0]);
    float x2 = bflo((unsigned)xv[1]), x3 = bfhi((unsigned)xv[1]);
    float m = wave_sum(x0 + x1 + x2 + x3) * (1.f / D_);
    float d0 = x0 - m, d1 = x1 - m, d2 = x2 - m, d3 = x3 - m;
    float v = wave_sum(d0*d0 + d1*d1 + d2*d2 + d3*d3) * (1.f / D_);
    float inv = rsqrtf(v + 1e-8f);
    float4 s4 = ((const float4*)sc)[lane];
    float4 b4 = ((const float4*)bi)[lane];
    float r0 = d0*inv*s4.x + b4.x, r1 = d1*inv*s4.y + b4.y;
    float r2 = d2*inv*s4.z + b4.z, r3 = d3*inv*s4.w + b4.w;
    if (F32OUT) {
        float4 r = {r0, r1, r2, r3};
        ((float4*)Y)[(size_t)row * (D_/4) + lane] = r;
    } else {
        i32x2 r;
        r[0] = (int)pk2(r0, r1);
        r[1] = (int)pk2(r2, r3);
        // i32x2 holds 4 bf16 -> row stride = D_/4 units (round-9 bug was D_/8)
        ((i32x2*)Y)[(size_t)row * (D_/4) + lane] = r;
    }
}

// ---------------- weight transpose: Wt[n][k] = bf16(W[k][n]) ----------------
__global__ __launch_bounds__(256) void wtrans_kernel(const float* __restrict__ W,
                                                     unsigned short* __restrict__ Wt) {
    __shared__ float tile[64][65];
    int c0 = blockIdx.x * 64, r0 = blockIdx.y * 64, l = blockIdx.z;
    const float* src = W + (size_t)l * DD_;
    unsigned short* dst = Wt + (size_t)l * DD_;
    int tid = threadIdx.x;
#pragma unroll
    for (int rep = 0; rep < 16; ++rep) {
        int idx = rep * 256 + tid;
        int r = idx >> 6, c = idx & 63;
        tile[r][c] = src[(size_t)(r0 + r) * D_ + c0 + c];
    }
    __syncthreads();
#pragma unroll
    for (int rep = 0; rep < 16; ++rep) {
        int idx = rep * 256 + tid;
        int r2 = idx >> 6, c2 = idx & 63;
        dst[(size_t)(c0 + r2) * D_ + r0 + c2] = f2bf(tile[c2][r2]);
    }
}

// zero vtbf pad cols [200,224)
__global__ void vtpad_kernel(unsigned short* __restrict__ vt) {
    if (threadIdx.x < VTP_ - T_)
        vt[(size_t)blockIdx.x * VTP_ + T_ + threadIdx.x] = 0;
}

// ---------------- MFMA GEMM: C[M,256] = A[M,256] @ W + bias (+res)(relu) ----
// A bf16 flat [m][256]; Wt bf16 [n][k] pre-transposed; res bf16 flat.
// OM: 0 = bf16 flat [m][256]; 1 = bf16 padded [b][208][256]; 2 = bf16 V^T [g][64][224].
template<int OM, bool RELU, bool RES>
__global__ __launch_bounds__(256) void gemm_mfma(
    const unsigned short* __restrict__ A, const unsigned short* __restrict__ Wt,
    const float* __restrict__ bias, const unsigned short* res,
    unsigned short* Cout) {
    __shared__ unsigned short As[128 * GS_];
    __shared__ unsigned short Ws[128 * GS_];
    int t = threadIdx.x, lane = t & 63, wv = t >> 6;
    int wm = wv >> 1, wn = wv & 1;
    int l15 = lane & 15, l4 = lane >> 4;
    int m0 = blockIdx.y * 128, n0 = blockIdx.x * 128;

    f32x4 acc[4][4];
#pragma unroll
    for (int m = 0; m < 4; ++m)
#pragma unroll
        for (int n = 0; n < 4; ++n)
            acc[m][n] = f32x4{0.f, 0.f, 0.f, 0.f};

    for (int k0 = 0; k0 < D_; k0 += 64) {
#pragma unroll
        for (int rep = 0; rep < 4; ++rep) {
            int idx = rep * 256 + t;
            int r = idx >> 3, c8 = (idx & 7) * 8;
            *(i32x4*)&As[r * GS_ + c8] =
                *(const i32x4*)(A + (size_t)(m0 + r) * D_ + k0 + c8);
        }
#pragma unroll
        for (int rep = 0; rep < 4; ++rep) {
            int idx = rep * 256 + t;
            int r = idx >> 3, c8 = (idx & 7) * 8;
            *(i32x4*)&Ws[r * GS_ + c8] =
                *(const i32x4*)(Wt + (size_t)(n0 + r) * D_ + k0 + c8);
        }
        __syncthreads();
#pragma unroll
        for (int kk = 0; kk < 2; ++kk) {
            bf16x8 af[4], bf[4];
#pragma unroll
            for (int m = 0; m < 4; ++m)
                af[m] = *(const bf16x8*)&As[(wm*64 + m*16 + l15) * GS_ + kk*32 + l4*8];
#pragma unroll
            for (int n = 0; n < 4; ++n)
                bf[n] = *(const bf16x8*)&Ws[(wn*64 + n*16 + l15) * GS_ + kk*32 + l4*8];
#pragma unroll
            for (int m = 0; m < 4; ++m)
#pragma unroll
                for (int n = 0; n < 4; ++n)
                    acc[m][n] = __builtin_amdgcn_mfma_f32_16x16x32_bf16(af[m], bf[n], acc[m][n], 0, 0, 0);
        }
        __syncthreads();
    }
#pragma unroll
    for (int n = 0; n < 4; ++n) {
        int gn = n0 + wn*64 + n*16 + l15;
        float bn = bias[gn];
#pragma unroll
        for (int m = 0; m < 4; ++m) {
#pragma unroll
            for (int i = 0; i < 4; ++i) {
                int gm = m0 + wm*64 + m*16 + l4*4 + i;
                float v = acc[m][n][i] + bn;
                if (RES) v += bflo((unsigned)res[(size_t)gm * D_ + gn]);
                if (RELU) v = fmaxf(v, 0.f);
                if (OM == 0) {
                    Cout[(size_t)gm * D_ + gn] = f2bf(v);
                } else if (OM == 1) {
                    int b = gm / 200, tt = gm - b * 200;
                    Cout[((size_t)b * TP_ + tt) * D_ + gn] = f2bf(v);
                } else {
                    int b = gm / 200, tt = gm - b * 200;
                    int hh = gn >> 6, dk = gn & 63;
                    Cout[(((size_t)b * H_ + hh) * 64 + dk) * VTP_ + tt] = f2bf(v);
                }
            }
        }
    }
}

// ---------------- MFMA attention: 1 wave per (qt,h,b), no LDS, online softmax,
// XCD-swizzled 1D grid (13312 = 8 x 1664) so one batch's 52 blocks share an XCD L2.
template<bool DEC>
__global__ __launch_bounds__(64) void attn_mfma(
    const unsigned short* __restrict__ qbf,   // [b][208][256]
    const unsigned short* __restrict__ kbf,   // [b][208][256]
    const unsigned short* __restrict__ vtbf,  // [b*4+h][64][224]
    const float* __restrict__ cm,
    unsigned short* __restrict__ obf) {       // [bt][256]
    int o = ((blockIdx.x & 7) * 1664) + (blockIdx.x >> 3);
    int b = o / 52;
    int r = o - b * 52;
    int h = r / 13;
    int qt = r - h * 13;
    int lane = threadIdx.x;
    int l15 = lane & 15, l4 = lane >> 4;
    int q0 = qt * 16;
    int qr = q0 + l15;                         // this lane's softmax row
    const f32x4 zero = {0.f, 0.f, 0.f, 0.f};

    size_t qkb = ((size_t)b * TP_) * D_ + h * 64;
    const unsigned short* qp = qbf + qkb + (size_t)(q0 + l15) * D_ + l4 * 8;
    bf16x8 bq0 = *(const bf16x8*)qp;
    bf16x8 bq1 = *(const bf16x8*)(qp + 32);

    size_t vbase = ((size_t)(b * H_ + h)) * 64 * VTP_;
    int sA = l15 + ((l4 & 1) << 5);
    int sB = sA + 16;
    bool lo4 = (l4 < 2);

    float m = -3e38f, l = 0.f;
    f32x4 O[4] = {zero, zero, zero, zero};

    int npair = (qt >> 1) + 1;
    for (int p = 0; p < npair; ++p) {
        int kt0 = 2 * p;
        bool hasOdd = (kt0 + 1 <= qt);

        f32x4 sv0, sv1;
        {
            const unsigned short* kp = kbf + qkb + (size_t)(kt0 * 16 + l15) * D_ + l4 * 8;
            bf16x8 ak0 = *(const bf16x8*)kp;
            bf16x8 ak1 = *(const bf16x8*)(kp + 32);
            f32x4 acc = __builtin_amdgcn_mfma_f32_16x16x32_bf16(ak0, bq0, zero, 0, 0, 0);
            acc = __builtin_amdgcn_mfma_f32_16x16x32_bf16(ak1, bq1, acc, 0, 0, 0);
#pragma unroll
            for (int i = 0; i < 4; ++i) {
                int kk = kt0 * 16 + l4 * 4 + i;
                float s = acc[i] * 0.125f;
                bool vld = (qr < T_) && (kk < T_);
                float cmv = (DEC && vld) ? cm[((size_t)(b * T_) + kk) * T_ + qr] : 0.f;
                if (!vld) s = -1e9f;
                else {
                    if (kk > qr) s = -1e9f;   // mask BEFORE cm multiply (as reference)
                    if (DEC) s *= (1.0f + 0.5f * cmv);
                }
                sv0[i] = s;
            }
        }
        if (hasOdd) {
            const unsigned short* kp = kbf + qkb + (size_t)((kt0 + 1) * 16 + l15) * D_ + l4 * 8;
            bf16x8 ak0 = *(const bf16x8*)kp;
            bf16x8 ak1 = *(const bf16x8*)(kp + 32);
            f32x4 acc = __builtin_amdgcn_mfma_f32_16x16x32_bf16(ak0, bq0, zero, 0, 0, 0);
            acc = __builtin_amdgcn_mfma_f32_16x16x32_bf16(ak1, bq1, acc, 0, 0, 0);
#pragma unroll
            for (int i = 0; i < 4; ++i) {
                int kk = (kt0 + 1) * 16 + l4 * 4 + i;
                float s = acc[i] * 0.125f;
                bool vld = (qr < T_) && (kk < T_);
                float cmv = (DEC && vld) ? cm[((size_t)(b * T_) + kk) * T_ + qr] : 0.f;
                if (!vld) s = -1e9f;
                else {
                    if (kk > qr) s = -1e9f;
                    if (DEC) s *= (1.0f + 0.5f * cmv);
                }
                sv1[i] = s;
            }
        }

        float tm = fmaxf(fmaxf(sv0[0], sv0[1]), fmaxf(sv0[2], sv0[3]));
        if (hasOdd) {
            float tm1 = fmaxf(fmaxf(sv1[0], sv1[1]), fmaxf(sv1[2], sv1[3]));
            tm = fmaxf(tm, tm1);
        }
        tm = fmaxf(tm, __shfl_xor(tm, 16));
        tm = fmaxf(tm, __shfl_xor(tm, 32));
        float m_new = fmaxf(m, tm);
        float sc = __expf(m - m_new);
        m = m_new;
        l *= sc;
#pragma unroll
        for (int i = 0; i < 4; ++i) {
            float osc = __shfl(sc, l4 * 4 + i);
#pragma unroll
            for (int dt = 0; dt < 4; ++dt) O[dt][i] *= osc;
        }

        float p0[4], p1[4];
#pragma unroll
        for (int i = 0; i < 4; ++i) {
            p0[i] = __expf(sv0[i] - m);
            l += p0[i];
        }
        if (hasOdd) {
#pragma unroll
            for (int i = 0; i < 4; ++i) {
                p1[i] = __expf(sv1[i] - m);
                l += p1[i];
            }
        } else {
#pragma unroll
            for (int i = 0; i < 4; ++i) p1[i] = 0.f;
        }

        unsigned pk0a = pk2(p0[0], p0[1]), pk0b = pk2(p0[2], p0[3]);
        unsigned pk1a = pk2(p1[0], p1[1]), pk1b = pk2(p1[2], p1[3]);
        unsigned e0 = (unsigned)__shfl((int)pk0a, sA);
        unsigned e1 = (unsigned)__shfl((int)pk0b, sA);
        unsigned e2 = (unsigned)__shfl((int)pk0a, sB);
        unsigned e3 = (unsigned)__shfl((int)pk0b, sB);
        unsigned o0 = (unsigned)__shfl((int)pk1a, sA);
        unsigned o1 = (unsigned)__shfl((int)pk1b, sA);
        unsigned o2 = (unsigned)__shfl((int)pk1a, sB);
        unsigned o3 = (unsigned)__shfl((int)pk1b, sB);
        frag8 pa;
        pa.u[0] = lo4 ? e0 : o0;
        pa.u[1] = lo4 ? e1 : o1;
        pa.u[2] = lo4 ? e2 : o2;
        pa.u[3] = lo4 ? e3 : o3;

#pragma unroll
        for (int dt = 0; dt < 4; ++dt) {
            bf16x8 vf = *(const bf16x8*)&vtbf[vbase + (size_t)(dt * 16 + l15) * VTP_ + p * 32 + l4 * 8];
            O[dt] = __builtin_amdgcn_mfma_f32_16x16x32_bf16(pa.v, vf, O[dt], 0, 0, 0);
        }
    }

    float L = l;
    L += __shfl_xor(L, 16);
    L += __shfl_xor(L, 32);
    float inv = 1.f / L;
#pragma unroll
    for (int i = 0; i < 4; ++i) {
        float oin = __shfl(inv, l4 * 4 + i);
        int qrow = q0 + l4 * 4 + i;
        if (qrow < T_) {
#pragma unroll
            for (int dt = 0; dt < 4; ++dt)
                obf[((size_t)(b * T_) + qrow) * D_ + h * 64 + dt * 16 + l15] = f2bf(O[dt][i]*oin);
        }
    }
}

// ---------------- cov (bf16 Z in) ----------------
__global__ void rowmean_kernel(const unsigned short* __restrict__ Z, float* __restrict__ m) {
    int row = blockIdx.x, lane = threadIdx.x;
    i32x2 xv = ((const i32x2*)(Z + (size_t)row * D_))[lane];
    float s = wave_sum(bflo((unsigned)xv[0]) + bfhi((unsigned)xv[0]) +
                       bflo((unsigned)xv[1]) + bfhi((unsigned)xv[1]));
    if (lane == 0) m[row] = s * (1.f / D_);
}

__global__ __launch_bounds__(512) void cov_mfma(const unsigned short* __restrict__ Z,
                                                const float* __restrict__ rm,
                                                float* __restrict__ cm) {
    __shared__ unsigned short Zb[208 * ZS_];
    int b = blockIdx.x;
    int tid = threadIdx.x, lane = tid & 63, wv = tid >> 6;
    int l15 = lane & 15, l4 = lane >> 4;

    for (int i = tid; i < T_ * 64; i += 512) {
        int t = i >> 6, c4 = (i & 63) << 2;
        i32x2 z = *(const i32x2*)(Z + ((size_t)b * T_ + t) * D_ + c4);
        float m = rm[b * T_ + t];
        unsigned* p = (unsigned*)&Zb[t * ZS_ + c4];
        p[0] = pk2(bflo((unsigned)z[0]) - m, bfhi((unsigned)z[0]) - m);
        p[1] = pk2(bflo((unsigned)z[1]) - m, bfhi((unsigned)z[1]) - m);
    }
    for (int i = tid; i < 8 * ZS_; i += 512) Zb[T_ * ZS_ + i] = 0;
    __syncthreads();

    for (int job = wv; job < 91; job += 8) {
        int ti = 0;
        while ((ti + 1) * (ti + 2) / 2 <= job) ++ti;
        int tj = job - ti * (ti + 1) / 2;
        f32x4 acc = {0.f, 0.f, 0.f, 0.f};
#pragma unroll
        for (int s = 0; s < 8; ++s) {
            bf16x8 a  = *(const bf16x8*)&Zb[(ti * 16 + l15) * ZS_ + s * 32 + l4 * 8];
            bf16x8 bb = *(const bf16x8*)&Zb[(tj * 16 + l15) * ZS_ + s * 32 + l4 * 8];
            acc = __builtin_amdgcn_mfma_f32_16x16x32_bf16(a, bb, acc, 0, 0, 0);
        }
#pragma unroll
        for (int i = 0; i < 4; ++i) {
            int t = ti * 16 + l4 * 4 + i, s2 = tj * 16 + l15;
            float vv = fminf(acc[i] * (1.f / 255.f), 3.0f);
            if (t < T_ && s2 < T_) {
                cm[((size_t)b * T_ + t) * T_ + s2] = vv;
                cm[((size_t)b * T_ + s2) * T_ + t] = vv;
            }
        }
    }
}

extern "C" void kernel_launch(void* const* d_in, const int* in_sizes, int n_in,
                              void* d_out, int out_size, void* d_ws, size_t ws_size,
                              hipStream_t stream) {
    const int*   log_seqs = (const int*)  d_in[0];
    const float* item_tab = (const float*)d_in[1];
    const float* pos_tab  = (const float*)d_in[2];
    const float* ln1_s = (const float*)d_in[3];
    const float* ln1_b = (const float*)d_in[4];
    const float* Wq = (const float*)d_in[5];
    const float* bq = (const float*)d_in[6];
    const float* Wk = (const float*)d_in[7];
    const float* bk = (const float*)d_in[8];
    const float* Wv = (const float*)d_in[9];
    const float* bv = (const float*)d_in[10];
    const float* Wo = (const float*)d_in[11];
    const float* bo = (const float*)d_in[12];
    const float* ln2_s = (const float*)d_in[13];
    const float* ln2_b = (const float*)d_in[14];
    const float* W1 = (const float*)d_in[15];
    const float* b1 = (const float*)d_in[16];
    const float* W2 = (const float*)d_in[17];
    const float* b2 = (const float*)d_in[18];
    const float* last_s = (const float*)d_in[19];
    const float* last_b = (const float*)d_in[20];

    const size_t NTD = (size_t)BT_ * D_;
    float* cmask = (float*)d_ws;                               // B*T*T fp32
    float* rmean = cmask + (size_t)B_ * T_ * T_;               // BT_
    unsigned short* act = (unsigned short*)(rmean + BT_);
    unsigned short* s0   = act;              // seqs / layer-3 out
    unsigned short* s1   = s0 + NTD;         // causal_z / layer-2 out
    unsigned short* Qn   = s1 + NTD;         // ln1 out, then s (in-place)
    unsigned short* yb   = Qn + NTD;         // ln2 out
    unsigned short* vb   = yb + NTD;         // obf, then ffn tmp
    unsigned short* qbf  = vb + NTD;                         // [B][208][256]
    unsigned short* kbf  = qbf + (size_t)B_ * TP_ * D_;      // [B][208][256]
    unsigned short* vtbf = kbf + (size_t)B_ * TP_ * D_;      // [B*H][64][224]
    unsigned short* wtb  = vtbf + (size_t)B_ * H_ * 64 * VTP_;

    unsigned short* wtq = wtb;
    unsigned short* wtk = wtb + 4 * (size_t)DD_;
    unsigned short* wtv = wtb + 8 * (size_t)DD_;
    unsigned short* wto = wtb + 12 * (size_t)DD_;
    unsigned short* wt1 = wtb + 16 * (size_t)DD_;
    unsigned short* wt2 = wtb + 20 * (size_t)DD_;

    dim3 tg(4, 4, 4);
    wtrans_kernel<<<tg, 256, 0, stream>>>(Wq, wtq);
    wtrans_kernel<<<tg, 256, 0, stream>>>(Wk, wtk);
    wtrans_kernel<<<tg, 256, 0, stream>>>(Wv, wtv);
    wtrans_kernel<<<tg, 256, 0, stream>>>(Wo, wto);
    wtrans_kernel<<<tg, 256, 0, stream>>>(W1, wt1);
    wtrans_kernel<<<tg, 256, 0, stream>>>(W2, wt2);
    vtpad_kernel<<<B_ * H_ * 64, 32, 0, stream>>>(vtbf);

    dim3 gg(2, 400);   // N/128, M/128

    auto encoder = [&](const unsigned short* X, unsigned short* OUT, int i, const float* cmp) {
        ln_kernel<false><<<BT_/4, 256, 0, stream>>>(X, ln1_s + i*D_, ln1_b + i*D_, Qn);
        gemm_mfma<1,false,false><<<gg, 256, 0, stream>>>(Qn, wtq + (size_t)i*DD_, bq + i*D_, nullptr, qbf);
        gemm_mfma<1,false,false><<<gg, 256, 0, stream>>>(X,  wtk + (size_t)i*DD_, bk + i*D_, nullptr, kbf);
        gemm_mfma<2,false,false><<<gg, 256, 0, stream>>>(X,  wtv + (size_t)i*DD_, bv + i*D_, nullptr, vtbf);
        if (cmp) attn_mfma<true ><<<13312, 64, 0, stream>>>(qbf, kbf, vtbf, cmp, vb);
        else     attn_mfma<false><<<13312, 64, 0, stream>>>(qbf, kbf, vtbf, nullptr, vb);
        // s = Qn + vb @ Wo + bo  (in-place into Qn; element-exclusive)
        gemm_mfma<0,false,true><<<gg, 256, 0, stream>>>(vb, wto + (size_t)i*DD_, bo + i*D_, Qn, Qn);
        ln_kernel<false><<<BT_/4, 256, 0, stream>>>(Qn, ln2_s + i*D_, ln2_b + i*D_, yb);
        gemm_mfma<0,true,false><<<gg, 256, 0, stream>>>(yb, wt1 + (size_t)i*DD_, b1 + i*D_, nullptr, vb);
        gemm_mfma<0,false,true><<<gg, 256, 0, stream>>>(vb, wt2 + (size_t)i*DD_, b2 + i*D_, yb, OUT);
    };

    embed_kernel<<<BT_, 64, 0, stream>>>(log_seqs, item_tab, pos_tab, s0);

    // causal loop applies each layer to ORIGINAL seqs -> only layer 1 survives
    encoder(s0, s1, 1, nullptr);

    rowmean_kernel<<<BT_, 64, 0, stream>>>(s1, rmean);
    cov_mfma<<<B_, 512, 0, stream>>>(s1, rmean, cmask);

    encoder(s0, s1, 2, cmask);
    encoder(s1, s0, 3, cmask);

    ln_kernel<true><<<BT_/4, 256, 0, stream>>>(s0, last_s, last_b, (float*)d_out);
}

// Round 12
// 1021.868 us; speedup vs baseline: 2.3295x; 1.1102x over previous
//
#include <hip/hip_runtime.h>
#include <hip/hip_bf16.h>

#define B_ 256
#define T_ 200
#define D_ 256
#define H_ 4
#define BT_ (B_*T_)
#define DD_ (D_*D_)
#define GS_ 72     // gemm LDS stride (64 + 8 pad)
#define TP_ 208    // padded token rows per batch for qbf/kbf
#define VTP_ 224   // vtbf row length (7*32)
#define ZS_ 264    // cov Zb stride
#define FS_ 264    // ffn Alds/Tlds stride (256 + 8)

typedef __attribute__((ext_vector_type(4))) float  f32x4;
typedef __attribute__((ext_vector_type(8))) __bf16 bf16x8;
typedef __attribute__((ext_vector_type(4))) int    i32x4;
typedef __attribute__((ext_vector_type(2))) int    i32x2;

union frag8 { unsigned u[4]; bf16x8 v; };

__device__ __forceinline__ unsigned short f2bf(float f) {
    unsigned u = __float_as_uint(f);
    u += 0x7FFFu + ((u >> 16) & 1u);          // RNE to bf16
    return (unsigned short)(u >> 16);
}
__device__ __forceinline__ unsigned pk2(float lo, float hi) {
    return (unsigned)f2bf(lo) | ((unsigned)f2bf(hi) << 16);
}
__device__ __forceinline__ float bflo(unsigned u) { return __uint_as_float(u << 16); }
__device__ __forceinline__ float bfhi(unsigned u) { return __uint_as_float(u & 0xFFFF0000u); }

__device__ __forceinline__ float wave_sum(float v) {
#pragma unroll
    for (int o = 32; o >= 1; o >>= 1) v += __shfl_xor(v, o);
    return v;
}

// ---------------- embed (bf16 out) ----------------
__global__ void embed_kernel(const int* __restrict__ ls,
                             const float* __restrict__ itab,
                             const float* __restrict__ ptab,
                             unsigned short* __restrict__ seqs) {
    int bt = blockIdx.x;
    int t = bt % T_;
    int lane = threadIdx.x;
    int idx = ls[bt];
    int pos = idx ? (t + 1) : 0;
    float4 a = ((const float4*)(itab + (size_t)idx * D_))[lane];
    float4 p = ((const float4*)(ptab + (size_t)pos * D_))[lane];
    i32x2 r;
    r[0] = (int)pk2(a.x*16.f+p.x, a.y*16.f+p.y);
    r[1] = (int)pk2(a.z*16.f+p.z, a.w*16.f+p.w);
    ((i32x2*)(seqs + (size_t)bt * D_))[lane] = r;
}

// ---------------- layernorm (bf16 in; bf16 or fp32 out), 4 rows/block ----------------
template<bool F32OUT>
__global__ __launch_bounds__(256) void ln_kernel(const unsigned short* __restrict__ X,
                                                 const float* __restrict__ sc,
                                                 const float* __restrict__ bi,
                                                 void* __restrict__ Y) {
    int row = blockIdx.x * 4 + (threadIdx.x >> 6);
    int lane = threadIdx.x & 63;
    i32x2 xv = ((const i32x2*)(X + (size_t)row * D_))[lane];
    float x0 = bflo((unsigned)xv[0]), x1 = bfhi((unsigned)xv[0]);
    float x2 = bflo((unsigned)xv[1]), x3 = bfhi((unsigned)xv[1]);
    float m = wave_sum(x0 + x1 + x2 + x3) * (1.f / D_);
    float d0 = x0 - m, d1 = x1 - m, d2 = x2 - m, d3 = x3 - m;
    float v = wave_sum(d0*d0 + d1*d1 + d2*d2 + d3*d3) * (1.f / D_);
    float inv = rsqrtf(v + 1e-8f);
    float4 s4 = ((const float4*)sc)[lane];
    float4 b4 = ((const float4*)bi)[lane];
    float r0 = d0*inv*s4.x + b4.x, r1 = d1*inv*s4.y + b4.y;
    float r2 = d2*inv*s4.z + b4.z, r3 = d3*inv*s4.w + b4.w;
    if (F32OUT) {
        float4 r = {r0, r1, r2, r3};
        ((float4*)Y)[(size_t)row * (D_/4) + lane] = r;
    } else {
        i32x2 r;
        r[0] = (int)pk2(r0, r1);
        r[1] = (int)pk2(r2, r3);
        ((i32x2*)Y)[(size_t)row * (D_/4) + lane] = r;   // i32x2 = 4 bf16
    }
}

// ---------------- weight transpose: Wt[n][k] = bf16(W[k][n]) ----------------
__global__ __launch_bounds__(256) void wtrans_kernel(const float* __restrict__ W,
                                                     unsigned short* __restrict__ Wt) {
    __shared__ float tile[64][65];
    int c0 = blockIdx.x * 64, r0 = blockIdx.y * 64, l = blockIdx.z;
    const float* src = W + (size_t)l * DD_;
    unsigned short* dst = Wt + (size_t)l * DD_;
    int tid = threadIdx.x;
#pragma unroll
    for (int rep = 0; rep < 16; ++rep) {
        int idx = rep * 256 + tid;
        int r = idx >> 6, c = idx & 63;
        tile[r][c] = src[(size_t)(r0 + r) * D_ + c0 + c];
    }
    __syncthreads();
#pragma unroll
    for (int rep = 0; rep < 16; ++rep) {
        int idx = rep * 256 + tid;
        int r2 = idx >> 6, c2 = idx & 63;
        dst[(size_t)(c0 + r2) * D_ + r0 + c2] = f2bf(tile[c2][r2]);
    }
}

// zero vtbf pad cols [200,224)
__global__ void vtpad_kernel(unsigned short* __restrict__ vt) {
    if (threadIdx.x < VTP_ - T_)
        vt[(size_t)blockIdx.x * VTP_ + T_ + threadIdx.x] = 0;
}

// ---------------- MFMA GEMM (single-output; used for Q and Wo) ----------------
// OM: 0 = bf16 flat [m][256]; 1 = bf16 padded [b][208][256].
template<int OM, bool RES>
__global__ __launch_bounds__(256) void gemm_mfma(
    const unsigned short* __restrict__ A, const unsigned short* __restrict__ Wt,
    const float* __restrict__ bias, const unsigned short* res,
    unsigned short* Cout) {
    __shared__ unsigned short As[128 * GS_];
    __shared__ unsigned short Ws[128 * GS_];
    int t = threadIdx.x, lane = t & 63, wv = t >> 6;
    int wm = wv >> 1, wn = wv & 1;
    int l15 = lane & 15, l4 = lane >> 4;
    int m0 = blockIdx.y * 128, n0 = blockIdx.x * 128;

    f32x4 acc[4][4];
#pragma unroll
    for (int m = 0; m < 4; ++m)
#pragma unroll
        for (int n = 0; n < 4; ++n)
            acc[m][n] = f32x4{0.f, 0.f, 0.f, 0.f};

    for (int k0 = 0; k0 < D_; k0 += 64) {
#pragma unroll
        for (int rep = 0; rep < 4; ++rep) {
            int idx = rep * 256 + t;
            int r = idx >> 3, c8 = (idx & 7) * 8;
            *(i32x4*)&As[r * GS_ + c8] =
                *(const i32x4*)(A + (size_t)(m0 + r) * D_ + k0 + c8);
        }
#pragma unroll
        for (int rep = 0; rep < 4; ++rep) {
            int idx = rep * 256 + t;
            int r = idx >> 3, c8 = (idx & 7) * 8;
            *(i32x4*)&Ws[r * GS_ + c8] =
                *(const i32x4*)(Wt + (size_t)(n0 + r) * D_ + k0 + c8);
        }
        __syncthreads();
#pragma unroll
        for (int kk = 0; kk < 2; ++kk) {
            bf16x8 af[4], bf[4];
#pragma unroll
            for (int m = 0; m < 4; ++m)
                af[m] = *(const bf16x8*)&As[(wm*64 + m*16 + l15) * GS_ + kk*32 + l4*8];
#pragma unroll
            for (int n = 0; n < 4; ++n)
                bf[n] = *(const bf16x8*)&Ws[(wn*64 + n*16 + l15) * GS_ + kk*32 + l4*8];
#pragma unroll
            for (int m = 0; m < 4; ++m)
#pragma unroll
                for (int n = 0; n < 4; ++n)
                    acc[m][n] = __builtin_amdgcn_mfma_f32_16x16x32_bf16(af[m], bf[n], acc[m][n], 0, 0, 0);
        }
        __syncthreads();
    }
#pragma unroll
    for (int n = 0; n < 4; ++n) {
        int gn = n0 + wn*64 + n*16 + l15;
        float bn = bias[gn];
#pragma unroll
        for (int m = 0; m < 4; ++m) {
#pragma unroll
            for (int i = 0; i < 4; ++i) {
                int gm = m0 + wm*64 + m*16 + l4*4 + i;
                float v = acc[m][n][i] + bn;
                if (RES) v += bflo((unsigned)res[(size_t)gm * D_ + gn]);
                if (OM == 0) {
                    Cout[(size_t)gm * D_ + gn] = f2bf(v);
                } else {
                    int b = gm / 200, tt = gm - b * 200;
                    Cout[((size_t)b * TP_ + tt) * D_ + gn] = f2bf(v);
                }
            }
        }
    }
}

// ---------------- fused K+V GEMM: stages A once, two outputs ----------------
__global__ __launch_bounds__(256) void gemm_kv(
    const unsigned short* __restrict__ A,
    const unsigned short* __restrict__ WtK, const unsigned short* __restrict__ WtV,
    const float* __restrict__ biasK, const float* __restrict__ biasV,
    unsigned short* __restrict__ kbf, unsigned short* __restrict__ vtbf) {
    __shared__ unsigned short As[128 * GS_];
    __shared__ unsigned short WsK[128 * GS_];
    __shared__ unsigned short WsV[128 * GS_];
    int t = threadIdx.x, lane = t & 63, wv = t >> 6;
    int wm = wv >> 1, wn = wv & 1;
    int l15 = lane & 15, l4 = lane >> 4;
    int m0 = blockIdx.y * 128, n0 = blockIdx.x * 128;

    f32x4 accK[4][4], accV[4][4];
#pragma unroll
    for (int m = 0; m < 4; ++m)
#pragma unroll
        for (int n = 0; n < 4; ++n) {
            accK[m][n] = f32x4{0.f, 0.f, 0.f, 0.f};
            accV[m][n] = f32x4{0.f, 0.f, 0.f, 0.f};
        }

    for (int k0 = 0; k0 < D_; k0 += 64) {
#pragma unroll
        for (int rep = 0; rep < 4; ++rep) {
            int idx = rep * 256 + t;
            int r = idx >> 3, c8 = (idx & 7) * 8;
            *(i32x4*)&As[r * GS_ + c8]  = *(const i32x4*)(A   + (size_t)(m0 + r) * D_ + k0 + c8);
            *(i32x4*)&WsK[r * GS_ + c8] = *(const i32x4*)(WtK + (size_t)(n0 + r) * D_ + k0 + c8);
            *(i32x4*)&WsV[r * GS_ + c8] = *(const i32x4*)(WtV + (size_t)(n0 + r) * D_ + k0 + c8);
        }
        __syncthreads();
#pragma unroll
        for (int kk = 0; kk < 2; ++kk) {
            bf16x8 af[4];
#pragma unroll
            for (int m = 0; m < 4; ++m)
                af[m] = *(const bf16x8*)&As[(wm*64 + m*16 + l15) * GS_ + kk*32 + l4*8];
#pragma unroll
            for (int n = 0; n < 4; ++n) {
                bf16x8 bk8 = *(const bf16x8*)&WsK[(wn*64 + n*16 + l15) * GS_ + kk*32 + l4*8];
                bf16x8 bv8 = *(const bf16x8*)&WsV[(wn*64 + n*16 + l15) * GS_ + kk*32 + l4*8];
#pragma unroll
                for (int m = 0; m < 4; ++m) {
                    accK[m][n] = __builtin_amdgcn_mfma_f32_16x16x32_bf16(af[m], bk8, accK[m][n], 0, 0, 0);
                    accV[m][n] = __builtin_amdgcn_mfma_f32_16x16x32_bf16(af[m], bv8, accV[m][n], 0, 0, 0);
                }
            }
        }
        __syncthreads();
    }
#pragma unroll
    for (int n = 0; n < 4; ++n) {
        int gn = n0 + wn*64 + n*16 + l15;
        float bnK = biasK[gn], bnV = biasV[gn];
        int hh = gn >> 6, dk = gn & 63;
#pragma unroll
        for (int m = 0; m < 4; ++m) {
#pragma unroll
            for (int i = 0; i < 4; ++i) {
                int gm = m0 + wm*64 + m*16 + l4*4 + i;
                int b = gm / 200, tt = gm - b * 200;
                kbf[((size_t)b * TP_ + tt) * D_ + gn] = f2bf(accK[m][n][i] + bnK);
                vtbf[(((size_t)b * H_ + hh) * 64 + dk) * VTP_ + tt] = f2bf(accV[m][n][i] + bnV);
            }
        }
    }
}

// ---------------- fused FFN: LN2 + relu(y@W1+b1)@W2 + b2 + y ----------------
// 64-row blocks; y (LN output) and tmp live in LDS; weights staged per K-chunk.
__global__ __launch_bounds__(256) void ffn_fused(
    const unsigned short* __restrict__ S,
    const float* __restrict__ ln_s, const float* __restrict__ ln_b,
    const unsigned short* __restrict__ Wt1, const float* __restrict__ b1,
    const unsigned short* __restrict__ Wt2, const float* __restrict__ b2,
    unsigned short* __restrict__ OUT) {
    __shared__ unsigned short Alds[64 * FS_];   // y = LN2(s)
    __shared__ unsigned short Tlds[64 * FS_];   // tmp = relu(y@W1+b1)
    __shared__ unsigned short Ws[256 * GS_];    // weight chunk [256 n][64 k]
    int t = threadIdx.x, lane = t & 63, wv = t >> 6;
    int l15 = lane & 15, l4 = lane >> 4;
    int m0 = blockIdx.x * 64;

    // ---- phase 0: LN of 64 rows (4 threads/row x 64 cols each; i32x4 = 8 bf16) ----
    {
        int r = t >> 2, c = (t & 3) * 64;
        const unsigned short* src = S + (size_t)(m0 + r) * D_ + c;
        i32x4 buf[8];
#pragma unroll
        for (int j = 0; j < 8; ++j) buf[j] = ((const i32x4*)src)[j];
        float sum = 0.f;
#pragma unroll
        for (int j = 0; j < 8; ++j)
#pragma unroll
            for (int q = 0; q < 4; ++q)
                sum += bflo((unsigned)buf[j][q]) + bfhi((unsigned)buf[j][q]);
        sum += __shfl_xor(sum, 1);
        sum += __shfl_xor(sum, 2);
        float mean = sum * (1.f / D_);
        float var = 0.f;
#pragma unroll
        for (int j = 0; j < 8; ++j)
#pragma unroll
            for (int q = 0; q < 4; ++q) {
                float a0 = bflo((unsigned)buf[j][q]) - mean;
                float a1 = bfhi((unsigned)buf[j][q]) - mean;
                var += a0*a0 + a1*a1;
            }
        var += __shfl_xor(var, 1);
        var += __shfl_xor(var, 2);
        float inv = rsqrtf(var * (1.f / D_) + 1e-8f);
#pragma unroll
        for (int j = 0; j < 8; ++j) {
            int cc = c + j * 8;
            float4 sa = *(const float4*)&ln_s[cc];
            float4 sb = *(const float4*)&ln_s[cc + 4];
            float4 ba = *(const float4*)&ln_b[cc];
            float4 bb = *(const float4*)&ln_b[cc + 4];
            float y0 = (bflo((unsigned)buf[j][0]) - mean) * inv * sa.x + ba.x;
            float y1 = (bfhi((unsigned)buf[j][0]) - mean) * inv * sa.y + ba.y;
            float y2 = (bflo((unsigned)buf[j][1]) - mean) * inv * sa.z + ba.z;
            float y3 = (bfhi((unsigned)buf[j][1]) - mean) * inv * sa.w + ba.w;
            float y4 = (bflo((unsigned)buf[j][2]) - mean) * inv * sb.x + bb.x;
            float y5 = (bfhi((unsigned)buf[j][2]) - mean) * inv * sb.y + bb.y;
            float y6 = (bflo((unsigned)buf[j][3]) - mean) * inv * sb.z + bb.z;
            float y7 = (bfhi((unsigned)buf[j][3]) - mean) * inv * sb.w + bb.w;
            i32x4 w;
            w[0] = (int)pk2(y0, y1);
            w[1] = (int)pk2(y2, y3);
            w[2] = (int)pk2(y4, y5);
            w[3] = (int)pk2(y6, y7);
            *(i32x4*)&Alds[r * FS_ + cc] = w;
        }
    }
    __syncthreads();

    // ---- phase 1: tmp = relu(y @ W1 + b1) ----
    f32x4 acc[4][4];
#pragma unroll
    for (int m = 0; m < 4; ++m)
#pragma unroll
        for (int n = 0; n < 4; ++n)
            acc[m][n] = f32x4{0.f, 0.f, 0.f, 0.f};
    for (int k0 = 0; k0 < D_; k0 += 64) {
#pragma unroll
        for (int rep = 0; rep < 8; ++rep) {
            int idx = rep * 256 + t;
            int rr = idx >> 3, c8 = (idx & 7) * 8;
            *(i32x4*)&Ws[rr * GS_ + c8] = *(const i32x4*)(Wt1 + (size_t)rr * D_ + k0 + c8);
        }
        __syncthreads();
#pragma unroll
        for (int kk = 0; kk < 2; ++kk) {
            bf16x8 af[4], bf[4];
#pragma unroll
            for (int m = 0; m < 4; ++m)
                af[m] = *(const bf16x8*)&Alds[(m*16 + l15) * FS_ + k0 + kk*32 + l4*8];
#pragma unroll
            for (int n = 0; n < 4; ++n)
                bf[n] = *(const bf16x8*)&Ws[(wv*64 + n*16 + l15) * GS_ + kk*32 + l4*8];
#pragma unroll
            for (int m = 0; m < 4; ++m)
#pragma unroll
                for (int n = 0; n < 4; ++n)
                    acc[m][n] = __builtin_amdgcn_mfma_f32_16x16x32_bf16(af[m], bf[n], acc[m][n], 0, 0, 0);
        }
        __syncthreads();
    }
#pragma unroll
    for (int n = 0; n < 4; ++n) {
        int gn = wv*64 + n*16 + l15;
        float bn = b1[gn];
#pragma unroll
        for (int m = 0; m < 4; ++m)
#pragma unroll
            for (int i = 0; i < 4; ++i)
                Tlds[(m*16 + l4*4 + i) * FS_ + gn] = f2bf(fmaxf(acc[m][n][i] + bn, 0.f));
    }
    __syncthreads();

    // ---- phase 2: OUT = tmp @ W2 + b2 + y ----
#pragma unroll
    for (int m = 0; m < 4; ++m)
#pragma unroll
        for (int n = 0; n < 4; ++n)
            acc[m][n] = f32x4{0.f, 0.f, 0.f, 0.f};
    for (int k0 = 0; k0 < D_; k0 += 64) {
#pragma unroll
        for (int rep = 0; rep < 8; ++rep) {
            int idx = rep * 256 + t;
            int rr = idx >> 3, c8 = (idx & 7) * 8;
            *(i32x4*)&Ws[rr * GS_ + c8] = *(const i32x4*)(Wt2 + (size_t)rr * D_ + k0 + c8);
        }
        __syncthreads();
#pragma unroll
        for (int kk = 0; kk < 2; ++kk) {
            bf16x8 af[4], bf[4];
#pragma unroll
            for (int m = 0; m < 4; ++m)
                af[m] = *(const bf16x8*)&Tlds[(m*16 + l15) * FS_ + k0 + kk*32 + l4*8];
#pragma unroll
            for (int n = 0; n < 4; ++n)
                bf[n] = *(const bf16x8*)&Ws[(wv*64 + n*16 + l15) * GS_ + kk*32 + l4*8];
#pragma unroll
            for (int m = 0; m < 4; ++m)
#pragma unroll
                for (int n = 0; n < 4; ++n)
                    acc[m][n] = __builtin_amdgcn_mfma_f32_16x16x32_bf16(af[m], bf[n], acc[m][n], 0, 0, 0);
        }
        __syncthreads();
    }
#pragma unroll
    for (int n = 0; n < 4; ++n) {
        int gn = wv*64 + n*16 + l15;
        float bn = b2[gn];
#pragma unroll
        for (int m = 0; m < 4; ++m) {
#pragma unroll
            for (int i = 0; i < 4; ++i) {
                int row = m*16 + l4*4 + i;
                float v = acc[m][n][i] + bn + bflo((unsigned)Alds[row * FS_ + gn]);
                OUT[(size_t)(m0 + row) * D_ + gn] = f2bf(v);
            }
        }
    }
}

// ---------------- MFMA attention: 1 wave per (qt,h,b), no LDS, online softmax,
// XCD-swizzled 1D grid (13312 = 8 x 1664); T5 setprio around MFMA clusters.
template<bool DEC>
__global__ __launch_bounds__(64) void attn_mfma(
    const unsigned short* __restrict__ qbf,   // [b][208][256]
    const unsigned short* __restrict__ kbf,   // [b][208][256]
    const unsigned short* __restrict__ vtbf,  // [b*4+h][64][224]
    const float* __restrict__ cm,
    unsigned short* __restrict__ obf) {       // [bt][256]
    int o = ((blockIdx.x & 7) * 1664) + (blockIdx.x >> 3);
    int b = o / 52;
    int r = o - b * 52;
    int h = r / 13;
    int qt = r - h * 13;
    int lane = threadIdx.x;
    int l15 = lane & 15, l4 = lane >> 4;
    int q0 = qt * 16;
    int qr = q0 + l15;
    const f32x4 zero = {0.f, 0.f, 0.f, 0.f};

    size_t qkb = ((size_t)b * TP_) * D_ + h * 64;
    const unsigned short* qp = qbf + qkb + (size_t)(q0 + l15) * D_ + l4 * 8;
    bf16x8 bq0 = *(const bf16x8*)qp;
    bf16x8 bq1 = *(const bf16x8*)(qp + 32);

    size_t vbase = ((size_t)(b * H_ + h)) * 64 * VTP_;
    int sA = l15 + ((l4 & 1) << 5);
    int sB = sA + 16;
    bool lo4 = (l4 < 2);

    float m = -3e38f, l = 0.f;
    f32x4 O[4] = {zero, zero, zero, zero};

    int npair = (qt >> 1) + 1;
    for (int p = 0; p < npair; ++p) {
        int kt0 = 2 * p;
        bool hasOdd = (kt0 + 1 <= qt);

        f32x4 sv0, sv1;
        {
            const unsigned short* kp = kbf + qkb + (size_t)(kt0 * 16 + l15) * D_ + l4 * 8;
            bf16x8 ak0 = *(const bf16x8*)kp;
            bf16x8 ak1 = *(const bf16x8*)(kp + 32);
            __builtin_amdgcn_s_setprio(1);
            f32x4 acc = __builtin_amdgcn_mfma_f32_16x16x32_bf16(ak0, bq0, zero, 0, 0, 0);
            acc = __builtin_amdgcn_mfma_f32_16x16x32_bf16(ak1, bq1, acc, 0, 0, 0);
            __builtin_amdgcn_s_setprio(0);
#pragma unroll
            for (int i = 0; i < 4; ++i) {
                int kk = kt0 * 16 + l4 * 4 + i;
                float s = acc[i] * 0.125f;
                bool vld = (qr < T_) && (kk < T_);
                float cmv = (DEC && vld) ? cm[((size_t)(b * T_) + kk) * T_ + qr] : 0.f;
                if (!vld) s = -1e9f;
                else {
                    if (kk > qr) s = -1e9f;   // mask BEFORE cm multiply (as reference)
                    if (DEC) s *= (1.0f + 0.5f * cmv);
                }
                sv0[i] = s;
            }
        }
        if (hasOdd) {
            const unsigned short* kp = kbf + qkb + (size_t)((kt0 + 1) * 16 + l15) * D_ + l4 * 8;
            bf16x8 ak0 = *(const bf16x8*)kp;
            bf16x8 ak1 = *(const bf16x8*)(kp + 32);
            __builtin_amdgcn_s_setprio(1);
            f32x4 acc = __builtin_amdgcn_mfma_f32_16x16x32_bf16(ak0, bq0, zero, 0, 0, 0);
            acc = __builtin_amdgcn_mfma_f32_16x16x32_bf16(ak1, bq1, acc, 0, 0, 0);
            __builtin_amdgcn_s_setprio(0);
#pragma unroll
            for (int i = 0; i < 4; ++i) {
                int kk = (kt0 + 1) * 16 + l4 * 4 + i;
                float s = acc[i] * 0.125f;
                bool vld = (qr < T_) && (kk < T_);
                float cmv = (DEC && vld) ? cm[((size_t)(b * T_) + kk) * T_ + qr] : 0.f;
                if (!vld) s = -1e9f;
                else {
                    if (kk > qr) s = -1e9f;
                    if (DEC) s *= (1.0f + 0.5f * cmv);
                }
                sv1[i] = s;
            }
        }

        float tm = fmaxf(fmaxf(sv0[0], sv0[1]), fmaxf(sv0[2], sv0[3]));
        if (hasOdd) {
            float tm1 = fmaxf(fmaxf(sv1[0], sv1[1]), fmaxf(sv1[2], sv1[3]));
            tm = fmaxf(tm, tm1);
        }
        tm = fmaxf(tm, __shfl_xor(tm, 16));
        tm = fmaxf(tm, __shfl_xor(tm, 32));
        float m_new = fmaxf(m, tm);
        float sc = __expf(m - m_new);
        m = m_new;
        l *= sc;
#pragma unroll
        for (int i = 0; i < 4; ++i) {
            float osc = __shfl(sc, l4 * 4 + i);
#pragma unroll
            for (int dt = 0; dt < 4; ++dt) O[dt][i] *= osc;
        }

        float p0[4], p1[4];
#pragma unroll
        for (int i = 0; i < 4; ++i) {
            p0[i] = __expf(sv0[i] - m);
            l += p0[i];
        }
        if (hasOdd) {
#pragma unroll
            for (int i = 0; i < 4; ++i) {
                p1[i] = __expf(sv1[i] - m);
                l += p1[i];
            }
        } else {
#pragma unroll
            for (int i = 0; i < 4; ++i) p1[i] = 0.f;
        }

        unsigned pk0a = pk2(p0[0], p0[1]), pk0b = pk2(p0[2], p0[3]);
        unsigned pk1a = pk2(p1[0], p1[1]), pk1b = pk2(p1[2], p1[3]);
        unsigned e0 = (unsigned)__shfl((int)pk0a, sA);
        unsigned e1 = (unsigned)__shfl((int)pk0b, sA);
        unsigned e2 = (unsigned)__shfl((int)pk0a, sB);
        unsigned e3 = (unsigned)__shfl((int)pk0b, sB);
        unsigned o0 = (unsigned)__shfl((int)pk1a, sA);
        unsigned o1 = (unsigned)__shfl((int)pk1b, sA);
        unsigned o2 = (unsigned)__shfl((int)pk1a, sB);
        unsigned o3 = (unsigned)__shfl((int)pk1b, sB);
        frag8 pa;
        pa.u[0] = lo4 ? e0 : o0;
        pa.u[1] = lo4 ? e1 : o1;
        pa.u[2] = lo4 ? e2 : o2;
        pa.u[3] = lo4 ? e3 : o3;

        __builtin_amdgcn_s_setprio(1);
#pragma unroll
        for (int dt = 0; dt < 4; ++dt) {
            bf16x8 vf = *(const bf16x8*)&vtbf[vbase + (size_t)(dt * 16 + l15) * VTP_ + p * 32 + l4 * 8];
            O[dt] = __builtin_amdgcn_mfma_f32_16x16x32_bf16(pa.v, vf, O[dt], 0, 0, 0);
        }
        __builtin_amdgcn_s_setprio(0);
    }

    float L = l;
    L += __shfl_xor(L, 16);
    L += __shfl_xor(L, 32);
    float inv = 1.f / L;
#pragma unroll
    for (int i = 0; i < 4; ++i) {
        float oin = __shfl(inv, l4 * 4 + i);
        int qrow = q0 + l4 * 4 + i;
        if (qrow < T_) {
#pragma unroll
            for (int dt = 0; dt < 4; ++dt)
                obf[((size_t)(b * T_) + qrow) * D_ + h * 64 + dt * 16 + l15] = f2bf(O[dt][i]*oin);
        }
    }
}

// ---------------- cov (bf16 Z in; row mean computed inline per wave) ----------------
__global__ __launch_bounds__(512) void cov_mfma(const unsigned short* __restrict__ Z,
                                                float* __restrict__ cm) {
    __shared__ unsigned short Zb[208 * ZS_];
    int b = blockIdx.x;
    int tid = threadIdx.x, lane = tid & 63, wv = tid >> 6;
    int l15 = lane & 15, l4 = lane >> 4;

    // each wave owns one row per iteration (64 lanes x 4 elems = 256 = D_)
    for (int i = tid; i < T_ * 64; i += 512) {
        int t = i >> 6, c4 = (i & 63) << 2;
        i32x2 z = *(const i32x2*)(Z + ((size_t)b * T_ + t) * D_ + c4);
        float z0 = bflo((unsigned)z[0]), z1 = bfhi((unsigned)z[0]);
        float z2 = bflo((unsigned)z[1]), z3 = bfhi((unsigned)z[1]);
        float mean = wave_sum(z0 + z1 + z2 + z3) * (1.f / D_);
        unsigned* p = (unsigned*)&Zb[t * ZS_ + c4];
        p[0] = pk2(z0 - mean, z1 - mean);
        p[1] = pk2(z2 - mean, z3 - mean);
    }
    for (int i = tid; i < 8 * ZS_; i += 512) Zb[T_ * ZS_ + i] = 0;
    __syncthreads();

    for (int job = wv; job < 91; job += 8) {
        int ti = 0;
        while ((ti + 1) * (ti + 2) / 2 <= job) ++ti;
        int tj = job - ti * (ti + 1) / 2;
        f32x4 acc = {0.f, 0.f, 0.f, 0.f};
#pragma unroll
        for (int s = 0; s < 8; ++s) {
            bf16x8 a  = *(const bf16x8*)&Zb[(ti * 16 + l15) * ZS_ + s * 32 + l4 * 8];
            bf16x8 bb = *(const bf16x8*)&Zb[(tj * 16 + l15) * ZS_ + s * 32 + l4 * 8];
            acc = __builtin_amdgcn_mfma_f32_16x16x32_bf16(a, bb, acc, 0, 0, 0);
        }
#pragma unroll
        for (int i = 0; i < 4; ++i) {
            int t = ti * 16 + l4 * 4 + i, s2 = tj * 16 + l15;
            float vv = fminf(acc[i] * (1.f / 255.f), 3.0f);
            if (t < T_ && s2 < T_) {
                cm[((size_t)b * T_ + t) * T_ + s2] = vv;
                cm[((size_t)b * T_ + s2) * T_ + t] = vv;
            }
        }
    }
}

extern "C" void kernel_launch(void* const* d_in, const int* in_sizes, int n_in,
                              void* d_out, int out_size, void* d_ws, size_t ws_size,
                              hipStream_t stream) {
    const int*   log_seqs = (const int*)  d_in[0];
    const float* item_tab = (const float*)d_in[1];
    const float* pos_tab  = (const float*)d_in[2];
    const float* ln1_s = (const float*)d_in[3];
    const float* ln1_b = (const float*)d_in[4];
    const float* Wq = (const float*)d_in[5];
    const float* bq = (const float*)d_in[6];
    const float* Wk = (const float*)d_in[7];
    const float* bk = (const float*)d_in[8];
    const float* Wv = (const float*)d_in[9];
    const float* bv = (const float*)d_in[10];
    const float* Wo = (const float*)d_in[11];
    const float* bo = (const float*)d_in[12];
    const float* ln2_s = (const float*)d_in[13];
    const float* ln2_b = (const float*)d_in[14];
    const float* W1 = (const float*)d_in[15];
    const float* b1 = (const float*)d_in[16];
    const float* W2 = (const float*)d_in[17];
    const float* b2 = (const float*)d_in[18];
    const float* last_s = (const float*)d_in[19];
    const float* last_b = (const float*)d_in[20];

    const size_t NTD = (size_t)BT_ * D_;
    float* cmask = (float*)d_ws;                               // B*T*T fp32
    unsigned short* act = (unsigned short*)(cmask + (size_t)B_ * T_ * T_);
    unsigned short* s0   = act;              // seqs / layer-3 out
    unsigned short* s1   = s0 + NTD;         // causal_z / layer-2 out
    unsigned short* Qn   = s1 + NTD;         // ln1 out, then s (in-place)
    unsigned short* vb   = Qn + NTD;         // obf
    unsigned short* qbf  = vb + NTD;                         // [B][208][256]
    unsigned short* kbf  = qbf + (size_t)B_ * TP_ * D_;      // [B][208][256]
    unsigned short* vtbf = kbf + (size_t)B_ * TP_ * D_;      // [B*H][64][224]
    unsigned short* wtb  = vtbf + (size_t)B_ * H_ * 64 * VTP_;

    unsigned short* wtq = wtb;
    unsigned short* wtk = wtb + 4 * (size_t)DD_;
    unsigned short* wtv = wtb + 8 * (size_t)DD_;
    unsigned short* wto = wtb + 12 * (size_t)DD_;
    unsigned short* wt1 = wtb + 16 * (size_t)DD_;
    unsigned short* wt2 = wtb + 20 * (size_t)DD_;

    dim3 tg(4, 4, 4);
    wtrans_kernel<<<tg, 256, 0, stream>>>(Wq, wtq);
    wtrans_kernel<<<tg, 256, 0, stream>>>(Wk, wtk);
    wtrans_kernel<<<tg, 256, 0, stream>>>(Wv, wtv);
    wtrans_kernel<<<tg, 256, 0, stream>>>(Wo, wto);
    wtrans_kernel<<<tg, 256, 0, stream>>>(W1, wt1);
    wtrans_kernel<<<tg, 256, 0, stream>>>(W2, wt2);
    vtpad_kernel<<<B_ * H_ * 64, 32, 0, stream>>>(vtbf);

    dim3 gg(2, 400);   // N/128, M/128

    auto encoder = [&](const unsigned short* X, unsigned short* OUT, int i, const float* cmp) {
        ln_kernel<false><<<BT_/4, 256, 0, stream>>>(X, ln1_s + i*D_, ln1_b + i*D_, Qn);
        gemm_mfma<1,false><<<gg, 256, 0, stream>>>(Qn, wtq + (size_t)i*DD_, bq + i*D_, nullptr, qbf);
        gemm_kv<<<gg, 256, 0, stream>>>(X, wtk + (size_t)i*DD_, wtv + (size_t)i*DD_,
                                        bk + i*D_, bv + i*D_, kbf, vtbf);
        if (cmp) attn_mfma<true ><<<13312, 64, 0, stream>>>(qbf, kbf, vtbf, cmp, vb);
        else     attn_mfma<false><<<13312, 64, 0, stream>>>(qbf, kbf, vtbf, nullptr, vb);
        // s = Qn + vb @ Wo + bo  (in-place into Qn; element-exclusive)
        gemm_mfma<0,true><<<gg, 256, 0, stream>>>(vb, wto + (size_t)i*DD_, bo + i*D_, Qn, Qn);
        // OUT = relu(LN2(s)@W1+b1)@W2 + b2 + LN2(s)
        ffn_fused<<<BT_/64, 256, 0, stream>>>(Qn, ln2_s + i*D_, ln2_b + i*D_,
                                              wt1 + (size_t)i*DD_, b1 + i*D_,
                                              wt2 + (size_t)i*DD_, b2 + i*D_, OUT);
    };

    embed_kernel<<<BT_, 64, 0, stream>>>(log_seqs, item_tab, pos_tab, s0);

    // causal loop applies each layer to ORIGINAL seqs -> only layer 1 survives
    encoder(s0, s1, 1, nullptr);

    cov_mfma<<<B_, 512, 0, stream>>>(s1, cmask);

    encoder(s0, s1, 2, cmask);
    encoder(s1, s0, 3, cmask);

    ln_kernel<true><<<BT_/4, 256, 0, stream>>>(s0, last_s, last_b, (float*)d_out);
}

// Round 13
// 962.438 us; speedup vs baseline: 2.4733x; 1.0617x over previous
//
#include <hip/hip_runtime.h>
#include <hip/hip_bf16.h>

#define B_ 256
#define T_ 200
#define D_ 256
#define H_ 4
#define BT_ (B_*T_)
#define DD_ (D_*D_)
#define GS_ 72     // gemm LDS stride (64 + 8 pad)
#define TP_ 208    // padded token rows per batch for qbf/kbf
#define VTP_ 224   // vtbf row length (7*32)
#define ZS_ 264    // cov Zb stride
#define FS_ 264    // ffn Alds/Tlds stride (256 + 8)
#define VS_ 136    // gemm_kv V-transpose LDS stride (128 + 8)

typedef __attribute__((ext_vector_type(4))) float  f32x4;
typedef __attribute__((ext_vector_type(8))) __bf16 bf16x8;
typedef __attribute__((ext_vector_type(4))) int    i32x4;
typedef __attribute__((ext_vector_type(2))) int    i32x2;

union frag8 { unsigned u[4]; bf16x8 v; };

__device__ __forceinline__ unsigned short f2bf(float f) {
    unsigned u = __float_as_uint(f);
    u += 0x7FFFu + ((u >> 16) & 1u);          // RNE to bf16
    return (unsigned short)(u >> 16);
}
__device__ __forceinline__ unsigned pk2(float lo, float hi) {
    return (unsigned)f2bf(lo) | ((unsigned)f2bf(hi) << 16);
}
__device__ __forceinline__ float bflo(unsigned u) { return __uint_as_float(u << 16); }
__device__ __forceinline__ float bfhi(unsigned u) { return __uint_as_float(u & 0xFFFF0000u); }

__device__ __forceinline__ float wave_sum(float v) {
#pragma unroll
    for (int o = 32; o >= 1; o >>= 1) v += __shfl_xor(v, o);
    return v;
}

// ---------------- embed (bf16 out) ----------------
__global__ void embed_kernel(const int* __restrict__ ls,
                             const float* __restrict__ itab,
                             const float* __restrict__ ptab,
                             unsigned short* __restrict__ seqs) {
    int bt = blockIdx.x;
    int t = bt % T_;
    int lane = threadIdx.x;
    int idx = ls[bt];
    int pos = idx ? (t + 1) : 0;
    float4 a = ((const float4*)(itab + (size_t)idx * D_))[lane];
    float4 p = ((const float4*)(ptab + (size_t)pos * D_))[lane];
    i32x2 r;
    r[0] = (int)pk2(a.x*16.f+p.x, a.y*16.f+p.y);
    r[1] = (int)pk2(a.z*16.f+p.z, a.w*16.f+p.w);
    ((i32x2*)(seqs + (size_t)bt * D_))[lane] = r;
}

// ---------------- layernorm (bf16 in; bf16 or fp32 out), 4 rows/block ----------------
template<bool F32OUT>
__global__ __launch_bounds__(256) void ln_kernel(const unsigned short* __restrict__ X,
                                                 const float* __restrict__ sc,
                                                 const float* __restrict__ bi,
                                                 void* __restrict__ Y) {
    int row = blockIdx.x * 4 + (threadIdx.x >> 6);
    int lane = threadIdx.x & 63;
    i32x2 xv = ((const i32x2*)(X + (size_t)row * D_))[lane];
    float x0 = bflo((unsigned)xv[0]), x1 = bfhi((unsigned)xv[0]);
    float x2 = bflo((unsigned)xv[1]), x3 = bfhi((unsigned)xv[1]);
    float m = wave_sum(x0 + x1 + x2 + x3) * (1.f / D_);
    float d0 = x0 - m, d1 = x1 - m, d2 = x2 - m, d3 = x3 - m;
    float v = wave_sum(d0*d0 + d1*d1 + d2*d2 + d3*d3) * (1.f / D_);
    float inv = rsqrtf(v + 1e-8f);
    float4 s4 = ((const float4*)sc)[lane];
    float4 b4 = ((const float4*)bi)[lane];
    float r0 = d0*inv*s4.x + b4.x, r1 = d1*inv*s4.y + b4.y;
    float r2 = d2*inv*s4.z + b4.z, r3 = d3*inv*s4.w + b4.w;
    if (F32OUT) {
        float4 r = {r0, r1, r2, r3};
        ((float4*)Y)[(size_t)row * (D_/4) + lane] = r;
    } else {
        i32x2 r;
        r[0] = (int)pk2(r0, r1);
        r[1] = (int)pk2(r2, r3);
        ((i32x2*)Y)[(size_t)row * (D_/4) + lane] = r;   // i32x2 = 4 bf16
    }
}

// ---------------- weight transpose: Wt[n][k] = bf16(W[k][n]) ----------------
__global__ __launch_bounds__(256) void wtrans_kernel(const float* __restrict__ W,
                                                     unsigned short* __restrict__ Wt) {
    __shared__ float tile[64][65];
    int c0 = blockIdx.x * 64, r0 = blockIdx.y * 64, l = blockIdx.z;
    const float* src = W + (size_t)l * DD_;
    unsigned short* dst = Wt + (size_t)l * DD_;
    int tid = threadIdx.x;
#pragma unroll
    for (int rep = 0; rep < 16; ++rep) {
        int idx = rep * 256 + tid;
        int r = idx >> 6, c = idx & 63;
        tile[r][c] = src[(size_t)(r0 + r) * D_ + c0 + c];
    }
    __syncthreads();
#pragma unroll
    for (int rep = 0; rep < 16; ++rep) {
        int idx = rep * 256 + tid;
        int r2 = idx >> 6, c2 = idx & 63;
        dst[(size_t)(c0 + r2) * D_ + r0 + c2] = f2bf(tile[c2][r2]);
    }
}

// zero vtbf pad cols [200,224)
__global__ void vtpad_kernel(unsigned short* __restrict__ vt) {
    if (threadIdx.x < VTP_ - T_)
        vt[(size_t)blockIdx.x * VTP_ + T_ + threadIdx.x] = 0;
}

// ---------------- MFMA GEMM (single-output; used for Q and Wo) ----------------
// OM: 0 = bf16 flat [m][256]; 1 = bf16 padded [b][208][256].
template<int OM, bool RES>
__global__ __launch_bounds__(256) void gemm_mfma(
    const unsigned short* __restrict__ A, const unsigned short* __restrict__ Wt,
    const float* __restrict__ bias, const unsigned short* res,
    unsigned short* Cout) {
    __shared__ unsigned short As[128 * GS_];
    __shared__ unsigned short Ws[128 * GS_];
    int t = threadIdx.x, lane = t & 63, wv = t >> 6;
    int wm = wv >> 1, wn = wv & 1;
    int l15 = lane & 15, l4 = lane >> 4;
    int m0 = blockIdx.y * 128, n0 = blockIdx.x * 128;

    f32x4 acc[4][4];
#pragma unroll
    for (int m = 0; m < 4; ++m)
#pragma unroll
        for (int n = 0; n < 4; ++n)
            acc[m][n] = f32x4{0.f, 0.f, 0.f, 0.f};

    for (int k0 = 0; k0 < D_; k0 += 64) {
#pragma unroll
        for (int rep = 0; rep < 4; ++rep) {
            int idx = rep * 256 + t;
            int r = idx >> 3, c8 = (idx & 7) * 8;
            *(i32x4*)&As[r * GS_ + c8] =
                *(const i32x4*)(A + (size_t)(m0 + r) * D_ + k0 + c8);
        }
#pragma unroll
        for (int rep = 0; rep < 4; ++rep) {
            int idx = rep * 256 + t;
            int r = idx >> 3, c8 = (idx & 7) * 8;
            *(i32x4*)&Ws[r * GS_ + c8] =
                *(const i32x4*)(Wt + (size_t)(n0 + r) * D_ + k0 + c8);
        }
        __syncthreads();
#pragma unroll
        for (int kk = 0; kk < 2; ++kk) {
            bf16x8 af[4], bf[4];
#pragma unroll
            for (int m = 0; m < 4; ++m)
                af[m] = *(const bf16x8*)&As[(wm*64 + m*16 + l15) * GS_ + kk*32 + l4*8];
#pragma unroll
            for (int n = 0; n < 4; ++n)
                bf[n] = *(const bf16x8*)&Ws[(wn*64 + n*16 + l15) * GS_ + kk*32 + l4*8];
#pragma unroll
            for (int m = 0; m < 4; ++m)
#pragma unroll
                for (int n = 0; n < 4; ++n)
                    acc[m][n] = __builtin_amdgcn_mfma_f32_16x16x32_bf16(af[m], bf[n], acc[m][n], 0, 0, 0);
        }
        __syncthreads();
    }
#pragma unroll
    for (int n = 0; n < 4; ++n) {
        int gn = n0 + wn*64 + n*16 + l15;
        float bn = bias[gn];
#pragma unroll
        for (int m = 0; m < 4; ++m) {
#pragma unroll
            for (int i = 0; i < 4; ++i) {
                int gm = m0 + wm*64 + m*16 + l4*4 + i;
                float v = acc[m][n][i] + bn;
                if (RES) v += bflo((unsigned)res[(size_t)gm * D_ + gn]);
                if (OM == 0) {
                    Cout[(size_t)gm * D_ + gn] = f2bf(v);
                } else {
                    int b = gm / 200, tt = gm - b * 200;
                    Cout[((size_t)b * TP_ + tt) * D_ + gn] = f2bf(v);
                }
            }
        }
    }
}

// ---------------- fused K+V GEMM: stages A once, two outputs ----------------
// V output goes through an LDS transpose so vtbf stores are coalesced i32x4.
__global__ __launch_bounds__(256) void gemm_kv(
    const unsigned short* __restrict__ A,
    const unsigned short* __restrict__ WtK, const unsigned short* __restrict__ WtV,
    const float* __restrict__ biasK, const float* __restrict__ biasV,
    unsigned short* __restrict__ kbf, unsigned short* __restrict__ vtbf) {
    __shared__ unsigned short sh[3 * 128 * GS_];   // staging; reused as V^T tile (128x136=34816 <= 55296)
    unsigned short* As  = sh;
    unsigned short* WsK = sh + 128 * GS_;
    unsigned short* WsV = sh + 2 * 128 * GS_;
    int t = threadIdx.x, lane = t & 63, wv = t >> 6;
    int wm = wv >> 1, wn = wv & 1;
    int l15 = lane & 15, l4 = lane >> 4;
    int m0 = blockIdx.y * 128, n0 = blockIdx.x * 128;

    f32x4 accK[4][4], accV[4][4];
#pragma unroll
    for (int m = 0; m < 4; ++m)
#pragma unroll
        for (int n = 0; n < 4; ++n) {
            accK[m][n] = f32x4{0.f, 0.f, 0.f, 0.f};
            accV[m][n] = f32x4{0.f, 0.f, 0.f, 0.f};
        }

    for (int k0 = 0; k0 < D_; k0 += 64) {
#pragma unroll
        for (int rep = 0; rep < 4; ++rep) {
            int idx = rep * 256 + t;
            int r = idx >> 3, c8 = (idx & 7) * 8;
            *(i32x4*)&As[r * GS_ + c8]  = *(const i32x4*)(A   + (size_t)(m0 + r) * D_ + k0 + c8);
            *(i32x4*)&WsK[r * GS_ + c8] = *(const i32x4*)(WtK + (size_t)(n0 + r) * D_ + k0 + c8);
            *(i32x4*)&WsV[r * GS_ + c8] = *(const i32x4*)(WtV + (size_t)(n0 + r) * D_ + k0 + c8);
        }
        __syncthreads();
#pragma unroll
        for (int kk = 0; kk < 2; ++kk) {
            bf16x8 af[4];
#pragma unroll
            for (int m = 0; m < 4; ++m)
                af[m] = *(const bf16x8*)&As[(wm*64 + m*16 + l15) * GS_ + kk*32 + l4*8];
#pragma unroll
            for (int n = 0; n < 4; ++n) {
                bf16x8 bk8 = *(const bf16x8*)&WsK[(wn*64 + n*16 + l15) * GS_ + kk*32 + l4*8];
                bf16x8 bv8 = *(const bf16x8*)&WsV[(wn*64 + n*16 + l15) * GS_ + kk*32 + l4*8];
#pragma unroll
                for (int m = 0; m < 4; ++m) {
                    accK[m][n] = __builtin_amdgcn_mfma_f32_16x16x32_bf16(af[m], bk8, accK[m][n], 0, 0, 0);
                    accV[m][n] = __builtin_amdgcn_mfma_f32_16x16x32_bf16(af[m], bv8, accV[m][n], 0, 0, 0);
                }
            }
        }
        __syncthreads();
    }

    // K: direct store (32B segments); V: pack into LDS transpose tile [gn_local][gm_local]
    unsigned short* Vt = sh;   // safe: all MFMA reads of staging complete (loop-final barrier)
#pragma unroll
    for (int n = 0; n < 4; ++n) {
        int gnl = wn*64 + n*16 + l15;
        int gn = n0 + gnl;
        float bnK = biasK[gn], bnV = biasV[gn];
#pragma unroll
        for (int m = 0; m < 4; ++m) {
#pragma unroll
            for (int i = 0; i < 4; ++i) {
                int gml = wm*64 + m*16 + l4*4 + i;
                int gm = m0 + gml;
                int b = gm / 200, tt = gm - b * 200;
                kbf[((size_t)b * TP_ + tt) * D_ + gn] = f2bf(accK[m][n][i] + bnK);
                Vt[gnl * VS_ + gml] = f2bf(accV[m][n][i] + bnV);
            }
        }
    }
    __syncthreads();
    // coalesced V^T write: 128 rows x 16 chunks of 8 bf16 (chunks never straddle a batch: 200 % 8 == 0)
#pragma unroll
    for (int rep = 0; rep < 8; ++rep) {
        int idx = rep * 256 + t;
        int row = idx >> 4, c8 = (idx & 15) * 8;
        int gn = n0 + row, hh = gn >> 6, dk = gn & 63;
        int gm = m0 + c8, b = gm / 200, tt = gm - b * 200;
        *(i32x4*)&vtbf[(((size_t)b * H_ + hh) * 64 + dk) * VTP_ + tt] =
            *(const i32x4*)&Vt[row * VS_ + c8];
    }
}

// ---------------- fused FFN: LN2 + relu(y@W1+b1)@W2 + b2 + y ----------------
__global__ __launch_bounds__(256) void ffn_fused(
    const unsigned short* __restrict__ S,
    const float* __restrict__ ln_s, const float* __restrict__ ln_b,
    const unsigned short* __restrict__ Wt1, const float* __restrict__ b1,
    const unsigned short* __restrict__ Wt2, const float* __restrict__ b2,
    unsigned short* __restrict__ OUT) {
    __shared__ unsigned short Alds[64 * FS_];   // y = LN2(s)
    __shared__ unsigned short Tlds[64 * FS_];   // tmp = relu(y@W1+b1)
    __shared__ unsigned short Ws[256 * GS_];    // weight chunk [256 n][64 k]
    int t = threadIdx.x, lane = t & 63, wv = t >> 6;
    int l15 = lane & 15, l4 = lane >> 4;
    int m0 = blockIdx.x * 64;

    // ---- phase 0: LN of 64 rows (4 threads/row x 64 cols each; i32x4 = 8 bf16) ----
    {
        int r = t >> 2, c = (t & 3) * 64;
        const unsigned short* src = S + (size_t)(m0 + r) * D_ + c;
        i32x4 buf[8];
#pragma unroll
        for (int j = 0; j < 8; ++j) buf[j] = ((const i32x4*)src)[j];
        float sum = 0.f;
#pragma unroll
        for (int j = 0; j < 8; ++j)
#pragma unroll
            for (int q = 0; q < 4; ++q)
                sum += bflo((unsigned)buf[j][q]) + bfhi((unsigned)buf[j][q]);
        sum += __shfl_xor(sum, 1);
        sum += __shfl_xor(sum, 2);
        float mean = sum * (1.f / D_);
        float var = 0.f;
#pragma unroll
        for (int j = 0; j < 8; ++j)
#pragma unroll
            for (int q = 0; q < 4; ++q) {
                float a0 = bflo((unsigned)buf[j][q]) - mean;
                float a1 = bfhi((unsigned)buf[j][q]) - mean;
                var += a0*a0 + a1*a1;
            }
        var += __shfl_xor(var, 1);
        var += __shfl_xor(var, 2);
        float inv = rsqrtf(var * (1.f / D_) + 1e-8f);
#pragma unroll
        for (int j = 0; j < 8; ++j) {
            int cc = c + j * 8;
            float4 sa = *(const float4*)&ln_s[cc];
            float4 sb = *(const float4*)&ln_s[cc + 4];
            float4 ba = *(const float4*)&ln_b[cc];
            float4 bb = *(const float4*)&ln_b[cc + 4];
            float y0 = (bflo((unsigned)buf[j][0]) - mean) * inv * sa.x + ba.x;
            float y1 = (bfhi((unsigned)buf[j][0]) - mean) * inv * sa.y + ba.y;
            float y2 = (bflo((unsigned)buf[j][1]) - mean) * inv * sa.z + ba.z;
            float y3 = (bfhi((unsigned)buf[j][1]) - mean) * inv * sa.w + ba.w;
            float y4 = (bflo((unsigned)buf[j][2]) - mean) * inv * sb.x + bb.x;
            float y5 = (bfhi((unsigned)buf[j][2]) - mean) * inv * sb.y + bb.y;
            float y6 = (bflo((unsigned)buf[j][3]) - mean) * inv * sb.z + bb.z;
            float y7 = (bfhi((unsigned)buf[j][3]) - mean) * inv * sb.w + bb.w;
            i32x4 w;
            w[0] = (int)pk2(y0, y1);
            w[1] = (int)pk2(y2, y3);
            w[2] = (int)pk2(y4, y5);
            w[3] = (int)pk2(y6, y7);
            *(i32x4*)&Alds[r * FS_ + cc] = w;
        }
    }
    __syncthreads();

    // ---- phase 1: tmp = relu(y @ W1 + b1) ----
    f32x4 acc[4][4];
#pragma unroll
    for (int m = 0; m < 4; ++m)
#pragma unroll
        for (int n = 0; n < 4; ++n)
            acc[m][n] = f32x4{0.f, 0.f, 0.f, 0.f};
    for (int k0 = 0; k0 < D_; k0 += 64) {
#pragma unroll
        for (int rep = 0; rep < 8; ++rep) {
            int idx = rep * 256 + t;
            int rr = idx >> 3, c8 = (idx & 7) * 8;
            *(i32x4*)&Ws[rr * GS_ + c8] = *(const i32x4*)(Wt1 + (size_t)rr * D_ + k0 + c8);
        }
        __syncthreads();
#pragma unroll
        for (int kk = 0; kk < 2; ++kk) {
            bf16x8 af[4], bf[4];
#pragma unroll
            for (int m = 0; m < 4; ++m)
                af[m] = *(const bf16x8*)&Alds[(m*16 + l15) * FS_ + k0 + kk*32 + l4*8];
#pragma unroll
            for (int n = 0; n < 4; ++n)
                bf[n] = *(const bf16x8*)&Ws[(wv*64 + n*16 + l15) * GS_ + kk*32 + l4*8];
#pragma unroll
            for (int m = 0; m < 4; ++m)
#pragma unroll
                for (int n = 0; n < 4; ++n)
                    acc[m][n] = __builtin_amdgcn_mfma_f32_16x16x32_bf16(af[m], bf[n], acc[m][n], 0, 0, 0);
        }
        __syncthreads();
    }
#pragma unroll
    for (int n = 0; n < 4; ++n) {
        int gn = wv*64 + n*16 + l15;
        float bn = b1[gn];
#pragma unroll
        for (int m = 0; m < 4; ++m)
#pragma unroll
            for (int i = 0; i < 4; ++i)
                Tlds[(m*16 + l4*4 + i) * FS_ + gn] = f2bf(fmaxf(acc[m][n][i] + bn, 0.f));
    }
    __syncthreads();

    // ---- phase 2: OUT = tmp @ W2 + b2 + y ----
#pragma unroll
    for (int m = 0; m < 4; ++m)
#pragma unroll
        for (int n = 0; n < 4; ++n)
            acc[m][n] = f32x4{0.f, 0.f, 0.f, 0.f};
    for (int k0 = 0; k0 < D_; k0 += 64) {
#pragma unroll
        for (int rep = 0; rep < 8; ++rep) {
            int idx = rep * 256 + t;
            int rr = idx >> 3, c8 = (idx & 7) * 8;
            *(i32x4*)&Ws[rr * GS_ + c8] = *(const i32x4*)(Wt2 + (size_t)rr * D_ + k0 + c8);
        }
        __syncthreads();
#pragma unroll
        for (int kk = 0; kk < 2; ++kk) {
            bf16x8 af[4], bf[4];
#pragma unroll
            for (int m = 0; m < 4; ++m)
                af[m] = *(const bf16x8*)&Tlds[(m*16 + l15) * FS_ + k0 + kk*32 + l4*8];
#pragma unroll
            for (int n = 0; n < 4; ++n)
                bf[n] = *(const bf16x8*)&Ws[(wv*64 + n*16 + l15) * GS_ + kk*32 + l4*8];
#pragma unroll
            for (int m = 0; m < 4; ++m)
#pragma unroll
                for (int n = 0; n < 4; ++n)
                    acc[m][n] = __builtin_amdgcn_mfma_f32_16x16x32_bf16(af[m], bf[n], acc[m][n], 0, 0, 0);
        }
        __syncthreads();
    }
#pragma unroll
    for (int n = 0; n < 4; ++n) {
        int gn = wv*64 + n*16 + l15;
        float bn = b2[gn];
#pragma unroll
        for (int m = 0; m < 4; ++m) {
#pragma unroll
            for (int i = 0; i < 4; ++i) {
                int row = m*16 + l4*4 + i;
                float v = acc[m][n][i] + bn + bflo((unsigned)Alds[row * FS_ + gn]);
                OUT[(size_t)(m0 + row) * D_ + gn] = f2bf(v);
            }
        }
    }
}

// ---------------- MFMA attention: 1 wave per (qt,h,b), no LDS, online softmax,
// XCD-swizzled 1D grid (13312 = 8 x 1664); T5 setprio around MFMA clusters.
template<bool DEC>
__global__ __launch_bounds__(64) void attn_mfma(
    const unsigned short* __restrict__ qbf,   // [b][208][256]
    const unsigned short* __restrict__ kbf,   // [b][208][256]
    const unsigned short* __restrict__ vtbf,  // [b*4+h][64][224]
    const float* __restrict__ cm,
    unsigned short* __restrict__ obf) {       // [bt][256]
    int o = ((blockIdx.x & 7) * 1664) + (blockIdx.x >> 3);
    int b = o / 52;
    int r = o - b * 52;
    int h = r / 13;
    int qt = r - h * 13;
    int lane = threadIdx.x;
    int l15 = lane & 15, l4 = lane >> 4;
    int q0 = qt * 16;
    int qr = q0 + l15;
    const f32x4 zero = {0.f, 0.f, 0.f, 0.f};

    size_t qkb = ((size_t)b * TP_) * D_ + h * 64;
    const unsigned short* qp = qbf + qkb + (size_t)(q0 + l15) * D_ + l4 * 8;
    bf16x8 bq0 = *(const bf16x8*)qp;
    bf16x8 bq1 = *(const bf16x8*)(qp + 32);

    size_t vbase = ((size_t)(b * H_ + h)) * 64 * VTP_;
    int sA = l15 + ((l4 & 1) << 5);
    int sB = sA + 16;
    bool lo4 = (l4 < 2);

    float m = -3e38f, l = 0.f;
    f32x4 O[4] = {zero, zero, zero, zero};

    int npair = (qt >> 1) + 1;
    for (int p = 0; p < npair; ++p) {
        int kt0 = 2 * p;
        bool hasOdd = (kt0 + 1 <= qt);

        f32x4 sv0, sv1;
        {
            const unsigned short* kp = kbf + qkb + (size_t)(kt0 * 16 + l15) * D_ + l4 * 8;
            bf16x8 ak0 = *(const bf16x8*)kp;
            bf16x8 ak1 = *(const bf16x8*)(kp + 32);
            __builtin_amdgcn_s_setprio(1);
            f32x4 acc = __builtin_amdgcn_mfma_f32_16x16x32_bf16(ak0, bq0, zero, 0, 0, 0);
            acc = __builtin_amdgcn_mfma_f32_16x16x32_bf16(ak1, bq1, acc, 0, 0, 0);
            __builtin_amdgcn_s_setprio(0);
#pragma unroll
            for (int i = 0; i < 4; ++i) {
                int kk = kt0 * 16 + l4 * 4 + i;
                float s = acc[i] * 0.125f;
                bool vld = (qr < T_) && (kk < T_);
                float cmv = (DEC && vld) ? cm[((size_t)(b * T_) + kk) * T_ + qr] : 0.f;
                if (!vld) s = -1e9f;
                else {
                    if (kk > qr) s = -1e9f;   // mask BEFORE cm multiply (as reference)
                    if (DEC) s *= (1.0f + 0.5f * cmv);
                }
                sv0[i] = s;
            }
        }
        if (hasOdd) {
            const unsigned short* kp = kbf + qkb + (size_t)((kt0 + 1) * 16 + l15) * D_ + l4 * 8;
            bf16x8 ak0 = *(const bf16x8*)kp;
            bf16x8 ak1 = *(const bf16x8*)(kp + 32);
            __builtin_amdgcn_s_setprio(1);
            f32x4 acc = __builtin_amdgcn_mfma_f32_16x16x32_bf16(ak0, bq0, zero, 0, 0, 0);
            acc = __builtin_amdgcn_mfma_f32_16x16x32_bf16(ak1, bq1, acc, 0, 0, 0);
            __builtin_amdgcn_s_setprio(0);
#pragma unroll
            for (int i = 0; i < 4; ++i) {
                int kk = (kt0 + 1) * 16 + l4 * 4 + i;
                float s = acc[i] * 0.125f;
                bool vld = (qr < T_) && (kk < T_);
                float cmv = (DEC && vld) ? cm[((size_t)(b * T_) + kk) * T_ + qr] : 0.f;
                if (!vld) s = -1e9f;
                else {
                    if (kk > qr) s = -1e9f;
                    if (DEC) s *= (1.0f + 0.5f * cmv);
                }
                sv1[i] = s;
            }
        }

        float tm = fmaxf(fmaxf(sv0[0], sv0[1]), fmaxf(sv0[2], sv0[3]));
        if (hasOdd) {
            float tm1 = fmaxf(fmaxf(sv1[0], sv1[1]), fmaxf(sv1[2], sv1[3]));
            tm = fmaxf(tm, tm1);
        }
        tm = fmaxf(tm, __shfl_xor(tm, 16));
        tm = fmaxf(tm, __shfl_xor(tm, 32));
        float m_new = fmaxf(m, tm);
        float sc = __expf(m - m_new);
        m = m_new;
        l *= sc;
#pragma unroll
        for (int i = 0; i < 4; ++i) {
            float osc = __shfl(sc, l4 * 4 + i);
#pragma unroll
            for (int dt = 0; dt < 4; ++dt) O[dt][i] *= osc;
        }

        float p0[4], p1[4];
#pragma unroll
        for (int i = 0; i < 4; ++i) {
            p0[i] = __expf(sv0[i] - m);
            l += p0[i];
        }
        if (hasOdd) {
#pragma unroll
            for (int i = 0; i < 4; ++i) {
                p1[i] = __expf(sv1[i] - m);
                l += p1[i];
            }
        } else {
#pragma unroll
            for (int i = 0; i < 4; ++i) p1[i] = 0.f;
        }

        unsigned pk0a = pk2(p0[0], p0[1]), pk0b = pk2(p0[2], p0[3]);
        unsigned pk1a = pk2(p1[0], p1[1]), pk1b = pk2(p1[2], p1[3]);
        unsigned e0 = (unsigned)__shfl((int)pk0a, sA);
        unsigned e1 = (unsigned)__shfl((int)pk0b, sA);
        unsigned e2 = (unsigned)__shfl((int)pk0a, sB);
        unsigned e3 = (unsigned)__shfl((int)pk0b, sB);
        unsigned o0 = (unsigned)__shfl((int)pk1a, sA);
        unsigned o1 = (unsigned)__shfl((int)pk1b, sA);
        unsigned o2 = (unsigned)__shfl((int)pk1a, sB);
        unsigned o3 = (unsigned)__shfl((int)pk1b, sB);
        frag8 pa;
        pa.u[0] = lo4 ? e0 : o0;
        pa.u[1] = lo4 ? e1 : o1;
        pa.u[2] = lo4 ? e2 : o2;
        pa.u[3] = lo4 ? e3 : o3;

        __builtin_amdgcn_s_setprio(1);
#pragma unroll
        for (int dt = 0; dt < 4; ++dt) {
            bf16x8 vf = *(const bf16x8*)&vtbf[vbase + (size_t)(dt * 16 + l15) * VTP_ + p * 32 + l4 * 8];
            O[dt] = __builtin_amdgcn_mfma_f32_16x16x32_bf16(pa.v, vf, O[dt], 0, 0, 0);
        }
        __builtin_amdgcn_s_setprio(0);
    }

    float L = l;
    L += __shfl_xor(L, 16);
    L += __shfl_xor(L, 32);
    float inv = 1.f / L;
#pragma unroll
    for (int i = 0; i < 4; ++i) {
        float oin = __shfl(inv, l4 * 4 + i);
        int qrow = q0 + l4 * 4 + i;
        if (qrow < T_) {
#pragma unroll
            for (int dt = 0; dt < 4; ++dt)
                obf[((size_t)(b * T_) + qrow) * D_ + h * 64 + dt * 16 + l15] = f2bf(O[dt][i]*oin);
        }
    }
}

// ---------------- cov (bf16 Z in; row mean computed inline per wave) ----------------
__global__ __launch_bounds__(512) void cov_mfma(const unsigned short* __restrict__ Z,
                                                float* __restrict__ cm) {
    __shared__ unsigned short Zb[208 * ZS_];
    int b = blockIdx.x;
    int tid = threadIdx.x, lane = tid & 63, wv = tid >> 6;
    int l15 = lane & 15, l4 = lane >> 4;

    for (int i = tid; i < T_ * 64; i += 512) {
        int t = i >> 6, c4 = (i & 63) << 2;
        i32x2 z = *(const i32x2*)(Z + ((size_t)b * T_ + t) * D_ + c4);
        float z0 = bflo((unsigned)z[0]), z1 = bfhi((unsigned)z[0]);
        float z2 = bflo((unsigned)z[1]), z3 = bfhi((unsigned)z[1]);
        float mean = wave_sum(z0 + z1 + z2 + z3) * (1.f / D_);
        unsigned* p = (unsigned*)&Zb[t * ZS_ + c4];
        p[0] = pk2(z0 - mean, z1 - mean);
        p[1] = pk2(z2 - mean, z3 - mean);
    }
    for (int i = tid; i < 8 * ZS_; i += 512) Zb[T_ * ZS_ + i] = 0;
    __syncthreads();

    for (int job = wv; job < 91; job += 8) {
        int ti = 0;
        while ((ti + 1) * (ti + 2) / 2 <= job) ++ti;
        int tj = job - ti * (ti + 1) / 2;
        f32x4 acc = {0.f, 0.f, 0.f, 0.f};
#pragma unroll
        for (int s = 0; s < 8; ++s) {
            bf16x8 a  = *(const bf16x8*)&Zb[(ti * 16 + l15) * ZS_ + s * 32 + l4 * 8];
            bf16x8 bb = *(const bf16x8*)&Zb[(tj * 16 + l15) * ZS_ + s * 32 + l4 * 8];
            acc = __builtin_amdgcn_mfma_f32_16x16x32_bf16(a, bb, acc, 0, 0, 0);
        }
#pragma unroll
        for (int i = 0; i < 4; ++i) {
            int t = ti * 16 + l4 * 4 + i, s2 = tj * 16 + l15;
            float vv = fminf(acc[i] * (1.f / 255.f), 3.0f);
            if (t < T_ && s2 < T_) {
                cm[((size_t)b * T_ + t) * T_ + s2] = vv;
                cm[((size_t)b * T_ + s2) * T_ + t] = vv;
            }
        }
    }
}

extern "C" void kernel_launch(void* const* d_in, const int* in_sizes, int n_in,
                              void* d_out, int out_size, void* d_ws, size_t ws_size,
                              hipStream_t stream) {
    const int*   log_seqs = (const int*)  d_in[0];
    const float* item_tab = (const float*)d_in[1];
    const float* pos_tab  = (const float*)d_in[2];
    const float* ln1_s = (const float*)d_in[3];
    const float* ln1_b = (const float*)d_in[4];
    const float* Wq = (const float*)d_in[5];
    const float* bq = (const float*)d_in[6];
    const float* Wk = (const float*)d_in[7];
    const float* bk = (const float*)d_in[8];
    const float* Wv = (const float*)d_in[9];
    const float* bv = (const float*)d_in[10];
    const float* Wo = (const float*)d_in[11];
    const float* bo = (const float*)d_in[12];
    const float* ln2_s = (const float*)d_in[13];
    const float* ln2_b = (const float*)d_in[14];
    const float* W1 = (const float*)d_in[15];
    const float* b1 = (const float*)d_in[16];
    const float* W2 = (const float*)d_in[17];
    const float* b2 = (const float*)d_in[18];
    const float* last_s = (const float*)d_in[19];
    const float* last_b = (const float*)d_in[20];

    const size_t NTD = (size_t)BT_ * D_;
    float* cmask = (float*)d_ws;                               // B*T*T fp32
    unsigned short* act = (unsigned short*)(cmask + (size_t)B_ * T_ * T_);
    unsigned short* s0   = act;              // seqs / layer-3 out
    unsigned short* s1   = s0 + NTD;         // causal_z / layer-2 out
    unsigned short* Qn   = s1 + NTD;         // ln1 out, then s (in-place)
    unsigned short* vb   = Qn + NTD;         // obf
    unsigned short* qbf  = vb + NTD;                         // [B][208][256]
    unsigned short* kbf  = qbf + (size_t)B_ * TP_ * D_;      // [B][208][256]
    unsigned short* vtbf = kbf + (size_t)B_ * TP_ * D_;      // [B*H][64][224]
    unsigned short* wtb  = vtbf + (size_t)B_ * H_ * 64 * VTP_;

    unsigned short* wtq = wtb;
    unsigned short* wtk = wtb + 4 * (size_t)DD_;
    unsigned short* wtv = wtb + 8 * (size_t)DD_;
    unsigned short* wto = wtb + 12 * (size_t)DD_;
    unsigned short* wt1 = wtb + 16 * (size_t)DD_;
    unsigned short* wt2 = wtb + 20 * (size_t)DD_;

    dim3 tg(4, 4, 4);
    wtrans_kernel<<<tg, 256, 0, stream>>>(Wq, wtq);
    wtrans_kernel<<<tg, 256, 0, stream>>>(Wk, wtk);
    wtrans_kernel<<<tg, 256, 0, stream>>>(Wv, wtv);
    wtrans_kernel<<<tg, 256, 0, stream>>>(Wo, wto);
    wtrans_kernel<<<tg, 256, 0, stream>>>(W1, wt1);
    wtrans_kernel<<<tg, 256, 0, stream>>>(W2, wt2);
    vtpad_kernel<<<B_ * H_ * 64, 32, 0, stream>>>(vtbf);

    dim3 gg(2, 400);   // N/128, M/128

    auto encoder = [&](const unsigned short* X, unsigned short* OUT, int i, const float* cmp) {
        ln_kernel<false><<<BT_/4, 256, 0, stream>>>(X, ln1_s + i*D_, ln1_b + i*D_, Qn);
        gemm_mfma<1,false><<<gg, 256, 0, stream>>>(Qn, wtq + (size_t)i*DD_, bq + i*D_, nullptr, qbf);
        gemm_kv<<<gg, 256, 0, stream>>>(X, wtk + (size_t)i*DD_, wtv + (size_t)i*DD_,
                                        bk + i*D_, bv + i*D_, kbf, vtbf);
        if (cmp) attn_mfma<true ><<<13312, 64, 0, stream>>>(qbf, kbf, vtbf, cmp, vb);
        else     attn_mfma<false><<<13312, 64, 0, stream>>>(qbf, kbf, vtbf, nullptr, vb);
        // s = Qn + vb @ Wo + bo  (in-place into Qn; element-exclusive)
        gemm_mfma<0,true><<<gg, 256, 0, stream>>>(vb, wto + (size_t)i*DD_, bo + i*D_, Qn, Qn);
        // OUT = relu(LN2(s)@W1+b1)@W2 + b2 + LN2(s)
        ffn_fused<<<BT_/64, 256, 0, stream>>>(Qn, ln2_s + i*D_, ln2_b + i*D_,
                                              wt1 + (size_t)i*DD_, b1 + i*D_,
                                              wt2 + (size_t)i*DD_, b2 + i*D_, OUT);
    };

    embed_kernel<<<BT_, 64, 0, stream>>>(log_seqs, item_tab, pos_tab, s0);

    // causal loop applies each layer to ORIGINAL seqs -> only layer 1 survives
    encoder(s0, s1, 1, nullptr);

    cov_mfma<<<B_, 512, 0, stream>>>(s1, cmask);

    encoder(s0, s1, 2, cmask);
    encoder(s1, s0, 3, cmask);

    ln_kernel<true><<<BT_/4, 256, 0, stream>>>(s0, last_s, last_b, (float*)d_out);
}

// Round 14
// 941.517 us; speedup vs baseline: 2.5283x; 1.0222x over previous
//
#include <hip/hip_runtime.h>
#include <hip/hip_bf16.h>

#define B_ 256
#define T_ 200
#define D_ 256
#define H_ 4
#define BT_ (B_*T_)
#define DD_ (D_*D_)
#define GS_ 72     // gemm LDS stride (64 + 8 pad)
#define TP_ 208    // padded token rows per batch for qbf/kbf
#define VTP_ 224   // vtbf row length (7*32)
#define ZS_ 264    // cov Zb stride
#define FS_ 264    // ffn Alds/Tlds stride (256 + 8)
#define VS_ 136    // epilogue LDS transpose stride (128 + 8)

typedef __attribute__((ext_vector_type(4))) float  f32x4;
typedef __attribute__((ext_vector_type(8))) __bf16 bf16x8;
typedef __attribute__((ext_vector_type(4))) int    i32x4;
typedef __attribute__((ext_vector_type(2))) int    i32x2;

union frag8 { unsigned u[4]; bf16x8 v; };

__device__ __forceinline__ unsigned short f2bf(float f) {
    unsigned u = __float_as_uint(f);
    u += 0x7FFFu + ((u >> 16) & 1u);          // RNE to bf16
    return (unsigned short)(u >> 16);
}
__device__ __forceinline__ unsigned pk2(float lo, float hi) {
    return (unsigned)f2bf(lo) | ((unsigned)f2bf(hi) << 16);
}
__device__ __forceinline__ float bflo(unsigned u) { return __uint_as_float(u << 16); }
__device__ __forceinline__ float bfhi(unsigned u) { return __uint_as_float(u & 0xFFFF0000u); }

__device__ __forceinline__ float wave_sum(float v) {
#pragma unroll
    for (int o = 32; o >= 1; o >>= 1) v += __shfl_xor(v, o);
    return v;
}

// ---------------- embed (bf16 out) ----------------
__global__ void embed_kernel(const int* __restrict__ ls,
                             const float* __restrict__ itab,
                             const float* __restrict__ ptab,
                             unsigned short* __restrict__ seqs) {
    int bt = blockIdx.x;
    int t = bt % T_;
    int lane = threadIdx.x;
    int idx = ls[bt];
    int pos = idx ? (t + 1) : 0;
    float4 a = ((const float4*)(itab + (size_t)idx * D_))[lane];
    float4 p = ((const float4*)(ptab + (size_t)pos * D_))[lane];
    i32x2 r;
    r[0] = (int)pk2(a.x*16.f+p.x, a.y*16.f+p.y);
    r[1] = (int)pk2(a.z*16.f+p.z, a.w*16.f+p.w);
    ((i32x2*)(seqs + (size_t)bt * D_))[lane] = r;
}

// ---------------- layernorm (bf16 in; bf16 or fp32 out), 4 rows/block ----------------
template<bool F32OUT>
__global__ __launch_bounds__(256) void ln_kernel(const unsigned short* __restrict__ X,
                                                 const float* __restrict__ sc,
                                                 const float* __restrict__ bi,
                                                 void* __restrict__ Y) {
    int row = blockIdx.x * 4 + (threadIdx.x >> 6);
    int lane = threadIdx.x & 63;
    i32x2 xv = ((const i32x2*)(X + (size_t)row * D_))[lane];
    float x0 = bflo((unsigned)xv[0]), x1 = bfhi((unsigned)xv[0]);
    float x2 = bflo((unsigned)xv[1]), x3 = bfhi((unsigned)xv[1]);
    float m = wave_sum(x0 + x1 + x2 + x3) * (1.f / D_);
    float d0 = x0 - m, d1 = x1 - m, d2 = x2 - m, d3 = x3 - m;
    float v = wave_sum(d0*d0 + d1*d1 + d2*d2 + d3*d3) * (1.f / D_);
    float inv = rsqrtf(v + 1e-8f);
    float4 s4 = ((const float4*)sc)[lane];
    float4 b4 = ((const float4*)bi)[lane];
    float r0 = d0*inv*s4.x + b4.x, r1 = d1*inv*s4.y + b4.y;
    float r2 = d2*inv*s4.z + b4.z, r3 = d3*inv*s4.w + b4.w;
    if (F32OUT) {
        float4 r = {r0, r1, r2, r3};
        ((float4*)Y)[(size_t)row * (D_/4) + lane] = r;
    } else {
        i32x2 r;
        r[0] = (int)pk2(r0, r1);
        r[1] = (int)pk2(r2, r3);
        ((i32x2*)Y)[(size_t)row * (D_/4) + lane] = r;   // i32x2 = 4 bf16
    }
}

// ---------------- weight transpose: Wt[n][k] = bf16(W[k][n]) ----------------
__global__ __launch_bounds__(256) void wtrans_kernel(const float* __restrict__ W,
                                                     unsigned short* __restrict__ Wt) {
    __shared__ float tile[64][65];
    int c0 = blockIdx.x * 64, r0 = blockIdx.y * 64, l = blockIdx.z;
    const float* src = W + (size_t)l * DD_;
    unsigned short* dst = Wt + (size_t)l * DD_;
    int tid = threadIdx.x;
#pragma unroll
    for (int rep = 0; rep < 16; ++rep) {
        int idx = rep * 256 + tid;
        int r = idx >> 6, c = idx & 63;
        tile[r][c] = src[(size_t)(r0 + r) * D_ + c0 + c];
    }
    __syncthreads();
#pragma unroll
    for (int rep = 0; rep < 16; ++rep) {
        int idx = rep * 256 + tid;
        int r2 = idx >> 6, c2 = idx & 63;
        dst[(size_t)(c0 + r2) * D_ + r0 + c2] = f2bf(tile[c2][r2]);
    }
}

// zero vtbf pad cols [200,224)
__global__ void vtpad_kernel(unsigned short* __restrict__ vt) {
    if (threadIdx.x < VTP_ - T_)
        vt[(size_t)blockIdx.x * VTP_ + T_ + threadIdx.x] = 0;
}

// ---------------- MFMA GEMM (single-output; used for Q and Wo) ----------------
// OM: 0 = bf16 flat [m][256]; 1 = bf16 padded [b][208][256].
// Epilogue: pack into LDS tile then coalesced i32x4 writes.
template<int OM, bool RES>
__global__ __launch_bounds__(256) void gemm_mfma(
    const unsigned short* __restrict__ A, const unsigned short* __restrict__ Wt,
    const float* __restrict__ bias, const unsigned short* res,
    unsigned short* Cout) {
    __shared__ unsigned short sh[2 * 128 * GS_];   // staging; reused as C tile 128*VS_=17408 elems
    unsigned short* As = sh;
    unsigned short* Ws = sh + 128 * GS_;
    int t = threadIdx.x, lane = t & 63, wv = t >> 6;
    int wm = wv >> 1, wn = wv & 1;
    int l15 = lane & 15, l4 = lane >> 4;
    int m0 = blockIdx.y * 128, n0 = blockIdx.x * 128;

    f32x4 acc[4][4];
#pragma unroll
    for (int m = 0; m < 4; ++m)
#pragma unroll
        for (int n = 0; n < 4; ++n)
            acc[m][n] = f32x4{0.f, 0.f, 0.f, 0.f};

    for (int k0 = 0; k0 < D_; k0 += 64) {
#pragma unroll
        for (int rep = 0; rep < 4; ++rep) {
            int idx = rep * 256 + t;
            int r = idx >> 3, c8 = (idx & 7) * 8;
            *(i32x4*)&As[r * GS_ + c8] =
                *(const i32x4*)(A + (size_t)(m0 + r) * D_ + k0 + c8);
        }
#pragma unroll
        for (int rep = 0; rep < 4; ++rep) {
            int idx = rep * 256 + t;
            int r = idx >> 3, c8 = (idx & 7) * 8;
            *(i32x4*)&Ws[r * GS_ + c8] =
                *(const i32x4*)(Wt + (size_t)(n0 + r) * D_ + k0 + c8);
        }
        __syncthreads();
#pragma unroll
        for (int kk = 0; kk < 2; ++kk) {
            bf16x8 af[4], bf[4];
#pragma unroll
            for (int m = 0; m < 4; ++m)
                af[m] = *(const bf16x8*)&As[(wm*64 + m*16 + l15) * GS_ + kk*32 + l4*8];
#pragma unroll
            for (int n = 0; n < 4; ++n)
                bf[n] = *(const bf16x8*)&Ws[(wn*64 + n*16 + l15) * GS_ + kk*32 + l4*8];
#pragma unroll
            for (int m = 0; m < 4; ++m)
#pragma unroll
                for (int n = 0; n < 4; ++n)
                    acc[m][n] = __builtin_amdgcn_mfma_f32_16x16x32_bf16(af[m], bf[n], acc[m][n], 0, 0, 0);
        }
        __syncthreads();
    }

    // pack results (bias/res applied, one rounding) into LDS [gml][gnl]
    unsigned short* Ct = sh;
#pragma unroll
    for (int n = 0; n < 4; ++n) {
        int gnl = wn*64 + n*16 + l15;
        int gn = n0 + gnl;
        float bn = bias[gn];
#pragma unroll
        for (int m = 0; m < 4; ++m) {
#pragma unroll
            for (int i = 0; i < 4; ++i) {
                int gml = wm*64 + m*16 + l4*4 + i;
                int gm = m0 + gml;
                float v = acc[m][n][i] + bn;
                if (RES) v += bflo((unsigned)res[(size_t)gm * D_ + gn]);
                Ct[gml * VS_ + gnl] = f2bf(v);
            }
        }
    }
    __syncthreads();
    // coalesced write: 128 rows x 16 chunks of 8 bf16
#pragma unroll
    for (int rep = 0; rep < 8; ++rep) {
        int idx = rep * 256 + t;
        int row = idx >> 4, c8 = (idx & 15) * 8;
        int gm = m0 + row;
        i32x4 w = *(const i32x4*)&Ct[row * VS_ + c8];
        if (OM == 0) {
            *(i32x4*)&Cout[(size_t)gm * D_ + n0 + c8] = w;
        } else {
            int b = gm / 200, tt = gm - b * 200;
            *(i32x4*)&Cout[((size_t)b * TP_ + tt) * D_ + n0 + c8] = w;
        }
    }
}

// ---------------- fused K+V GEMM: stages A once, two outputs ----------------
// Both K and V go through LDS transpose epilogues for coalesced i32x4 stores.
__global__ __launch_bounds__(256) void gemm_kv(
    const unsigned short* __restrict__ A,
    const unsigned short* __restrict__ WtK, const unsigned short* __restrict__ WtV,
    const float* __restrict__ biasK, const float* __restrict__ biasV,
    unsigned short* __restrict__ kbf, unsigned short* __restrict__ vtbf) {
    __shared__ unsigned short sh[3 * 128 * GS_];   // staging; reused for epilogue tiles
    unsigned short* As  = sh;
    unsigned short* WsK = sh + 128 * GS_;
    unsigned short* WsV = sh + 2 * 128 * GS_;
    int t = threadIdx.x, lane = t & 63, wv = t >> 6;
    int wm = wv >> 1, wn = wv & 1;
    int l15 = lane & 15, l4 = lane >> 4;
    int m0 = blockIdx.y * 128, n0 = blockIdx.x * 128;

    f32x4 accK[4][4], accV[4][4];
#pragma unroll
    for (int m = 0; m < 4; ++m)
#pragma unroll
        for (int n = 0; n < 4; ++n) {
            accK[m][n] = f32x4{0.f, 0.f, 0.f, 0.f};
            accV[m][n] = f32x4{0.f, 0.f, 0.f, 0.f};
        }

    for (int k0 = 0; k0 < D_; k0 += 64) {
#pragma unroll
        for (int rep = 0; rep < 4; ++rep) {
            int idx = rep * 256 + t;
            int r = idx >> 3, c8 = (idx & 7) * 8;
            *(i32x4*)&As[r * GS_ + c8]  = *(const i32x4*)(A   + (size_t)(m0 + r) * D_ + k0 + c8);
            *(i32x4*)&WsK[r * GS_ + c8] = *(const i32x4*)(WtK + (size_t)(n0 + r) * D_ + k0 + c8);
            *(i32x4*)&WsV[r * GS_ + c8] = *(const i32x4*)(WtV + (size_t)(n0 + r) * D_ + k0 + c8);
        }
        __syncthreads();
#pragma unroll
        for (int kk = 0; kk < 2; ++kk) {
            bf16x8 af[4];
#pragma unroll
            for (int m = 0; m < 4; ++m)
                af[m] = *(const bf16x8*)&As[(wm*64 + m*16 + l15) * GS_ + kk*32 + l4*8];
#pragma unroll
            for (int n = 0; n < 4; ++n) {
                bf16x8 bk8 = *(const bf16x8*)&WsK[(wn*64 + n*16 + l15) * GS_ + kk*32 + l4*8];
                bf16x8 bv8 = *(const bf16x8*)&WsV[(wn*64 + n*16 + l15) * GS_ + kk*32 + l4*8];
#pragma unroll
                for (int m = 0; m < 4; ++m) {
                    accK[m][n] = __builtin_amdgcn_mfma_f32_16x16x32_bf16(af[m], bk8, accK[m][n], 0, 0, 0);
                    accV[m][n] = __builtin_amdgcn_mfma_f32_16x16x32_bf16(af[m], bv8, accV[m][n], 0, 0, 0);
                }
            }
        }
        __syncthreads();
    }

    // --- K epilogue: pack [gml][gnl] then coalesced write to kbf ---
    unsigned short* Ct = sh;
#pragma unroll
    for (int n = 0; n < 4; ++n) {
        int gnl = wn*64 + n*16 + l15;
        float bnK = biasK[n0 + gnl];
#pragma unroll
        for (int m = 0; m < 4; ++m)
#pragma unroll
            for (int i = 0; i < 4; ++i) {
                int gml = wm*64 + m*16 + l4*4 + i;
                Ct[gml * VS_ + gnl] = f2bf(accK[m][n][i] + bnK);
            }
    }
    __syncthreads();
#pragma unroll
    for (int rep = 0; rep < 8; ++rep) {
        int idx = rep * 256 + t;
        int row = idx >> 4, c8 = (idx & 15) * 8;
        int gm = m0 + row, b = gm / 200, tt = gm - b * 200;
        *(i32x4*)&kbf[((size_t)b * TP_ + tt) * D_ + n0 + c8] =
            *(const i32x4*)&Ct[row * VS_ + c8];
    }
    __syncthreads();

    // --- V epilogue: pack transpose [gnl][gml] then coalesced write to vtbf ---
    unsigned short* Vt = sh;
#pragma unroll
    for (int n = 0; n < 4; ++n) {
        int gnl = wn*64 + n*16 + l15;
        float bnV = biasV[n0 + gnl];
#pragma unroll
        for (int m = 0; m < 4; ++m)
#pragma unroll
            for (int i = 0; i < 4; ++i) {
                int gml = wm*64 + m*16 + l4*4 + i;
                Vt[gnl * VS_ + gml] = f2bf(accV[m][n][i] + bnV);
            }
    }
    __syncthreads();
    // 128 rows (gn) x 16 chunks of 8 bf16 along gm (chunks never straddle a batch: 200 % 8 == 0)
#pragma unroll
    for (int rep = 0; rep < 8; ++rep) {
        int idx = rep * 256 + t;
        int row = idx >> 4, c8 = (idx & 15) * 8;
        int gn = n0 + row, hh = gn >> 6, dk = gn & 63;
        int gm = m0 + c8, b = gm / 200, tt = gm - b * 200;
        *(i32x4*)&vtbf[(((size_t)b * H_ + hh) * 64 + dk) * VTP_ + tt] =
            *(const i32x4*)&Vt[row * VS_ + c8];
    }
}

// ---------------- fused FFN: LN2 + relu(y@W1+b1)@W2 + b2 + y ----------------
__global__ __launch_bounds__(256) void ffn_fused(
    const unsigned short* __restrict__ S,
    const float* __restrict__ ln_s, const float* __restrict__ ln_b,
    const unsigned short* __restrict__ Wt1, const float* __restrict__ b1,
    const unsigned short* __restrict__ Wt2, const float* __restrict__ b2,
    unsigned short* __restrict__ OUT) {
    __shared__ unsigned short Alds[64 * FS_];   // y = LN2(s)
    __shared__ unsigned short Tlds[64 * FS_];   // tmp = relu(y@W1+b1); reused for OUT pack
    __shared__ unsigned short Ws[256 * GS_];    // weight chunk [256 n][64 k]
    int t = threadIdx.x, lane = t & 63, wv = t >> 6;
    int l15 = lane & 15, l4 = lane >> 4;
    int m0 = blockIdx.x * 64;

    // ---- phase 0: LN of 64 rows (4 threads/row x 64 cols each; i32x4 = 8 bf16) ----
    {
        int r = t >> 2, c = (t & 3) * 64;
        const unsigned short* src = S + (size_t)(m0 + r) * D_ + c;
        i32x4 buf[8];
#pragma unroll
        for (int j = 0; j < 8; ++j) buf[j] = ((const i32x4*)src)[j];
        float sum = 0.f;
#pragma unroll
        for (int j = 0; j < 8; ++j)
#pragma unroll
            for (int q = 0; q < 4; ++q)
                sum += bflo((unsigned)buf[j][q]) + bfhi((unsigned)buf[j][q]);
        sum += __shfl_xor(sum, 1);
        sum += __shfl_xor(sum, 2);
        float mean = sum * (1.f / D_);
        float var = 0.f;
#pragma unroll
        for (int j = 0; j < 8; ++j)
#pragma unroll
            for (int q = 0; q < 4; ++q) {
                float a0 = bflo((unsigned)buf[j][q]) - mean;
                float a1 = bfhi((unsigned)buf[j][q]) - mean;
                var += a0*a0 + a1*a1;
            }
        var += __shfl_xor(var, 1);
        var += __shfl_xor(var, 2);
        float inv = rsqrtf(var * (1.f / D_) + 1e-8f);
#pragma unroll
        for (int j = 0; j < 8; ++j) {
            int cc = c + j * 8;
            float4 sa = *(const float4*)&ln_s[cc];
            float4 sb = *(const float4*)&ln_s[cc + 4];
            float4 ba = *(const float4*)&ln_b[cc];
            float4 bb = *(const float4*)&ln_b[cc + 4];
            float y0 = (bflo((unsigned)buf[j][0]) - mean) * inv * sa.x + ba.x;
            float y1 = (bfhi((unsigned)buf[j][0]) - mean) * inv * sa.y + ba.y;
            float y2 = (bflo((unsigned)buf[j][1]) - mean) * inv * sa.z + ba.z;
            float y3 = (bfhi((unsigned)buf[j][1]) - mean) * inv * sa.w + ba.w;
            float y4 = (bflo((unsigned)buf[j][2]) - mean) * inv * sb.x + bb.x;
            float y5 = (bfhi((unsigned)buf[j][2]) - mean) * inv * sb.y + bb.y;
            float y6 = (bflo((unsigned)buf[j][3]) - mean) * inv * sb.z + bb.z;
            float y7 = (bfhi((unsigned)buf[j][3]) - mean) * inv * sb.w + bb.w;
            i32x4 w;
            w[0] = (int)pk2(y0, y1);
            w[1] = (int)pk2(y2, y3);
            w[2] = (int)pk2(y4, y5);
            w[3] = (int)pk2(y6, y7);
            *(i32x4*)&Alds[r * FS_ + cc] = w;
        }
    }
    __syncthreads();

    // ---- phase 1: tmp = relu(y @ W1 + b1) ----
    f32x4 acc[4][4];
#pragma unroll
    for (int m = 0; m < 4; ++m)
#pragma unroll
        for (int n = 0; n < 4; ++n)
            acc[m][n] = f32x4{0.f, 0.f, 0.f, 0.f};
    for (int k0 = 0; k0 < D_; k0 += 64) {
#pragma unroll
        for (int rep = 0; rep < 8; ++rep) {
            int idx = rep * 256 + t;
            int rr = idx >> 3, c8 = (idx & 7) * 8;
            *(i32x4*)&Ws[rr * GS_ + c8] = *(const i32x4*)(Wt1 + (size_t)rr * D_ + k0 + c8);
        }
        __syncthreads();
#pragma unroll
        for (int kk = 0; kk < 2; ++kk) {
            bf16x8 af[4], bf[4];
#pragma unroll
            for (int m = 0; m < 4; ++m)
                af[m] = *(const bf16x8*)&Alds[(m*16 + l15) * FS_ + k0 + kk*32 + l4*8];
#pragma unroll
            for (int n = 0; n < 4; ++n)
                bf[n] = *(const bf16x8*)&Ws[(wv*64 + n*16 + l15) * GS_ + kk*32 + l4*8];
#pragma unroll
            for (int m = 0; m < 4; ++m)
#pragma unroll
                for (int n = 0; n < 4; ++n)
                    acc[m][n] = __builtin_amdgcn_mfma_f32_16x16x32_bf16(af[m], bf[n], acc[m][n], 0, 0, 0);
        }
        __syncthreads();
    }
#pragma unroll
    for (int n = 0; n < 4; ++n) {
        int gn = wv*64 + n*16 + l15;
        float bn = b1[gn];
#pragma unroll
        for (int m = 0; m < 4; ++m)
#pragma unroll
            for (int i = 0; i < 4; ++i)
                Tlds[(m*16 + l4*4 + i) * FS_ + gn] = f2bf(fmaxf(acc[m][n][i] + bn, 0.f));
    }
    __syncthreads();

    // ---- phase 2: OUT = tmp @ W2 + b2 + y ----
#pragma unroll
    for (int m = 0; m < 4; ++m)
#pragma unroll
        for (int n = 0; n < 4; ++n)
            acc[m][n] = f32x4{0.f, 0.f, 0.f, 0.f};
    for (int k0 = 0; k0 < D_; k0 += 64) {
#pragma unroll
        for (int rep = 0; rep < 8; ++rep) {
            int idx = rep * 256 + t;
            int rr = idx >> 3, c8 = (idx & 7) * 8;
            *(i32x4*)&Ws[rr * GS_ + c8] = *(const i32x4*)(Wt2 + (size_t)rr * D_ + k0 + c8);
        }
        __syncthreads();
#pragma unroll
        for (int kk = 0; kk < 2; ++kk) {
            bf16x8 af[4], bf[4];
#pragma unroll
            for (int m = 0; m < 4; ++m)
                af[m] = *(const bf16x8*)&Tlds[(m*16 + l15) * FS_ + k0 + kk*32 + l4*8];
#pragma unroll
            for (int n = 0; n < 4; ++n)
                bf[n] = *(const bf16x8*)&Ws[(wv*64 + n*16 + l15) * GS_ + kk*32 + l4*8];
#pragma unroll
            for (int m = 0; m < 4; ++m)
#pragma unroll
                for (int n = 0; n < 4; ++n)
                    acc[m][n] = __builtin_amdgcn_mfma_f32_16x16x32_bf16(af[m], bf[n], acc[m][n], 0, 0, 0);
        }
        __syncthreads();
    }
    // pack OUT into Tlds (tmp no longer needed), then coalesced write
#pragma unroll
    for (int n = 0; n < 4; ++n) {
        int gn = wv*64 + n*16 + l15;
        float bn = b2[gn];
#pragma unroll
        for (int m = 0; m < 4; ++m) {
#pragma unroll
            for (int i = 0; i < 4; ++i) {
                int row = m*16 + l4*4 + i;
                float v = acc[m][n][i] + bn + bflo((unsigned)Alds[row * FS_ + gn]);
                Tlds[row * FS_ + gn] = f2bf(v);
            }
        }
    }
    __syncthreads();
#pragma unroll
    for (int rep = 0; rep < 8; ++rep) {
        int idx = rep * 256 + t;
        int row = idx >> 5, c8 = (idx & 31) * 8;
        *(i32x4*)&OUT[(size_t)(m0 + row) * D_ + c8] = *(const i32x4*)&Tlds[row * FS_ + c8];
    }
}

// ---------------- MFMA attention: 1 wave per (qt,h,b), online softmax,
// XCD-swizzled 1D grid (13312 = 8 x 1664); T5 setprio; LDS-repacked coalesced O store.
template<bool DEC>
__global__ __launch_bounds__(64) void attn_mfma(
    const unsigned short* __restrict__ qbf,   // [b][208][256]
    const unsigned short* __restrict__ kbf,   // [b][208][256]
    const unsigned short* __restrict__ vtbf,  // [b*4+h][64][224]
    const float* __restrict__ cm,
    unsigned short* __restrict__ obf) {       // [bt][256]
    __shared__ unsigned short Olds[16 * 72];
    int o = ((blockIdx.x & 7) * 1664) + (blockIdx.x >> 3);
    int b = o / 52;
    int r = o - b * 52;
    int h = r / 13;
    int qt = r - h * 13;
    int lane = threadIdx.x;
    int l15 = lane & 15, l4 = lane >> 4;
    int q0 = qt * 16;
    int qr = q0 + l15;
    const f32x4 zero = {0.f, 0.f, 0.f, 0.f};

    size_t qkb = ((size_t)b * TP_) * D_ + h * 64;
    const unsigned short* qp = qbf + qkb + (size_t)(q0 + l15) * D_ + l4 * 8;
    bf16x8 bq0 = *(const bf16x8*)qp;
    bf16x8 bq1 = *(const bf16x8*)(qp + 32);

    size_t vbase = ((size_t)(b * H_ + h)) * 64 * VTP_;
    int sA = l15 + ((l4 & 1) << 5);
    int sB = sA + 16;
    bool lo4 = (l4 < 2);

    float m = -3e38f, l = 0.f;
    f32x4 O[4] = {zero, zero, zero, zero};

    int npair = (qt >> 1) + 1;
    for (int p = 0; p < npair; ++p) {
        int kt0 = 2 * p;
        bool hasOdd = (kt0 + 1 <= qt);

        f32x4 sv0, sv1;
        {
            const unsigned short* kp = kbf + qkb + (size_t)(kt0 * 16 + l15) * D_ + l4 * 8;
            bf16x8 ak0 = *(const bf16x8*)kp;
            bf16x8 ak1 = *(const bf16x8*)(kp + 32);
            __builtin_amdgcn_s_setprio(1);
            f32x4 acc = __builtin_amdgcn_mfma_f32_16x16x32_bf16(ak0, bq0, zero, 0, 0, 0);
            acc = __builtin_amdgcn_mfma_f32_16x16x32_bf16(ak1, bq1, acc, 0, 0, 0);
            __builtin_amdgcn_s_setprio(0);
#pragma unroll
            for (int i = 0; i < 4; ++i) {
                int kk = kt0 * 16 + l4 * 4 + i;
                float s = acc[i] * 0.125f;
                bool vld = (qr < T_) && (kk < T_);
                float cmv = (DEC && vld) ? cm[((size_t)(b * T_) + kk) * T_ + qr] : 0.f;
                if (!vld) s = -1e9f;
                else {
                    if (kk > qr) s = -1e9f;   // mask BEFORE cm multiply (as reference)
                    if (DEC) s *= (1.0f + 0.5f * cmv);
                }
                sv0[i] = s;
            }
        }
        if (hasOdd) {
            const unsigned short* kp = kbf + qkb + (size_t)((kt0 + 1) * 16 + l15) * D_ + l4 * 8;
            bf16x8 ak0 = *(const bf16x8*)kp;
            bf16x8 ak1 = *(const bf16x8*)(kp + 32);
            __builtin_amdgcn_s_setprio(1);
            f32x4 acc = __builtin_amdgcn_mfma_f32_16x16x32_bf16(ak0, bq0, zero, 0, 0, 0);
            acc = __builtin_amdgcn_mfma_f32_16x16x32_bf16(ak1, bq1, acc, 0, 0, 0);
            __builtin_amdgcn_s_setprio(0);
#pragma unroll
            for (int i = 0; i < 4; ++i) {
                int kk = (kt0 + 1) * 16 + l4 * 4 + i;
                float s = acc[i] * 0.125f;
                bool vld = (qr < T_) && (kk < T_);
                float cmv = (DEC && vld) ? cm[((size_t)(b * T_) + kk) * T_ + qr] : 0.f;
                if (!vld) s = -1e9f;
                else {
                    if (kk > qr) s = -1e9f;
                    if (DEC) s *= (1.0f + 0.5f * cmv);
                }
                sv1[i] = s;
            }
        }

        float tm = fmaxf(fmaxf(sv0[0], sv0[1]), fmaxf(sv0[2], sv0[3]));
        if (hasOdd) {
            float tm1 = fmaxf(fmaxf(sv1[0], sv1[1]), fmaxf(sv1[2], sv1[3]));
            tm = fmaxf(tm, tm1);
        }
        tm = fmaxf(tm, __shfl_xor(tm, 16));
        tm = fmaxf(tm, __shfl_xor(tm, 32));
        float m_new = fmaxf(m, tm);
        float sc = __expf(m - m_new);
        m = m_new;
        l *= sc;
#pragma unroll
        for (int i = 0; i < 4; ++i) {
            float osc = __shfl(sc, l4 * 4 + i);
#pragma unroll
            for (int dt = 0; dt < 4; ++dt) O[dt][i] *= osc;
        }

        float p0[4], p1[4];
#pragma unroll
        for (int i = 0; i < 4; ++i) {
            p0[i] = __expf(sv0[i] - m);
            l += p0[i];
        }
        if (hasOdd) {
#pragma unroll
            for (int i = 0; i < 4; ++i) {
                p1[i] = __expf(sv1[i] - m);
                l += p1[i];
            }
        } else {
#pragma unroll
            for (int i = 0; i < 4; ++i) p1[i] = 0.f;
        }

        unsigned pk0a = pk2(p0[0], p0[1]), pk0b = pk2(p0[2], p0[3]);
        unsigned pk1a = pk2(p1[0], p1[1]), pk1b = pk2(p1[2], p1[3]);
        unsigned e0 = (unsigned)__shfl((int)pk0a, sA);
        unsigned e1 = (unsigned)__shfl((int)pk0b, sA);
        unsigned e2 = (unsigned)__shfl((int)pk0a, sB);
        unsigned e3 = (unsigned)__shfl((int)pk0b, sB);
        unsigned o0 = (unsigned)__shfl((int)pk1a, sA);
        unsigned o1 = (unsigned)__shfl((int)pk1b, sA);
        unsigned o2 = (unsigned)__shfl((int)pk1a, sB);
        unsigned o3 = (unsigned)__shfl((int)pk1b, sB);
        frag8 pa;
        pa.u[0] = lo4 ? e0 : o0;
        pa.u[1] = lo4 ? e1 : o1;
        pa.u[2] = lo4 ? e2 : o2;
        pa.u[3] = lo4 ? e3 : o3;

        __builtin_amdgcn_s_setprio(1);
#pragma unroll
        for (int dt = 0; dt < 4; ++dt) {
            bf16x8 vf = *(const bf16x8*)&vtbf[vbase + (size_t)(dt * 16 + l15) * VTP_ + p * 32 + l4 * 8];
            O[dt] = __builtin_amdgcn_mfma_f32_16x16x32_bf16(pa.v, vf, O[dt], 0, 0, 0);
        }
        __builtin_amdgcn_s_setprio(0);
    }

    float L = l;
    L += __shfl_xor(L, 16);
    L += __shfl_xor(L, 32);
    float inv = 1.f / L;
    // pack O into LDS [qrow-local][d-local] then coalesced i32x4 writes
#pragma unroll
    for (int i = 0; i < 4; ++i) {
        float oin = __shfl(inv, l4 * 4 + i);
#pragma unroll
        for (int dt = 0; dt < 4; ++dt)
            Olds[(l4 * 4 + i) * 72 + dt * 16 + l15] = f2bf(O[dt][i] * oin);
    }
    __syncthreads();
#pragma unroll
    for (int rep = 0; rep < 2; ++rep) {
        int idx = rep * 64 + lane;
        int row = idx >> 3, c8 = (idx & 7) * 8;
        int qrow = q0 + row;
        if (qrow < T_)
            *(i32x4*)&obf[((size_t)(b * T_) + qrow) * D_ + h * 64 + c8] =
                *(const i32x4*)&Olds[row * 72 + c8];
    }
}

// ---------------- cov (bf16 Z in; row mean computed inline per wave) ----------------
__global__ __launch_bounds__(512) void cov_mfma(const unsigned short* __restrict__ Z,
                                                float* __restrict__ cm) {
    __shared__ unsigned short Zb[208 * ZS_];
    int b = blockIdx.x;
    int tid = threadIdx.x, lane = tid & 63, wv = tid >> 6;
    int l15 = lane & 15, l4 = lane >> 4;

    for (int i = tid; i < T_ * 64; i += 512) {
        int t = i >> 6, c4 = (i & 63) << 2;
        i32x2 z = *(const i32x2*)(Z + ((size_t)b * T_ + t) * D_ + c4);
        float z0 = bflo((unsigned)z[0]), z1 = bfhi((unsigned)z[0]);
        float z2 = bflo((unsigned)z[1]), z3 = bfhi((unsigned)z[1]);
        float mean = wave_sum(z0 + z1 + z2 + z3) * (1.f / D_);
        unsigned* p = (unsigned*)&Zb[t * ZS_ + c4];
        p[0] = pk2(z0 - mean, z1 - mean);
        p[1] = pk2(z2 - mean, z3 - mean);
    }
    for (int i = tid; i < 8 * ZS_; i += 512) Zb[T_ * ZS_ + i] = 0;
    __syncthreads();

    for (int job = wv; job < 91; job += 8) {
        int ti = 0;
        while ((ti + 1) * (ti + 2) / 2 <= job) ++ti;
        int tj = job - ti * (ti + 1) / 2;
        f32x4 acc = {0.f, 0.f, 0.f, 0.f};
#pragma unroll
        for (int s = 0; s < 8; ++s) {
            bf16x8 a  = *(const bf16x8*)&Zb[(ti * 16 + l15) * ZS_ + s * 32 + l4 * 8];
            bf16x8 bb = *(const bf16x8*)&Zb[(tj * 16 + l15) * ZS_ + s * 32 + l4 * 8];
            acc = __builtin_amdgcn_mfma_f32_16x16x32_bf16(a, bb, acc, 0, 0, 0);
        }
#pragma unroll
        for (int i = 0; i < 4; ++i) {
            int t = ti * 16 + l4 * 4 + i, s2 = tj * 16 + l15;
            float vv = fminf(acc[i] * (1.f / 255.f), 3.0f);
            if (t < T_ && s2 < T_) {
                cm[((size_t)b * T_ + t) * T_ + s2] = vv;
                cm[((size_t)b * T_ + s2) * T_ + t] = vv;
            }
        }
    }
}

extern "C" void kernel_launch(void* const* d_in, const int* in_sizes, int n_in,
                              void* d_out, int out_size, void* d_ws, size_t ws_size,
                              hipStream_t stream) {
    const int*   log_seqs = (const int*)  d_in[0];
    const float* item_tab = (const float*)d_in[1];
    const float* pos_tab  = (const float*)d_in[2];
    const float* ln1_s = (const float*)d_in[3];
    const float* ln1_b = (const float*)d_in[4];
    const float* Wq = (const float*)d_in[5];
    const float* bq = (const float*)d_in[6];
    const float* Wk = (const float*)d_in[7];
    const float* bk = (const float*)d_in[8];
    const float* Wv = (const float*)d_in[9];
    const float* bv = (const float*)d_in[10];
    const float* Wo = (const float*)d_in[11];
    const float* bo = (const float*)d_in[12];
    const float* ln2_s = (const float*)d_in[13];
    const float* ln2_b = (const float*)d_in[14];
    const float* W1 = (const float*)d_in[15];
    const float* b1 = (const float*)d_in[16];
    const float* W2 = (const float*)d_in[17];
    const float* b2 = (const float*)d_in[18];
    const float* last_s = (const float*)d_in[19];
    const float* last_b = (const float*)d_in[20];

    const size_t NTD = (size_t)BT_ * D_;
    float* cmask = (float*)d_ws;                               // B*T*T fp32
    unsigned short* act = (unsigned short*)(cmask + (size_t)B_ * T_ * T_);
    unsigned short* s0   = act;              // seqs / layer-3 out
    unsigned short* s1   = s0 + NTD;         // causal_z / layer-2 out
    unsigned short* Qn   = s1 + NTD;         // ln1 out, then s (in-place)
    unsigned short* vb   = Qn + NTD;         // obf
    unsigned short* qbf  = vb + NTD;                         // [B][208][256]
    unsigned short* kbf  = qbf + (size_t)B_ * TP_ * D_;      // [B][208][256]
    unsigned short* vtbf = kbf + (size_t)B_ * TP_ * D_;      // [B*H][64][224]
    unsigned short* wtb  = vtbf + (size_t)B_ * H_ * 64 * VTP_;

    unsigned short* wtq = wtb;
    unsigned short* wtk = wtb + 4 * (size_t)DD_;
    unsigned short* wtv = wtb + 8 * (size_t)DD_;
    unsigned short* wto = wtb + 12 * (size_t)DD_;
    unsigned short* wt1 = wtb + 16 * (size_t)DD_;
    unsigned short* wt2 = wtb + 20 * (size_t)DD_;

    dim3 tg(4, 4, 4);
    wtrans_kernel<<<tg, 256, 0, stream>>>(Wq, wtq);
    wtrans_kernel<<<tg, 256, 0, stream>>>(Wk, wtk);
    wtrans_kernel<<<tg, 256, 0, stream>>>(Wv, wtv);
    wtrans_kernel<<<tg, 256, 0, stream>>>(Wo, wto);
    wtrans_kernel<<<tg, 256, 0, stream>>>(W1, wt1);
    wtrans_kernel<<<tg, 256, 0, stream>>>(W2, wt2);
    vtpad_kernel<<<B_ * H_ * 64, 32, 0, stream>>>(vtbf);

    dim3 gg(2, 400);   // N/128, M/128

    auto encoder = [&](const unsigned short* X, unsigned short* OUT, int i, const float* cmp) {
        ln_kernel<false><<<BT_/4, 256, 0, stream>>>(X, ln1_s + i*D_, ln1_b + i*D_, Qn);
        gemm_mfma<1,false><<<gg, 256, 0, stream>>>(Qn, wtq + (size_t)i*DD_, bq + i*D_, nullptr, qbf);
        gemm_kv<<<gg, 256, 0, stream>>>(X, wtk + (size_t)i*DD_, wtv + (size_t)i*DD_,
                                        bk + i*D_, bv + i*D_, kbf, vtbf);
        if (cmp) attn_mfma<true ><<<13312, 64, 0, stream>>>(qbf, kbf, vtbf, cmp, vb);
        else     attn_mfma<false><<<13312, 64, 0, stream>>>(qbf, kbf, vtbf, nullptr, vb);
        // s = Qn + vb @ Wo + bo  (in-place into Qn; element-exclusive)
        gemm_mfma<0,true><<<gg, 256, 0, stream>>>(vb, wto + (size_t)i*DD_, bo + i*D_, Qn, Qn);
        // OUT = relu(LN2(s)@W1+b1)@W2 + b2 + LN2(s)
        ffn_fused<<<BT_/64, 256, 0, stream>>>(Qn, ln2_s + i*D_, ln2_b + i*D_,
                                              wt1 + (size_t)i*DD_, b1 + i*D_,
                                              wt2 + (size_t)i*DD_, b2 + i*D_, OUT);
    };

    embed_kernel<<<BT_, 64, 0, stream>>>(log_seqs, item_tab, pos_tab, s0);

    // causal loop applies each layer to ORIGINAL seqs -> only layer 1 survives
    encoder(s0, s1, 1, nullptr);

    cov_mfma<<<B_, 512, 0, stream>>>(s1, cmask);

    encoder(s0, s1, 2, cmask);
    encoder(s1, s0, 3, cmask);

    ln_kernel<true><<<BT_/4, 256, 0, stream>>>(s0, last_s, last_b, (float*)d_out);
}

// Round 15
// 784.360 us; speedup vs baseline: 3.0348x; 1.2004x over previous
//
#include <hip/hip_runtime.h>
#include <hip/hip_bf16.h>

#define B_ 256
#define T_ 200
#define D_ 256
#define H_ 4
#define BT_ (B_*T_)
#define DD_ (D_*D_)
#define GS_ 72     // gemm LDS stride (64 + 8 pad)
#define TP_ 208    // padded token rows per batch for qbf/kbf
#define VTP_ 224   // vtbf row length (7*32)
#define ZS_ 264    // cov Zb stride
#define FS_ 264    // ffn Alds/Tlds stride (256 + 8)
#define VS_ 136    // epilogue LDS transpose stride (128 + 8)

typedef __attribute__((ext_vector_type(4))) float  f32x4;
typedef __attribute__((ext_vector_type(8))) __bf16 bf16x8;
typedef __attribute__((ext_vector_type(4))) int    i32x4;
typedef __attribute__((ext_vector_type(2))) int    i32x2;

union frag8 { unsigned u[4]; bf16x8 v; };

__device__ __forceinline__ unsigned short f2bf(float f) {
    unsigned u = __float_as_uint(f);
    u += 0x7FFFu + ((u >> 16) & 1u);          // RNE to bf16
    return (unsigned short)(u >> 16);
}
__device__ __forceinline__ unsigned pk2(float lo, float hi) {
    return (unsigned)f2bf(lo) | ((unsigned)f2bf(hi) << 16);
}
__device__ __forceinline__ float bflo(unsigned u) { return __uint_as_float(u << 16); }
__device__ __forceinline__ float bfhi(unsigned u) { return __uint_as_float(u & 0xFFFF0000u); }

__device__ __forceinline__ float wave_sum(float v) {
#pragma unroll
    for (int o = 32; o >= 1; o >>= 1) v += __shfl_xor(v, o);
    return v;
}

// ---------------- embed (bf16 out) ----------------
__global__ void embed_kernel(const int* __restrict__ ls,
                             const float* __restrict__ itab,
                             const float* __restrict__ ptab,
                             unsigned short* __restrict__ seqs) {
    int bt = blockIdx.x;
    int t = bt % T_;
    int lane = threadIdx.x;
    int idx = ls[bt];
    int pos = idx ? (t + 1) : 0;
    float4 a = ((const float4*)(itab + (size_t)idx * D_))[lane];
    float4 p = ((const float4*)(ptab + (size_t)pos * D_))[lane];
    i32x2 r;
    r[0] = (int)pk2(a.x*16.f+p.x, a.y*16.f+p.y);
    r[1] = (int)pk2(a.z*16.f+p.z, a.w*16.f+p.w);
    ((i32x2*)(seqs + (size_t)bt * D_))[lane] = r;
}

// ---------------- layernorm (bf16 in; bf16 or fp32 out), 4 rows/block ----------------
template<bool F32OUT>
__global__ __launch_bounds__(256) void ln_kernel(const unsigned short* __restrict__ X,
                                                 const float* __restrict__ sc,
                                                 const float* __restrict__ bi,
                                                 void* __restrict__ Y) {
    int row = blockIdx.x * 4 + (threadIdx.x >> 6);
    int lane = threadIdx.x & 63;
    i32x2 xv = ((const i32x2*)(X + (size_t)row * D_))[lane];
    float x0 = bflo((unsigned)xv[0]), x1 = bfhi((unsigned)xv[0]);
    float x2 = bflo((unsigned)xv[1]), x3 = bfhi((unsigned)xv[1]);
    float m = wave_sum(x0 + x1 + x2 + x3) * (1.f / D_);
    float d0 = x0 - m, d1 = x1 - m, d2 = x2 - m, d3 = x3 - m;
    float v = wave_sum(d0*d0 + d1*d1 + d2*d2 + d3*d3) * (1.f / D_);
    float inv = rsqrtf(v + 1e-8f);
    float4 s4 = ((const float4*)sc)[lane];
    float4 b4 = ((const float4*)bi)[lane];
    float r0 = d0*inv*s4.x + b4.x, r1 = d1*inv*s4.y + b4.y;
    float r2 = d2*inv*s4.z + b4.z, r3 = d3*inv*s4.w + b4.w;
    if (F32OUT) {
        float4 r = {r0, r1, r2, r3};
        ((float4*)Y)[(size_t)row * (D_/4) + lane] = r;
    } else {
        i32x2 r;
        r[0] = (int)pk2(r0, r1);
        r[1] = (int)pk2(r2, r3);
        ((i32x2*)Y)[(size_t)row * (D_/4) + lane] = r;   // i32x2 = 4 bf16
    }
}

// ---------------- weight transpose: Wt[n][k] = bf16(W[k][n]) ----------------
__global__ __launch_bounds__(256) void wtrans_kernel(const float* __restrict__ W,
                                                     unsigned short* __restrict__ Wt) {
    __shared__ float tile[64][65];
    int c0 = blockIdx.x * 64, r0 = blockIdx.y * 64, l = blockIdx.z;
    const float* src = W + (size_t)l * DD_;
    unsigned short* dst = Wt + (size_t)l * DD_;
    int tid = threadIdx.x;
#pragma unroll
    for (int rep = 0; rep < 16; ++rep) {
        int idx = rep * 256 + tid;
        int r = idx >> 6, c = idx & 63;
        tile[r][c] = src[(size_t)(r0 + r) * D_ + c0 + c];
    }
    __syncthreads();
#pragma unroll
    for (int rep = 0; rep < 16; ++rep) {
        int idx = rep * 256 + tid;
        int r2 = idx >> 6, c2 = idx & 63;
        dst[(size_t)(c0 + r2) * D_ + r0 + c2] = f2bf(tile[c2][r2]);
    }
}

// zero vtbf pad cols [200,224)
__global__ void vtpad_kernel(unsigned short* __restrict__ vt) {
    if (threadIdx.x < VTP_ - T_)
        vt[(size_t)blockIdx.x * VTP_ + T_ + threadIdx.x] = 0;
}

// ---------------- MFMA GEMM (single-output; used for Q and Wo) ----------------
// OM: 0 = bf16 flat [m][256]; 1 = bf16 padded [b][208][256].
template<int OM, bool RES>
__global__ __launch_bounds__(256) void gemm_mfma(
    const unsigned short* __restrict__ A, const unsigned short* __restrict__ Wt,
    const float* __restrict__ bias, const unsigned short* res,
    unsigned short* Cout) {
    __shared__ unsigned short sh[2 * 128 * GS_];
    unsigned short* As = sh;
    unsigned short* Ws = sh + 128 * GS_;
    int t = threadIdx.x, lane = t & 63, wv = t >> 6;
    int wm = wv >> 1, wn = wv & 1;
    int l15 = lane & 15, l4 = lane >> 4;
    int m0 = blockIdx.y * 128, n0 = blockIdx.x * 128;

    f32x4 acc[4][4];
#pragma unroll
    for (int m = 0; m < 4; ++m)
#pragma unroll
        for (int n = 0; n < 4; ++n)
            acc[m][n] = f32x4{0.f, 0.f, 0.f, 0.f};

    for (int k0 = 0; k0 < D_; k0 += 64) {
#pragma unroll
        for (int rep = 0; rep < 4; ++rep) {
            int idx = rep * 256 + t;
            int r = idx >> 3, c8 = (idx & 7) * 8;
            *(i32x4*)&As[r * GS_ + c8] =
                *(const i32x4*)(A + (size_t)(m0 + r) * D_ + k0 + c8);
        }
#pragma unroll
        for (int rep = 0; rep < 4; ++rep) {
            int idx = rep * 256 + t;
            int r = idx >> 3, c8 = (idx & 7) * 8;
            *(i32x4*)&Ws[r * GS_ + c8] =
                *(const i32x4*)(Wt + (size_t)(n0 + r) * D_ + k0 + c8);
        }
        __syncthreads();
#pragma unroll
        for (int kk = 0; kk < 2; ++kk) {
            bf16x8 af[4], bf[4];
#pragma unroll
            for (int m = 0; m < 4; ++m)
                af[m] = *(const bf16x8*)&As[(wm*64 + m*16 + l15) * GS_ + kk*32 + l4*8];
#pragma unroll
            for (int n = 0; n < 4; ++n)
                bf[n] = *(const bf16x8*)&Ws[(wn*64 + n*16 + l15) * GS_ + kk*32 + l4*8];
#pragma unroll
            for (int m = 0; m < 4; ++m)
#pragma unroll
                for (int n = 0; n < 4; ++n)
                    acc[m][n] = __builtin_amdgcn_mfma_f32_16x16x32_bf16(af[m], bf[n], acc[m][n], 0, 0, 0);
        }
        __syncthreads();
    }

    unsigned short* Ct = sh;
#pragma unroll
    for (int n = 0; n < 4; ++n) {
        int gnl = wn*64 + n*16 + l15;
        int gn = n0 + gnl;
        float bn = bias[gn];
#pragma unroll
        for (int m = 0; m < 4; ++m) {
#pragma unroll
            for (int i = 0; i < 4; ++i) {
                int gml = wm*64 + m*16 + l4*4 + i;
                int gm = m0 + gml;
                float v = acc[m][n][i] + bn;
                if (RES) v += bflo((unsigned)res[(size_t)gm * D_ + gn]);
                Ct[gml * VS_ + gnl] = f2bf(v);
            }
        }
    }
    __syncthreads();
#pragma unroll
    for (int rep = 0; rep < 8; ++rep) {
        int idx = rep * 256 + t;
        int row = idx >> 4, c8 = (idx & 15) * 8;
        int gm = m0 + row;
        i32x4 w = *(const i32x4*)&Ct[row * VS_ + c8];
        if (OM == 0) {
            *(i32x4*)&Cout[(size_t)gm * D_ + n0 + c8] = w;
        } else {
            int b = gm / 200, tt = gm - b * 200;
            *(i32x4*)&Cout[((size_t)b * TP_ + tt) * D_ + n0 + c8] = w;
        }
    }
}

// ---------------- fused K+V GEMM: 512 threads / 8 waves for occupancy ----------------
// Each wave owns 32 rows x 64 cols of both outputs (acc 64 VGPR/thread).
__global__ __launch_bounds__(512) void gemm_kv(
    const unsigned short* __restrict__ A,
    const unsigned short* __restrict__ WtK, const unsigned short* __restrict__ WtV,
    const float* __restrict__ biasK, const float* __restrict__ biasV,
    unsigned short* __restrict__ kbf, unsigned short* __restrict__ vtbf) {
    __shared__ unsigned short sh[3 * 128 * GS_];   // staging; reused for epilogue tiles
    unsigned short* As  = sh;
    unsigned short* WsK = sh + 128 * GS_;
    unsigned short* WsV = sh + 2 * 128 * GS_;
    int t = threadIdx.x, lane = t & 63, wv = t >> 6;   // wv 0..7
    int wm = wv >> 1, wn = wv & 1;                     // wm 0..3 (32-row slices), wn 0..1
    int l15 = lane & 15, l4 = lane >> 4;
    int m0 = blockIdx.y * 128, n0 = blockIdx.x * 128;

    f32x4 accK[2][4], accV[2][4];
#pragma unroll
    for (int m = 0; m < 2; ++m)
#pragma unroll
        for (int n = 0; n < 4; ++n) {
            accK[m][n] = f32x4{0.f, 0.f, 0.f, 0.f};
            accV[m][n] = f32x4{0.f, 0.f, 0.f, 0.f};
        }

    for (int k0 = 0; k0 < D_; k0 += 64) {
#pragma unroll
        for (int rep = 0; rep < 2; ++rep) {
            int idx = rep * 512 + t;
            int r = idx >> 3, c8 = (idx & 7) * 8;
            *(i32x4*)&As[r * GS_ + c8]  = *(const i32x4*)(A   + (size_t)(m0 + r) * D_ + k0 + c8);
            *(i32x4*)&WsK[r * GS_ + c8] = *(const i32x4*)(WtK + (size_t)(n0 + r) * D_ + k0 + c8);
            *(i32x4*)&WsV[r * GS_ + c8] = *(const i32x4*)(WtV + (size_t)(n0 + r) * D_ + k0 + c8);
        }
        __syncthreads();
#pragma unroll
        for (int kk = 0; kk < 2; ++kk) {
            bf16x8 af[2];
#pragma unroll
            for (int m = 0; m < 2; ++m)
                af[m] = *(const bf16x8*)&As[(wm*32 + m*16 + l15) * GS_ + kk*32 + l4*8];
#pragma unroll
            for (int n = 0; n < 4; ++n) {
                bf16x8 bk8 = *(const bf16x8*)&WsK[(wn*64 + n*16 + l15) * GS_ + kk*32 + l4*8];
                bf16x8 bv8 = *(const bf16x8*)&WsV[(wn*64 + n*16 + l15) * GS_ + kk*32 + l4*8];
#pragma unroll
                for (int m = 0; m < 2; ++m) {
                    accK[m][n] = __builtin_amdgcn_mfma_f32_16x16x32_bf16(af[m], bk8, accK[m][n], 0, 0, 0);
                    accV[m][n] = __builtin_amdgcn_mfma_f32_16x16x32_bf16(af[m], bv8, accV[m][n], 0, 0, 0);
                }
            }
        }
        __syncthreads();
    }

    // --- K epilogue: pack [gml][gnl] then coalesced write ---
    unsigned short* Ct = sh;
#pragma unroll
    for (int n = 0; n < 4; ++n) {
        int gnl = wn*64 + n*16 + l15;
        float bnK = biasK[n0 + gnl];
#pragma unroll
        for (int m = 0; m < 2; ++m)
#pragma unroll
            for (int i = 0; i < 4; ++i) {
                int gml = wm*32 + m*16 + l4*4 + i;
                Ct[gml * VS_ + gnl] = f2bf(accK[m][n][i] + bnK);
            }
    }
    __syncthreads();
#pragma unroll
    for (int rep = 0; rep < 4; ++rep) {
        int idx = rep * 512 + t;
        int row = idx >> 4, c8 = (idx & 15) * 8;
        int gm = m0 + row, b = gm / 200, tt = gm - b * 200;
        *(i32x4*)&kbf[((size_t)b * TP_ + tt) * D_ + n0 + c8] =
            *(const i32x4*)&Ct[row * VS_ + c8];
    }
    __syncthreads();

    // --- V epilogue: pack transpose [gnl][gml] then coalesced write ---
    unsigned short* Vt = sh;
#pragma unroll
    for (int n = 0; n < 4; ++n) {
        int gnl = wn*64 + n*16 + l15;
        float bnV = biasV[n0 + gnl];
#pragma unroll
        for (int m = 0; m < 2; ++m)
#pragma unroll
            for (int i = 0; i < 4; ++i) {
                int gml = wm*32 + m*16 + l4*4 + i;
                Vt[gnl * VS_ + gml] = f2bf(accV[m][n][i] + bnV);
            }
    }
    __syncthreads();
#pragma unroll
    for (int rep = 0; rep < 4; ++rep) {
        int idx = rep * 512 + t;
        int row = idx >> 4, c8 = (idx & 15) * 8;
        int gn = n0 + row, hh = gn >> 6, dk = gn & 63;
        int gm = m0 + c8, b = gm / 200, tt = gm - b * 200;
        *(i32x4*)&vtbf[(((size_t)b * H_ + hh) * 64 + dk) * VTP_ + tt] =
            *(const i32x4*)&Vt[row * VS_ + c8];
    }
}

// ---------------- fused FFN: LN2 + relu(y@W1+b1)@W2 + b2 + y ----------------
// 32-row blocks (LDS 70.7 KB -> 2 blocks/CU).
__global__ __launch_bounds__(256) void ffn_fused(
    const unsigned short* __restrict__ S,
    const float* __restrict__ ln_s, const float* __restrict__ ln_b,
    const unsigned short* __restrict__ Wt1, const float* __restrict__ b1,
    const unsigned short* __restrict__ Wt2, const float* __restrict__ b2,
    unsigned short* __restrict__ OUT) {
    __shared__ unsigned short Alds[32 * FS_];   // y = LN2(s)
    __shared__ unsigned short Tlds[32 * FS_];   // tmp; reused for OUT pack
    __shared__ unsigned short Ws[256 * GS_];    // weight chunk [256 n][64 k]
    int t = threadIdx.x, lane = t & 63, wv = t >> 6;
    int l15 = lane & 15, l4 = lane >> 4;
    int m0 = blockIdx.x * 32;

    // ---- phase 0: LN of 32 rows (8 threads/row x 32 cols; i32x4 = 8 bf16) ----
    {
        int r = t >> 3, c = (t & 7) * 32;
        const unsigned short* src = S + (size_t)(m0 + r) * D_ + c;
        i32x4 buf[4];
#pragma unroll
        for (int j = 0; j < 4; ++j) buf[j] = ((const i32x4*)src)[j];
        float sum = 0.f;
#pragma unroll
        for (int j = 0; j < 4; ++j)
#pragma unroll
            for (int q = 0; q < 4; ++q)
                sum += bflo((unsigned)buf[j][q]) + bfhi((unsigned)buf[j][q]);
        sum += __shfl_xor(sum, 1);
        sum += __shfl_xor(sum, 2);
        sum += __shfl_xor(sum, 4);
        float mean = sum * (1.f / D_);
        float var = 0.f;
#pragma unroll
        for (int j = 0; j < 4; ++j)
#pragma unroll
            for (int q = 0; q < 4; ++q) {
                float a0 = bflo((unsigned)buf[j][q]) - mean;
                float a1 = bfhi((unsigned)buf[j][q]) - mean;
                var += a0*a0 + a1*a1;
            }
        var += __shfl_xor(var, 1);
        var += __shfl_xor(var, 2);
        var += __shfl_xor(var, 4);
        float inv = rsqrtf(var * (1.f / D_) + 1e-8f);
#pragma unroll
        for (int j = 0; j < 4; ++j) {
            int cc = c + j * 8;
            float4 sa = *(const float4*)&ln_s[cc];
            float4 sb = *(const float4*)&ln_s[cc + 4];
            float4 ba = *(const float4*)&ln_b[cc];
            float4 bb = *(const float4*)&ln_b[cc + 4];
            float y0 = (bflo((unsigned)buf[j][0]) - mean) * inv * sa.x + ba.x;
            float y1 = (bfhi((unsigned)buf[j][0]) - mean) * inv * sa.y + ba.y;
            float y2 = (bflo((unsigned)buf[j][1]) - mean) * inv * sa.z + ba.z;
            float y3 = (bfhi((unsigned)buf[j][1]) - mean) * inv * sa.w + ba.w;
            float y4 = (bflo((unsigned)buf[j][2]) - mean) * inv * sb.x + bb.x;
            float y5 = (bfhi((unsigned)buf[j][2]) - mean) * inv * sb.y + bb.y;
            float y6 = (bflo((unsigned)buf[j][3]) - mean) * inv * sb.z + bb.z;
            float y7 = (bfhi((unsigned)buf[j][3]) - mean) * inv * sb.w + bb.w;
            i32x4 w;
            w[0] = (int)pk2(y0, y1);
            w[1] = (int)pk2(y2, y3);
            w[2] = (int)pk2(y4, y5);
            w[3] = (int)pk2(y6, y7);
            *(i32x4*)&Alds[r * FS_ + cc] = w;
        }
    }
    __syncthreads();

    // ---- phase 1: tmp = relu(y @ W1 + b1) ----
    f32x4 acc[2][4];
#pragma unroll
    for (int m = 0; m < 2; ++m)
#pragma unroll
        for (int n = 0; n < 4; ++n)
            acc[m][n] = f32x4{0.f, 0.f, 0.f, 0.f};
    for (int k0 = 0; k0 < D_; k0 += 64) {
#pragma unroll
        for (int rep = 0; rep < 8; ++rep) {
            int idx = rep * 256 + t;
            int rr = idx >> 3, c8 = (idx & 7) * 8;
            *(i32x4*)&Ws[rr * GS_ + c8] = *(const i32x4*)(Wt1 + (size_t)rr * D_ + k0 + c8);
        }
        __syncthreads();
#pragma unroll
        for (int kk = 0; kk < 2; ++kk) {
            bf16x8 af[2], bf[4];
#pragma unroll
            for (int m = 0; m < 2; ++m)
                af[m] = *(const bf16x8*)&Alds[(m*16 + l15) * FS_ + k0 + kk*32 + l4*8];
#pragma unroll
            for (int n = 0; n < 4; ++n)
                bf[n] = *(const bf16x8*)&Ws[(wv*64 + n*16 + l15) * GS_ + kk*32 + l4*8];
#pragma unroll
            for (int m = 0; m < 2; ++m)
#pragma unroll
                for (int n = 0; n < 4; ++n)
                    acc[m][n] = __builtin_amdgcn_mfma_f32_16x16x32_bf16(af[m], bf[n], acc[m][n], 0, 0, 0);
        }
        __syncthreads();
    }
#pragma unroll
    for (int n = 0; n < 4; ++n) {
        int gn = wv*64 + n*16 + l15;
        float bn = b1[gn];
#pragma unroll
        for (int m = 0; m < 2; ++m)
#pragma unroll
            for (int i = 0; i < 4; ++i)
                Tlds[(m*16 + l4*4 + i) * FS_ + gn] = f2bf(fmaxf(acc[m][n][i] + bn, 0.f));
    }
    __syncthreads();

    // ---- phase 2: OUT = tmp @ W2 + b2 + y ----
#pragma unroll
    for (int m = 0; m < 2; ++m)
#pragma unroll
        for (int n = 0; n < 4; ++n)
            acc[m][n] = f32x4{0.f, 0.f, 0.f, 0.f};
    for (int k0 = 0; k0 < D_; k0 += 64) {
#pragma unroll
        for (int rep = 0; rep < 8; ++rep) {
            int idx = rep * 256 + t;
            int rr = idx >> 3, c8 = (idx & 7) * 8;
            *(i32x4*)&Ws[rr * GS_ + c8] = *(const i32x4*)(Wt2 + (size_t)rr * D_ + k0 + c8);
        }
        __syncthreads();
#pragma unroll
        for (int kk = 0; kk < 2; ++kk) {
            bf16x8 af[2], bf[4];
#pragma unroll
            for (int m = 0; m < 2; ++m)
                af[m] = *(const bf16x8*)&Tlds[(m*16 + l15) * FS_ + k0 + kk*32 + l4*8];
#pragma unroll
            for (int n = 0; n < 4; ++n)
                bf[n] = *(const bf16x8*)&Ws[(wv*64 + n*16 + l15) * GS_ + kk*32 + l4*8];
#pragma unroll
            for (int m = 0; m < 2; ++m)
#pragma unroll
                for (int n = 0; n < 4; ++n)
                    acc[m][n] = __builtin_amdgcn_mfma_f32_16x16x32_bf16(af[m], bf[n], acc[m][n], 0, 0, 0);
        }
        __syncthreads();
    }
    // pack OUT into Tlds then coalesced write
#pragma unroll
    for (int n = 0; n < 4; ++n) {
        int gn = wv*64 + n*16 + l15;
        float bn = b2[gn];
#pragma unroll
        for (int m = 0; m < 2; ++m) {
#pragma unroll
            for (int i = 0; i < 4; ++i) {
                int row = m*16 + l4*4 + i;
                float v = acc[m][n][i] + bn + bflo((unsigned)Alds[row * FS_ + gn]);
                Tlds[row * FS_ + gn] = f2bf(v);
            }
        }
    }
    __syncthreads();
#pragma unroll
    for (int rep = 0; rep < 4; ++rep) {
        int idx = rep * 256 + t;
        int row = idx >> 5, c8 = (idx & 31) * 8;
        *(i32x4*)&OUT[(size_t)(m0 + row) * D_ + c8] = *(const i32x4*)&Tlds[row * FS_ + c8];
    }
}

// ---------------- MFMA attention: 1 wave per (qt,h,b), online softmax,
// XCD-swizzled 1D grid (13312 = 8 x 1664); T5 setprio; LDS-repacked coalesced O store.
template<bool DEC>
__global__ __launch_bounds__(64) void attn_mfma(
    const unsigned short* __restrict__ qbf,   // [b][208][256]
    const unsigned short* __restrict__ kbf,   // [b][208][256]
    const unsigned short* __restrict__ vtbf,  // [b*4+h][64][224]
    const float* __restrict__ cm,
    unsigned short* __restrict__ obf) {       // [bt][256]
    __shared__ unsigned short Olds[16 * 72];
    int o = ((blockIdx.x & 7) * 1664) + (blockIdx.x >> 3);
    int b = o / 52;
    int r = o - b * 52;
    int h = r / 13;
    int qt = r - h * 13;
    int lane = threadIdx.x;
    int l15 = lane & 15, l4 = lane >> 4;
    int q0 = qt * 16;
    int qr = q0 + l15;
    const f32x4 zero = {0.f, 0.f, 0.f, 0.f};

    size_t qkb = ((size_t)b * TP_) * D_ + h * 64;
    const unsigned short* qp = qbf + qkb + (size_t)(q0 + l15) * D_ + l4 * 8;
    bf16x8 bq0 = *(const bf16x8*)qp;
    bf16x8 bq1 = *(const bf16x8*)(qp + 32);

    size_t vbase = ((size_t)(b * H_ + h)) * 64 * VTP_;
    int sA = l15 + ((l4 & 1) << 5);
    int sB = sA + 16;
    bool lo4 = (l4 < 2);

    float m = -3e38f, l = 0.f;
    f32x4 O[4] = {zero, zero, zero, zero};

    int npair = (qt >> 1) + 1;
    for (int p = 0; p < npair; ++p) {
        int kt0 = 2 * p;
        bool hasOdd = (kt0 + 1 <= qt);

        f32x4 sv0, sv1;
        {
            const unsigned short* kp = kbf + qkb + (size_t)(kt0 * 16 + l15) * D_ + l4 * 8;
            bf16x8 ak0 = *(const bf16x8*)kp;
            bf16x8 ak1 = *(const bf16x8*)(kp + 32);
            __builtin_amdgcn_s_setprio(1);
            f32x4 acc = __builtin_amdgcn_mfma_f32_16x16x32_bf16(ak0, bq0, zero, 0, 0, 0);
            acc = __builtin_amdgcn_mfma_f32_16x16x32_bf16(ak1, bq1, acc, 0, 0, 0);
            __builtin_amdgcn_s_setprio(0);
#pragma unroll
            for (int i = 0; i < 4; ++i) {
                int kk = kt0 * 16 + l4 * 4 + i;
                float s = acc[i] * 0.125f;
                bool vld = (qr < T_) && (kk < T_);
                float cmv = (DEC && vld) ? cm[((size_t)(b * T_) + kk) * T_ + qr] : 0.f;
                if (!vld) s = -1e9f;
                else {
                    if (kk > qr) s = -1e9f;   // mask BEFORE cm multiply (as reference)
                    if (DEC) s *= (1.0f + 0.5f * cmv);
                }
                sv0[i] = s;
            }
        }
        if (hasOdd) {
            const unsigned short* kp = kbf + qkb + (size_t)((kt0 + 1) * 16 + l15) * D_ + l4 * 8;
            bf16x8 ak0 = *(const bf16x8*)kp;
            bf16x8 ak1 = *(const bf16x8*)(kp + 32);
            __builtin_amdgcn_s_setprio(1);
            f32x4 acc = __builtin_amdgcn_mfma_f32_16x16x32_bf16(ak0, bq0, zero, 0, 0, 0);
            acc = __builtin_amdgcn_mfma_f32_16x16x32_bf16(ak1, bq1, acc, 0, 0, 0);
            __builtin_amdgcn_s_setprio(0);
#pragma unroll
            for (int i = 0; i < 4; ++i) {
                int kk = (kt0 + 1) * 16 + l4 * 4 + i;
                float s = acc[i] * 0.125f;
                bool vld = (qr < T_) && (kk < T_);
                float cmv = (DEC && vld) ? cm[((size_t)(b * T_) + kk) * T_ + qr] : 0.f;
                if (!vld) s = -1e9f;
                else {
                    if (kk > qr) s = -1e9f;
                    if (DEC) s *= (1.0f + 0.5f * cmv);
                }
                sv1[i] = s;
            }
        }

        float tm = fmaxf(fmaxf(sv0[0], sv0[1]), fmaxf(sv0[2], sv0[3]));
        if (hasOdd) {
            float tm1 = fmaxf(fmaxf(sv1[0], sv1[1]), fmaxf(sv1[2], sv1[3]));
            tm = fmaxf(tm, tm1);
        }
        tm = fmaxf(tm, __shfl_xor(tm, 16));
        tm = fmaxf(tm, __shfl_xor(tm, 32));
        float m_new = fmaxf(m, tm);
        float sc = __expf(m - m_new);
        m = m_new;
        l *= sc;
#pragma unroll
        for (int i = 0; i < 4; ++i) {
            float osc = __shfl(sc, l4 * 4 + i);
#pragma unroll
            for (int dt = 0; dt < 4; ++dt) O[dt][i] *= osc;
        }

        float p0[4], p1[4];
#pragma unroll
        for (int i = 0; i < 4; ++i) {
            p0[i] = __expf(sv0[i] - m);
            l += p0[i];
        }
        if (hasOdd) {
#pragma unroll
            for (int i = 0; i < 4; ++i) {
                p1[i] = __expf(sv1[i] - m);
                l += p1[i];
            }
        } else {
#pragma unroll
            for (int i = 0; i < 4; ++i) p1[i] = 0.f;
        }

        unsigned pk0a = pk2(p0[0], p0[1]), pk0b = pk2(p0[2], p0[3]);
        unsigned pk1a = pk2(p1[0], p1[1]), pk1b = pk2(p1[2], p1[3]);
        unsigned e0 = (unsigned)__shfl((int)pk0a, sA);
        unsigned e1 = (unsigned)__shfl((int)pk0b, sA);
        unsigned e2 = (unsigned)__shfl((int)pk0a, sB);
        unsigned e3 = (unsigned)__shfl((int)pk0b, sB);
        unsigned o0 = (unsigned)__shfl((int)pk1a, sA);
        unsigned o1 = (unsigned)__shfl((int)pk1b, sA);
        unsigned o2 = (unsigned)__shfl((int)pk1a, sB);
        unsigned o3 = (unsigned)__shfl((int)pk1b, sB);
        frag8 pa;
        pa.u[0] = lo4 ? e0 : o0;
        pa.u[1] = lo4 ? e1 : o1;
        pa.u[2] = lo4 ? e2 : o2;
        pa.u[3] = lo4 ? e3 : o3;

        __builtin_amdgcn_s_setprio(1);
#pragma unroll
        for (int dt = 0; dt < 4; ++dt) {
            bf16x8 vf = *(const bf16x8*)&vtbf[vbase + (size_t)(dt * 16 + l15) * VTP_ + p * 32 + l4 * 8];
            O[dt] = __builtin_amdgcn_mfma_f32_16x16x32_bf16(pa.v, vf, O[dt], 0, 0, 0);
        }
        __builtin_amdgcn_s_setprio(0);
    }

    float L = l;
    L += __shfl_xor(L, 16);
    L += __shfl_xor(L, 32);
    float inv = 1.f / L;
#pragma unroll
    for (int i = 0; i < 4; ++i) {
        float oin = __shfl(inv, l4 * 4 + i);
#pragma unroll
        for (int dt = 0; dt < 4; ++dt)
            Olds[(l4 * 4 + i) * 72 + dt * 16 + l15] = f2bf(O[dt][i] * oin);
    }
    __syncthreads();
#pragma unroll
    for (int rep = 0; rep < 2; ++rep) {
        int idx = rep * 64 + lane;
        int row = idx >> 3, c8 = (idx & 7) * 8;
        int qrow = q0 + row;
        if (qrow < T_)
            *(i32x4*)&obf[((size_t)(b * T_) + qrow) * D_ + h * 64 + c8] =
                *(const i32x4*)&Olds[row * 72 + c8];
    }
}

// ---------------- cov (bf16 Z in; row mean computed inline per wave) ----------------
__global__ __launch_bounds__(512) void cov_mfma(const unsigned short* __restrict__ Z,
                                                float* __restrict__ cm) {
    __shared__ unsigned short Zb[208 * ZS_];
    int b = blockIdx.x;
    int tid = threadIdx.x, lane = tid & 63, wv = tid >> 6;
    int l15 = lane & 15, l4 = lane >> 4;

    for (int i = tid; i < T_ * 64; i += 512) {
        int t = i >> 6, c4 = (i & 63) << 2;
        i32x2 z = *(const i32x2*)(Z + ((size_t)b * T_ + t) * D_ + c4);
        float z0 = bflo((unsigned)z[0]), z1 = bfhi((unsigned)z[0]);
        float z2 = bflo((unsigned)z[1]), z3 = bfhi((unsigned)z[1]);
        float mean = wave_sum(z0 + z1 + z2 + z3) * (1.f / D_);
        unsigned* p = (unsigned*)&Zb[t * ZS_ + c4];
        p[0] = pk2(z0 - mean, z1 - mean);
        p[1] = pk2(z2 - mean, z3 - mean);
    }
    for (int i = tid; i < 8 * ZS_; i += 512) Zb[T_ * ZS_ + i] = 0;
    __syncthreads();

    for (int job = wv; job < 91; job += 8) {
        int ti = 0;
        while ((ti + 1) * (ti + 2) / 2 <= job) ++ti;
        int tj = job - ti * (ti + 1) / 2;
        f32x4 acc = {0.f, 0.f, 0.f, 0.f};
#pragma unroll
        for (int s = 0; s < 8; ++s) {
            bf16x8 a  = *(const bf16x8*)&Zb[(ti * 16 + l15) * ZS_ + s * 32 + l4 * 8];
            bf16x8 bb = *(const bf16x8*)&Zb[(tj * 16 + l15) * ZS_ + s * 32 + l4 * 8];
            acc = __builtin_amdgcn_mfma_f32_16x16x32_bf16(a, bb, acc, 0, 0, 0);
        }
#pragma unroll
        for (int i = 0; i < 4; ++i) {
            int t = ti * 16 + l4 * 4 + i, s2 = tj * 16 + l15;
            float vv = fminf(acc[i] * (1.f / 255.f), 3.0f);
            if (t < T_ && s2 < T_) {
                cm[((size_t)b * T_ + t) * T_ + s2] = vv;
                cm[((size_t)b * T_ + s2) * T_ + t] = vv;
            }
        }
    }
}

extern "C" void kernel_launch(void* const* d_in, const int* in_sizes, int n_in,
                              void* d_out, int out_size, void* d_ws, size_t ws_size,
                              hipStream_t stream) {
    const int*   log_seqs = (const int*)  d_in[0];
    const float* item_tab = (const float*)d_in[1];
    const float* pos_tab  = (const float*)d_in[2];
    const float* ln1_s = (const float*)d_in[3];
    const float* ln1_b = (const float*)d_in[4];
    const float* Wq = (const float*)d_in[5];
    const float* bq = (const float*)d_in[6];
    const float* Wk = (const float*)d_in[7];
    const float* bk = (const float*)d_in[8];
    const float* Wv = (const float*)d_in[9];
    const float* bv = (const float*)d_in[10];
    const float* Wo = (const float*)d_in[11];
    const float* bo = (const float*)d_in[12];
    const float* ln2_s = (const float*)d_in[13];
    const float* ln2_b = (const float*)d_in[14];
    const float* W1 = (const float*)d_in[15];
    const float* b1 = (const float*)d_in[16];
    const float* W2 = (const float*)d_in[17];
    const float* b2 = (const float*)d_in[18];
    const float* last_s = (const float*)d_in[19];
    const float* last_b = (const float*)d_in[20];

    const size_t NTD = (size_t)BT_ * D_;
    float* cmask = (float*)d_ws;                               // B*T*T fp32
    unsigned short* act = (unsigned short*)(cmask + (size_t)B_ * T_ * T_);
    unsigned short* s0   = act;              // seqs / layer-3 out
    unsigned short* s1   = s0 + NTD;         // causal_z / layer-2 out
    unsigned short* Qn   = s1 + NTD;         // ln1 out, then s (in-place)
    unsigned short* vb   = Qn + NTD;         // obf
    unsigned short* qbf  = vb + NTD;                         // [B][208][256]
    unsigned short* kbf  = qbf + (size_t)B_ * TP_ * D_;      // [B][208][256]
    unsigned short* vtbf = kbf + (size_t)B_ * TP_ * D_;      // [B*H][64][224]
    unsigned short* wtb  = vtbf + (size_t)B_ * H_ * 64 * VTP_;

    unsigned short* wtq = wtb;
    unsigned short* wtk = wtb + 4 * (size_t)DD_;
    unsigned short* wtv = wtb + 8 * (size_t)DD_;
    unsigned short* wto = wtb + 12 * (size_t)DD_;
    unsigned short* wt1 = wtb + 16 * (size_t)DD_;
    unsigned short* wt2 = wtb + 20 * (size_t)DD_;

    dim3 tg(4, 4, 4);
    wtrans_kernel<<<tg, 256, 0, stream>>>(Wq, wtq);
    wtrans_kernel<<<tg, 256, 0, stream>>>(Wk, wtk);
    wtrans_kernel<<<tg, 256, 0, stream>>>(Wv, wtv);
    wtrans_kernel<<<tg, 256, 0, stream>>>(Wo, wto);
    wtrans_kernel<<<tg, 256, 0, stream>>>(W1, wt1);
    wtrans_kernel<<<tg, 256, 0, stream>>>(W2, wt2);
    vtpad_kernel<<<B_ * H_ * 64, 32, 0, stream>>>(vtbf);

    dim3 gg(2, 400);   // N/128, M/128

    auto encoder = [&](const unsigned short* X, unsigned short* OUT, int i, const float* cmp) {
        ln_kernel<false><<<BT_/4, 256, 0, stream>>>(X, ln1_s + i*D_, ln1_b + i*D_, Qn);
        gemm_mfma<1,false><<<gg, 256, 0, stream>>>(Qn, wtq + (size_t)i*DD_, bq + i*D_, nullptr, qbf);
        gemm_kv<<<gg, 512, 0, stream>>>(X, wtk + (size_t)i*DD_, wtv + (size_t)i*DD_,
                                        bk + i*D_, bv + i*D_, kbf, vtbf);
        if (cmp) attn_mfma<true ><<<13312, 64, 0, stream>>>(qbf, kbf, vtbf, cmp, vb);
        else     attn_mfma<false><<<13312, 64, 0, stream>>>(qbf, kbf, vtbf, nullptr, vb);
        // s = Qn + vb @ Wo + bo  (in-place into Qn; element-exclusive)
        gemm_mfma<0,true><<<gg, 256, 0, stream>>>(vb, wto + (size_t)i*DD_, bo + i*D_, Qn, Qn);
        // OUT = relu(LN2(s)@W1+b1)@W2 + b2 + LN2(s)
        ffn_fused<<<BT_/32, 256, 0, stream>>>(Qn, ln2_s + i*D_, ln2_b + i*D_,
                                              wt1 + (size_t)i*DD_, b1 + i*D_,
                                              wt2 + (size_t)i*DD_, b2 + i*D_, OUT);
    };

    embed_kernel<<<BT_, 64, 0, stream>>>(log_seqs, item_tab, pos_tab, s0);

    // causal loop applies each layer to ORIGINAL seqs -> only layer 1 survives
    encoder(s0, s1, 1, nullptr);

    cov_mfma<<<B_, 512, 0, stream>>>(s1, cmask);

    encoder(s0, s1, 2, cmask);
    encoder(s1, s0, 3, cmask);

    ln_kernel<true><<<BT_/4, 256, 0, stream>>>(s0, last_s, last_b, (float*)d_out);
}

// Round 16
// 714.109 us; speedup vs baseline: 3.3334x; 1.0984x over previous
//
#include <hip/hip_runtime.h>
#include <hip/hip_bf16.h>

#define B_ 256
#define T_ 200
#define D_ 256
#define H_ 4
#define BT_ (B_*T_)
#define DD_ (D_*D_)
#define GS_ 72     // gemm LDS stride (64 + 8 pad)
#define TP_ 208    // padded token rows per batch for qbf/kbf
#define VTP_ 224   // vtbf row length (7*32)
#define ZS_ 264    // cov Zb stride
#define FS_ 264    // ffn Alds/Tlds stride (256 + 8)
#define VS_ 136    // epilogue LDS transpose stride (128 + 8)

typedef __attribute__((ext_vector_type(4))) float  f32x4;
typedef __attribute__((ext_vector_type(8))) __bf16 bf16x8;
typedef __attribute__((ext_vector_type(4))) int    i32x4;
typedef __attribute__((ext_vector_type(2))) int    i32x2;

union frag8 { unsigned u[4]; bf16x8 v; };

__device__ __forceinline__ unsigned short f2bf(float f) {
    unsigned u = __float_as_uint(f);
    u += 0x7FFFu + ((u >> 16) & 1u);          // RNE to bf16
    return (unsigned short)(u >> 16);
}
__device__ __forceinline__ unsigned pk2(float lo, float hi) {
    return (unsigned)f2bf(lo) | ((unsigned)f2bf(hi) << 16);
}
__device__ __forceinline__ float bflo(unsigned u) { return __uint_as_float(u << 16); }
__device__ __forceinline__ float bfhi(unsigned u) { return __uint_as_float(u & 0xFFFF0000u); }

__device__ __forceinline__ float wave_sum(float v) {
#pragma unroll
    for (int o = 32; o >= 1; o >>= 1) v += __shfl_xor(v, o);
    return v;
}

// ---------------- embed (bf16 out) ----------------
__global__ void embed_kernel(const int* __restrict__ ls,
                             const float* __restrict__ itab,
                             const float* __restrict__ ptab,
                             unsigned short* __restrict__ seqs) {
    int bt = blockIdx.x;
    int t = bt % T_;
    int lane = threadIdx.x;
    int idx = ls[bt];
    int pos = idx ? (t + 1) : 0;
    float4 a = ((const float4*)(itab + (size_t)idx * D_))[lane];
    float4 p = ((const float4*)(ptab + (size_t)pos * D_))[lane];
    i32x2 r;
    r[0] = (int)pk2(a.x*16.f+p.x, a.y*16.f+p.y);
    r[1] = (int)pk2(a.z*16.f+p.z, a.w*16.f+p.w);
    ((i32x2*)(seqs + (size_t)bt * D_))[lane] = r;
}

// ---------------- layernorm (bf16 in; bf16 or fp32 out), 4 rows/block ----------------
template<bool F32OUT>
__global__ __launch_bounds__(256) void ln_kernel(const unsigned short* __restrict__ X,
                                                 const float* __restrict__ sc,
                                                 const float* __restrict__ bi,
                                                 void* __restrict__ Y) {
    int row = blockIdx.x * 4 + (threadIdx.x >> 6);
    int lane = threadIdx.x & 63;
    i32x2 xv = ((const i32x2*)(X + (size_t)row * D_))[lane];
    float x0 = bflo((unsigned)xv[0]), x1 = bfhi((unsigned)xv[0]);
    float x2 = bflo((unsigned)xv[1]), x3 = bfhi((unsigned)xv[1]);
    float m = wave_sum(x0 + x1 + x2 + x3) * (1.f / D_);
    float d0 = x0 - m, d1 = x1 - m, d2 = x2 - m, d3 = x3 - m;
    float v = wave_sum(d0*d0 + d1*d1 + d2*d2 + d3*d3) * (1.f / D_);
    float inv = rsqrtf(v + 1e-8f);
    float4 s4 = ((const float4*)sc)[lane];
    float4 b4 = ((const float4*)bi)[lane];
    float r0 = d0*inv*s4.x + b4.x, r1 = d1*inv*s4.y + b4.y;
    float r2 = d2*inv*s4.z + b4.z, r3 = d3*inv*s4.w + b4.w;
    if (F32OUT) {
        float4 r = {r0, r1, r2, r3};
        ((float4*)Y)[(size_t)row * (D_/4) + lane] = r;
    } else {
        i32x2 r;
        r[0] = (int)pk2(r0, r1);
        r[1] = (int)pk2(r2, r3);
        ((i32x2*)Y)[(size_t)row * (D_/4) + lane] = r;   // i32x2 = 4 bf16
    }
}

// ---------------- weight transpose: Wt[n][k] = bf16(W[k][n]) ----------------
__global__ __launch_bounds__(256) void wtrans_kernel(const float* __restrict__ W,
                                                     unsigned short* __restrict__ Wt) {
    __shared__ float tile[64][65];
    int c0 = blockIdx.x * 64, r0 = blockIdx.y * 64, l = blockIdx.z;
    const float* src = W + (size_t)l * DD_;
    unsigned short* dst = Wt + (size_t)l * DD_;
    int tid = threadIdx.x;
#pragma unroll
    for (int rep = 0; rep < 16; ++rep) {
        int idx = rep * 256 + tid;
        int r = idx >> 6, c = idx & 63;
        tile[r][c] = src[(size_t)(r0 + r) * D_ + c0 + c];
    }
    __syncthreads();
#pragma unroll
    for (int rep = 0; rep < 16; ++rep) {
        int idx = rep * 256 + tid;
        int r2 = idx >> 6, c2 = idx & 63;
        dst[(size_t)(c0 + r2) * D_ + r0 + c2] = f2bf(tile[c2][r2]);
    }
}

// zero vtbf pad cols [200,224)
__global__ void vtpad_kernel(unsigned short* __restrict__ vt) {
    if (threadIdx.x < VTP_ - T_)
        vt[(size_t)blockIdx.x * VTP_ + T_ + threadIdx.x] = 0;
}

// ---------------- MFMA GEMM (512 threads / 8 waves; used for Q and Wo) ----------------
// OM: 0 = bf16 flat [m][256]; 1 = bf16 padded [b][208][256].
template<int OM, bool RES>
__global__ __launch_bounds__(512) void gemm_mfma(
    const unsigned short* __restrict__ A, const unsigned short* __restrict__ Wt,
    const float* __restrict__ bias, const unsigned short* res,
    unsigned short* Cout) {
    __shared__ unsigned short sh[2 * 128 * GS_];
    unsigned short* As = sh;
    unsigned short* Ws = sh + 128 * GS_;
    int t = threadIdx.x, lane = t & 63, wv = t >> 6;   // wv 0..7
    int wm = wv >> 1, wn = wv & 1;                     // wm 0..3 (32-row slices)
    int l15 = lane & 15, l4 = lane >> 4;
    int m0 = blockIdx.y * 128, n0 = blockIdx.x * 128;

    f32x4 acc[2][4];
#pragma unroll
    for (int m = 0; m < 2; ++m)
#pragma unroll
        for (int n = 0; n < 4; ++n)
            acc[m][n] = f32x4{0.f, 0.f, 0.f, 0.f};

    for (int k0 = 0; k0 < D_; k0 += 64) {
#pragma unroll
        for (int rep = 0; rep < 2; ++rep) {
            int idx = rep * 512 + t;
            int r = idx >> 3, c8 = (idx & 7) * 8;
            *(i32x4*)&As[r * GS_ + c8] = *(const i32x4*)(A  + (size_t)(m0 + r) * D_ + k0 + c8);
            *(i32x4*)&Ws[r * GS_ + c8] = *(const i32x4*)(Wt + (size_t)(n0 + r) * D_ + k0 + c8);
        }
        __syncthreads();
#pragma unroll
        for (int kk = 0; kk < 2; ++kk) {
            bf16x8 af[2], bf[4];
#pragma unroll
            for (int m = 0; m < 2; ++m)
                af[m] = *(const bf16x8*)&As[(wm*32 + m*16 + l15) * GS_ + kk*32 + l4*8];
#pragma unroll
            for (int n = 0; n < 4; ++n)
                bf[n] = *(const bf16x8*)&Ws[(wn*64 + n*16 + l15) * GS_ + kk*32 + l4*8];
#pragma unroll
            for (int m = 0; m < 2; ++m)
#pragma unroll
                for (int n = 0; n < 4; ++n)
                    acc[m][n] = __builtin_amdgcn_mfma_f32_16x16x32_bf16(af[m], bf[n], acc[m][n], 0, 0, 0);
        }
        __syncthreads();
    }

    unsigned short* Ct = sh;
#pragma unroll
    for (int n = 0; n < 4; ++n) {
        int gnl = wn*64 + n*16 + l15;
        int gn = n0 + gnl;
        float bn = bias[gn];
#pragma unroll
        for (int m = 0; m < 2; ++m) {
#pragma unroll
            for (int i = 0; i < 4; ++i) {
                int gml = wm*32 + m*16 + l4*4 + i;
                int gm = m0 + gml;
                float v = acc[m][n][i] + bn;
                if (RES) v += bflo((unsigned)res[(size_t)gm * D_ + gn]);
                Ct[gml * VS_ + gnl] = f2bf(v);
            }
        }
    }
    __syncthreads();
#pragma unroll
    for (int rep = 0; rep < 4; ++rep) {
        int idx = rep * 512 + t;
        int row = idx >> 4, c8 = (idx & 15) * 8;
        int gm = m0 + row;
        i32x4 w = *(const i32x4*)&Ct[row * VS_ + c8];
        if (OM == 0) {
            *(i32x4*)&Cout[(size_t)gm * D_ + n0 + c8] = w;
        } else {
            int b = gm / 200, tt = gm - b * 200;
            *(i32x4*)&Cout[((size_t)b * TP_ + tt) * D_ + n0 + c8] = w;
        }
    }
}

// ---------------- fused K+V GEMM: 512 threads / 8 waves ----------------
__global__ __launch_bounds__(512) void gemm_kv(
    const unsigned short* __restrict__ A,
    const unsigned short* __restrict__ WtK, const unsigned short* __restrict__ WtV,
    const float* __restrict__ biasK, const float* __restrict__ biasV,
    unsigned short* __restrict__ kbf, unsigned short* __restrict__ vtbf) {
    __shared__ unsigned short sh[3 * 128 * GS_];
    unsigned short* As  = sh;
    unsigned short* WsK = sh + 128 * GS_;
    unsigned short* WsV = sh + 2 * 128 * GS_;
    int t = threadIdx.x, lane = t & 63, wv = t >> 6;
    int wm = wv >> 1, wn = wv & 1;
    int l15 = lane & 15, l4 = lane >> 4;
    int m0 = blockIdx.y * 128, n0 = blockIdx.x * 128;

    f32x4 accK[2][4], accV[2][4];
#pragma unroll
    for (int m = 0; m < 2; ++m)
#pragma unroll
        for (int n = 0; n < 4; ++n) {
            accK[m][n] = f32x4{0.f, 0.f, 0.f, 0.f};
            accV[m][n] = f32x4{0.f, 0.f, 0.f, 0.f};
        }

    for (int k0 = 0; k0 < D_; k0 += 64) {
#pragma unroll
        for (int rep = 0; rep < 2; ++rep) {
            int idx = rep * 512 + t;
            int r = idx >> 3, c8 = (idx & 7) * 8;
            *(i32x4*)&As[r * GS_ + c8]  = *(const i32x4*)(A   + (size_t)(m0 + r) * D_ + k0 + c8);
            *(i32x4*)&WsK[r * GS_ + c8] = *(const i32x4*)(WtK + (size_t)(n0 + r) * D_ + k0 + c8);
            *(i32x4*)&WsV[r * GS_ + c8] = *(const i32x4*)(WtV + (size_t)(n0 + r) * D_ + k0 + c8);
        }
        __syncthreads();
#pragma unroll
        for (int kk = 0; kk < 2; ++kk) {
            bf16x8 af[2];
#pragma unroll
            for (int m = 0; m < 2; ++m)
                af[m] = *(const bf16x8*)&As[(wm*32 + m*16 + l15) * GS_ + kk*32 + l4*8];
#pragma unroll
            for (int n = 0; n < 4; ++n) {
                bf16x8 bk8 = *(const bf16x8*)&WsK[(wn*64 + n*16 + l15) * GS_ + kk*32 + l4*8];
                bf16x8 bv8 = *(const bf16x8*)&WsV[(wn*64 + n*16 + l15) * GS_ + kk*32 + l4*8];
#pragma unroll
                for (int m = 0; m < 2; ++m) {
                    accK[m][n] = __builtin_amdgcn_mfma_f32_16x16x32_bf16(af[m], bk8, accK[m][n], 0, 0, 0);
                    accV[m][n] = __builtin_amdgcn_mfma_f32_16x16x32_bf16(af[m], bv8, accV[m][n], 0, 0, 0);
                }
            }
        }
        __syncthreads();
    }

    unsigned short* Ct = sh;
#pragma unroll
    for (int n = 0; n < 4; ++n) {
        int gnl = wn*64 + n*16 + l15;
        float bnK = biasK[n0 + gnl];
#pragma unroll
        for (int m = 0; m < 2; ++m)
#pragma unroll
            for (int i = 0; i < 4; ++i) {
                int gml = wm*32 + m*16 + l4*4 + i;
                Ct[gml * VS_ + gnl] = f2bf(accK[m][n][i] + bnK);
            }
    }
    __syncthreads();
#pragma unroll
    for (int rep = 0; rep < 4; ++rep) {
        int idx = rep * 512 + t;
        int row = idx >> 4, c8 = (idx & 15) * 8;
        int gm = m0 + row, b = gm / 200, tt = gm - b * 200;
        *(i32x4*)&kbf[((size_t)b * TP_ + tt) * D_ + n0 + c8] =
            *(const i32x4*)&Ct[row * VS_ + c8];
    }
    __syncthreads();

    unsigned short* Vt = sh;
#pragma unroll
    for (int n = 0; n < 4; ++n) {
        int gnl = wn*64 + n*16 + l15;
        float bnV = biasV[n0 + gnl];
#pragma unroll
        for (int m = 0; m < 2; ++m)
#pragma unroll
            for (int i = 0; i < 4; ++i) {
                int gml = wm*32 + m*16 + l4*4 + i;
                Vt[gnl * VS_ + gml] = f2bf(accV[m][n][i] + bnV);
            }
    }
    __syncthreads();
#pragma unroll
    for (int rep = 0; rep < 4; ++rep) {
        int idx = rep * 512 + t;
        int row = idx >> 4, c8 = (idx & 15) * 8;
        int gn = n0 + row, hh = gn >> 6, dk = gn & 63;
        int gm = m0 + c8, b = gm / 200, tt = gm - b * 200;
        *(i32x4*)&vtbf[(((size_t)b * H_ + hh) * 64 + dk) * VTP_ + tt] =
            *(const i32x4*)&Vt[row * VS_ + c8];
    }
}

// ---------------- fused FFN: LN2 + relu(y@W1+b1)@W2 + b2 + y (32-row blocks) ---
__global__ __launch_bounds__(256) void ffn_fused(
    const unsigned short* __restrict__ S,
    const float* __restrict__ ln_s, const float* __restrict__ ln_b,
    const unsigned short* __restrict__ Wt1, const float* __restrict__ b1,
    const unsigned short* __restrict__ Wt2, const float* __restrict__ b2,
    unsigned short* __restrict__ OUT) {
    __shared__ unsigned short Alds[32 * FS_];
    __shared__ unsigned short Tlds[32 * FS_];
    __shared__ unsigned short Ws[256 * GS_];
    int t = threadIdx.x, lane = t & 63, wv = t >> 6;
    int l15 = lane & 15, l4 = lane >> 4;
    int m0 = blockIdx.x * 32;

    {
        int r = t >> 3, c = (t & 7) * 32;
        const unsigned short* src = S + (size_t)(m0 + r) * D_ + c;
        i32x4 buf[4];
#pragma unroll
        for (int j = 0; j < 4; ++j) buf[j] = ((const i32x4*)src)[j];
        float sum = 0.f;
#pragma unroll
        for (int j = 0; j < 4; ++j)
#pragma unroll
            for (int q = 0; q < 4; ++q)
                sum += bflo((unsigned)buf[j][q]) + bfhi((unsigned)buf[j][q]);
        sum += __shfl_xor(sum, 1);
        sum += __shfl_xor(sum, 2);
        sum += __shfl_xor(sum, 4);
        float mean = sum * (1.f / D_);
        float var = 0.f;
#pragma unroll
        for (int j = 0; j < 4; ++j)
#pragma unroll
            for (int q = 0; q < 4; ++q) {
                float a0 = bflo((unsigned)buf[j][q]) - mean;
                float a1 = bfhi((unsigned)buf[j][q]) - mean;
                var += a0*a0 + a1*a1;
            }
        var += __shfl_xor(var, 1);
        var += __shfl_xor(var, 2);
        var += __shfl_xor(var, 4);
        float inv = rsqrtf(var * (1.f / D_) + 1e-8f);
#pragma unroll
        for (int j = 0; j < 4; ++j) {
            int cc = c + j * 8;
            float4 sa = *(const float4*)&ln_s[cc];
            float4 sb = *(const float4*)&ln_s[cc + 4];
            float4 ba = *(const float4*)&ln_b[cc];
            float4 bb = *(const float4*)&ln_b[cc + 4];
            float y0 = (bflo((unsigned)buf[j][0]) - mean) * inv * sa.x + ba.x;
            float y1 = (bfhi((unsigned)buf[j][0]) - mean) * inv * sa.y + ba.y;
            float y2 = (bflo((unsigned)buf[j][1]) - mean) * inv * sa.z + ba.z;
            float y3 = (bfhi((unsigned)buf[j][1]) - mean) * inv * sa.w + ba.w;
            float y4 = (bflo((unsigned)buf[j][2]) - mean) * inv * sb.x + bb.x;
            float y5 = (bfhi((unsigned)buf[j][2]) - mean) * inv * sb.y + bb.y;
            float y6 = (bflo((unsigned)buf[j][3]) - mean) * inv * sb.z + bb.z;
            float y7 = (bfhi((unsigned)buf[j][3]) - mean) * inv * sb.w + bb.w;
            i32x4 w;
            w[0] = (int)pk2(y0, y1);
            w[1] = (int)pk2(y2, y3);
            w[2] = (int)pk2(y4, y5);
            w[3] = (int)pk2(y6, y7);
            *(i32x4*)&Alds[r * FS_ + cc] = w;
        }
    }
    __syncthreads();

    f32x4 acc[2][4];
#pragma unroll
    for (int m = 0; m < 2; ++m)
#pragma unroll
        for (int n = 0; n < 4; ++n)
            acc[m][n] = f32x4{0.f, 0.f, 0.f, 0.f};
    for (int k0 = 0; k0 < D_; k0 += 64) {
#pragma unroll
        for (int rep = 0; rep < 8; ++rep) {
            int idx = rep * 256 + t;
            int rr = idx >> 3, c8 = (idx & 7) * 8;
            *(i32x4*)&Ws[rr * GS_ + c8] = *(const i32x4*)(Wt1 + (size_t)rr * D_ + k0 + c8);
        }
        __syncthreads();
#pragma unroll
        for (int kk = 0; kk < 2; ++kk) {
            bf16x8 af[2], bf[4];
#pragma unroll
            for (int m = 0; m < 2; ++m)
                af[m] = *(const bf16x8*)&Alds[(m*16 + l15) * FS_ + k0 + kk*32 + l4*8];
#pragma unroll
            for (int n = 0; n < 4; ++n)
                bf[n] = *(const bf16x8*)&Ws[(wv*64 + n*16 + l15) * GS_ + kk*32 + l4*8];
#pragma unroll
            for (int m = 0; m < 2; ++m)
#pragma unroll
                for (int n = 0; n < 4; ++n)
                    acc[m][n] = __builtin_amdgcn_mfma_f32_16x16x32_bf16(af[m], bf[n], acc[m][n], 0, 0, 0);
        }
        __syncthreads();
    }
#pragma unroll
    for (int n = 0; n < 4; ++n) {
        int gn = wv*64 + n*16 + l15;
        float bn = b1[gn];
#pragma unroll
        for (int m = 0; m < 2; ++m)
#pragma unroll
            for (int i = 0; i < 4; ++i)
                Tlds[(m*16 + l4*4 + i) * FS_ + gn] = f2bf(fmaxf(acc[m][n][i] + bn, 0.f));
    }
    __syncthreads();

#pragma unroll
    for (int m = 0; m < 2; ++m)
#pragma unroll
        for (int n = 0; n < 4; ++n)
            acc[m][n] = f32x4{0.f, 0.f, 0.f, 0.f};
    for (int k0 = 0; k0 < D_; k0 += 64) {
#pragma unroll
        for (int rep = 0; rep < 8; ++rep) {
            int idx = rep * 256 + t;
            int rr = idx >> 3, c8 = (idx & 7) * 8;
            *(i32x4*)&Ws[rr * GS_ + c8] = *(const i32x4*)(Wt2 + (size_t)rr * D_ + k0 + c8);
        }
        __syncthreads();
#pragma unroll
        for (int kk = 0; kk < 2; ++kk) {
            bf16x8 af[2], bf[4];
#pragma unroll
            for (int m = 0; m < 2; ++m)
                af[m] = *(const bf16x8*)&Tlds[(m*16 + l15) * FS_ + k0 + kk*32 + l4*8];
#pragma unroll
            for (int n = 0; n < 4; ++n)
                bf[n] = *(const bf16x8*)&Ws[(wv*64 + n*16 + l15) * GS_ + kk*32 + l4*8];
#pragma unroll
            for (int m = 0; m < 2; ++m)
#pragma unroll
                for (int n = 0; n < 4; ++n)
                    acc[m][n] = __builtin_amdgcn_mfma_f32_16x16x32_bf16(af[m], bf[n], acc[m][n], 0, 0, 0);
        }
        __syncthreads();
    }
#pragma unroll
    for (int n = 0; n < 4; ++n) {
        int gn = wv*64 + n*16 + l15;
        float bn = b2[gn];
#pragma unroll
        for (int m = 0; m < 2; ++m) {
#pragma unroll
            for (int i = 0; i < 4; ++i) {
                int row = m*16 + l4*4 + i;
                float v = acc[m][n][i] + bn + bflo((unsigned)Alds[row * FS_ + gn]);
                Tlds[row * FS_ + gn] = f2bf(v);
            }
        }
    }
    __syncthreads();
#pragma unroll
    for (int rep = 0; rep < 4; ++rep) {
        int idx = rep * 256 + t;
        int row = idx >> 5, c8 = (idx & 31) * 8;
        *(i32x4*)&OUT[(size_t)(m0 + row) * D_ + c8] = *(const i32x4*)&Tlds[row * FS_ + c8];
    }
}

// ---------------- score epilogue helper ----------------
template<bool DEC>
__device__ __forceinline__ f32x4 score_ep(f32x4 acc, int kt, int qr, int l4,
                                          size_t bT, const float* __restrict__ cm) {
    f32x4 sv;
#pragma unroll
    for (int i = 0; i < 4; ++i) {
        int kk = kt * 16 + l4 * 4 + i;
        float s = acc[i] * 0.125f;
        bool vld = (qr < T_) && (kk < T_);
        float cmv = (DEC && vld) ? cm[(bT + kk) * T_ + qr] : 0.f;
        if (!vld) s = -1e9f;
        else {
            if (kk > qr) s = -1e9f;   // mask BEFORE cm multiply (as reference)
            if (DEC) s *= (1.0f + 0.5f * cmv);
        }
        sv[i] = s;
    }
    return sv;
}

// ---------------- MFMA attention: paired q-tiles (j, 12-j) per wave ----------------
// Grid 7168 = 8*896 (XCD swizzled). K/V tile fragments shared by both streams.
template<bool DEC>
__global__ __launch_bounds__(64) void attn_mfma(
    const unsigned short* __restrict__ qbf,   // [b][208][256]
    const unsigned short* __restrict__ kbf,   // [b][208][256]
    const unsigned short* __restrict__ vtbf,  // [b*4+h][64][224]
    const float* __restrict__ cm,
    unsigned short* __restrict__ obf) {       // [bt][256]
    __shared__ unsigned short Olds[32 * 72];
    int o = ((blockIdx.x & 7) * 896) + (blockIdx.x >> 3);
    int b = o / 28;
    int r = o - b * 28;
    int h = r / 7;
    int j = r - h * 7;
    int qtA = j, qtB = 12 - j;
    bool hasA = (qtA != qtB);                 // j==6 -> single stream
    int lane = threadIdx.x;
    int l15 = lane & 15, l4 = lane >> 4;
    int q0A = qtA * 16, q0B = qtB * 16;
    int qrA = q0A + l15, qrB = q0B + l15;
    size_t bT = (size_t)b * T_;
    const f32x4 zero = {0.f, 0.f, 0.f, 0.f};

    size_t qkb = ((size_t)b * TP_) * D_ + h * 64;
    const unsigned short* qpB = qbf + qkb + (size_t)(q0B + l15) * D_ + l4 * 8;
    bf16x8 bqB0 = *(const bf16x8*)qpB;
    bf16x8 bqB1 = *(const bf16x8*)(qpB + 32);
    bf16x8 bqA0 = bqB0, bqA1 = bqB1;
    if (hasA) {
        const unsigned short* qpA = qbf + qkb + (size_t)(q0A + l15) * D_ + l4 * 8;
        bqA0 = *(const bf16x8*)qpA;
        bqA1 = *(const bf16x8*)(qpA + 32);
    }

    size_t vbase = ((size_t)(b * H_ + h)) * 64 * VTP_;
    int sA = l15 + ((l4 & 1) << 5);
    int sB = sA + 16;
    bool lo4 = (l4 < 2);

    float mA = -3e38f, lA = 0.f, mB = -3e38f, lB = 0.f;
    f32x4 OA[4] = {zero, zero, zero, zero};
    f32x4 OB[4] = {zero, zero, zero, zero};

    int npair = (qtB >> 1) + 1;
    for (int p = 0; p < npair; ++p) {
        int kt0 = 2 * p;
        bool oddB = (kt0 + 1 <= qtB);
        bool evnA = hasA && (kt0 <= qtA);
        bool oddA = hasA && (kt0 + 1 <= qtA);

        // shared K loads
        const unsigned short* kp0 = kbf + qkb + (size_t)(kt0 * 16 + l15) * D_ + l4 * 8;
        bf16x8 ak00 = *(const bf16x8*)kp0;
        bf16x8 ak01 = *(const bf16x8*)(kp0 + 32);
        bf16x8 ak10 = ak00, ak11 = ak01;
        if (oddB) {
            const unsigned short* kp1 = kp0 + (size_t)16 * D_;
            ak10 = *(const bf16x8*)kp1;
            ak11 = *(const bf16x8*)(kp1 + 32);
        }

        // B scores
        f32x4 svB0, svB1, svA0, svA1;
        {
            __builtin_amdgcn_s_setprio(1);
            f32x4 acc = __builtin_amdgcn_mfma_f32_16x16x32_bf16(ak00, bqB0, zero, 0, 0, 0);
            acc = __builtin_amdgcn_mfma_f32_16x16x32_bf16(ak01, bqB1, acc, 0, 0, 0);
            __builtin_amdgcn_s_setprio(0);
            svB0 = score_ep<DEC>(acc, kt0, qrB, l4, bT, cm);
        }
        if (oddB) {
            __builtin_amdgcn_s_setprio(1);
            f32x4 acc = __builtin_amdgcn_mfma_f32_16x16x32_bf16(ak10, bqB0, zero, 0, 0, 0);
            acc = __builtin_amdgcn_mfma_f32_16x16x32_bf16(ak11, bqB1, acc, 0, 0, 0);
            __builtin_amdgcn_s_setprio(0);
            svB1 = score_ep<DEC>(acc, kt0 + 1, qrB, l4, bT, cm);
        }
        // A scores (shared K fragments)
        if (evnA) {
            __builtin_amdgcn_s_setprio(1);
            f32x4 acc = __builtin_amdgcn_mfma_f32_16x16x32_bf16(ak00, bqA0, zero, 0, 0, 0);
            acc = __builtin_amdgcn_mfma_f32_16x16x32_bf16(ak01, bqA1, acc, 0, 0, 0);
            __builtin_amdgcn_s_setprio(0);
            svA0 = score_ep<DEC>(acc, kt0, qrA, l4, bT, cm);
        }
        if (oddA) {
            __builtin_amdgcn_s_setprio(1);
            f32x4 acc = __builtin_amdgcn_mfma_f32_16x16x32_bf16(ak10, bqA0, zero, 0, 0, 0);
            acc = __builtin_amdgcn_mfma_f32_16x16x32_bf16(ak11, bqA1, acc, 0, 0, 0);
            __builtin_amdgcn_s_setprio(0);
            svA1 = score_ep<DEC>(acc, kt0 + 1, qrA, l4, bT, cm);
        }

        // shared V tile loads
        bf16x8 vf[4];
#pragma unroll
        for (int dt = 0; dt < 4; ++dt)
            vf[dt] = *(const bf16x8*)&vtbf[vbase + (size_t)(dt * 16 + l15) * VTP_ + p * 32 + l4 * 8];

        // ---- B online update + PV ----
        {
            float tm = fmaxf(fmaxf(svB0[0], svB0[1]), fmaxf(svB0[2], svB0[3]));
            if (oddB) tm = fmaxf(tm, fmaxf(fmaxf(svB1[0], svB1[1]), fmaxf(svB1[2], svB1[3])));
            tm = fmaxf(tm, __shfl_xor(tm, 16));
            tm = fmaxf(tm, __shfl_xor(tm, 32));
            float mn = fmaxf(mB, tm);
            float sc = __expf(mB - mn);
            mB = mn;
            lB *= sc;
#pragma unroll
            for (int i = 0; i < 4; ++i) {
                float osc = __shfl(sc, l4 * 4 + i);
#pragma unroll
                for (int dt = 0; dt < 4; ++dt) OB[dt][i] *= osc;
            }
            float p0[4], p1[4];
#pragma unroll
            for (int i = 0; i < 4; ++i) { p0[i] = __expf(svB0[i] - mB); lB += p0[i]; }
            if (oddB) {
#pragma unroll
                for (int i = 0; i < 4; ++i) { p1[i] = __expf(svB1[i] - mB); lB += p1[i]; }
            } else {
#pragma unroll
                for (int i = 0; i < 4; ++i) p1[i] = 0.f;
            }
            unsigned pk0a = pk2(p0[0], p0[1]), pk0b = pk2(p0[2], p0[3]);
            unsigned pk1a = pk2(p1[0], p1[1]), pk1b = pk2(p1[2], p1[3]);
            unsigned e0 = (unsigned)__shfl((int)pk0a, sA);
            unsigned e1 = (unsigned)__shfl((int)pk0b, sA);
            unsigned e2 = (unsigned)__shfl((int)pk0a, sB);
            unsigned e3 = (unsigned)__shfl((int)pk0b, sB);
            unsigned o0 = (unsigned)__shfl((int)pk1a, sA);
            unsigned o1 = (unsigned)__shfl((int)pk1b, sA);
            unsigned o2 = (unsigned)__shfl((int)pk1a, sB);
            unsigned o3 = (unsigned)__shfl((int)pk1b, sB);
            frag8 pa;
            pa.u[0] = lo4 ? e0 : o0;
            pa.u[1] = lo4 ? e1 : o1;
            pa.u[2] = lo4 ? e2 : o2;
            pa.u[3] = lo4 ? e3 : o3;
            __builtin_amdgcn_s_setprio(1);
#pragma unroll
            for (int dt = 0; dt < 4; ++dt)
                OB[dt] = __builtin_amdgcn_mfma_f32_16x16x32_bf16(pa.v, vf[dt], OB[dt], 0, 0, 0);
            __builtin_amdgcn_s_setprio(0);
        }

        // ---- A online update + PV (guarded; reuses vf) ----
        if (evnA) {
            float tm = fmaxf(fmaxf(svA0[0], svA0[1]), fmaxf(svA0[2], svA0[3]));
            if (oddA) tm = fmaxf(tm, fmaxf(fmaxf(svA1[0], svA1[1]), fmaxf(svA1[2], svA1[3])));
            tm = fmaxf(tm, __shfl_xor(tm, 16));
            tm = fmaxf(tm, __shfl_xor(tm, 32));
            float mn = fmaxf(mA, tm);
            float sc = __expf(mA - mn);
            mA = mn;
            lA *= sc;
#pragma unroll
            for (int i = 0; i < 4; ++i) {
                float osc = __shfl(sc, l4 * 4 + i);
#pragma unroll
                for (int dt = 0; dt < 4; ++dt) OA[dt][i] *= osc;
            }
            float p0[4], p1[4];
#pragma unroll
            for (int i = 0; i < 4; ++i) { p0[i] = __expf(svA0[i] - mA); lA += p0[i]; }
            if (oddA) {
#pragma unroll
                for (int i = 0; i < 4; ++i) { p1[i] = __expf(svA1[i] - mA); lA += p1[i]; }
            } else {
#pragma unroll
                for (int i = 0; i < 4; ++i) p1[i] = 0.f;
            }
            unsigned pk0a = pk2(p0[0], p0[1]), pk0b = pk2(p0[2], p0[3]);
            unsigned pk1a = pk2(p1[0], p1[1]), pk1b = pk2(p1[2], p1[3]);
            unsigned e0 = (unsigned)__shfl((int)pk0a, sA);
            unsigned e1 = (unsigned)__shfl((int)pk0b, sA);
            unsigned e2 = (unsigned)__shfl((int)pk0a, sB);
            unsigned e3 = (unsigned)__shfl((int)pk0b, sB);
            unsigned o0 = (unsigned)__shfl((int)pk1a, sA);
            unsigned o1 = (unsigned)__shfl((int)pk1b, sA);
            unsigned o2 = (unsigned)__shfl((int)pk1a, sB);
            unsigned o3 = (unsigned)__shfl((int)pk1b, sB);
            frag8 pa;
            pa.u[0] = lo4 ? e0 : o0;
            pa.u[1] = lo4 ? e1 : o1;
            pa.u[2] = lo4 ? e2 : o2;
            pa.u[3] = lo4 ? e3 : o3;
            __builtin_amdgcn_s_setprio(1);
#pragma unroll
            for (int dt = 0; dt < 4; ++dt)
                OA[dt] = __builtin_amdgcn_mfma_f32_16x16x32_bf16(pa.v, vf[dt], OA[dt], 0, 0, 0);
            __builtin_amdgcn_s_setprio(0);
        }
    }

    // ---- finalize both streams into Olds, then coalesced store ----
    {
        float L = lB;
        L += __shfl_xor(L, 16);
        L += __shfl_xor(L, 32);
        float inv = 1.f / L;
#pragma unroll
        for (int i = 0; i < 4; ++i) {
            float oin = __shfl(inv, l4 * 4 + i);
#pragma unroll
            for (int dt = 0; dt < 4; ++dt)
                Olds[(l4 * 4 + i) * 72 + dt * 16 + l15] = f2bf(OB[dt][i] * oin);
        }
    }
    if (hasA) {
        float L = lA;
        L += __shfl_xor(L, 16);
        L += __shfl_xor(L, 32);
        float inv = 1.f / L;
#pragma unroll
        for (int i = 0; i < 4; ++i) {
            float oin = __shfl(inv, l4 * 4 + i);
#pragma unroll
            for (int dt = 0; dt < 4; ++dt)
                Olds[(16 + l4 * 4 + i) * 72 + dt * 16 + l15] = f2bf(OA[dt][i] * oin);
        }
    }
    __syncthreads();
#pragma unroll
    for (int rep = 0; rep < 2; ++rep) {
        int idx = rep * 64 + lane;
        int row = idx >> 3, c8 = (idx & 7) * 8;
        int qrow = q0B + row;
        if (qrow < T_)
            *(i32x4*)&obf[(bT + qrow) * D_ + h * 64 + c8] =
                *(const i32x4*)&Olds[row * 72 + c8];
    }
    if (hasA) {
#pragma unroll
        for (int rep = 0; rep < 2; ++rep) {
            int idx = rep * 64 + lane;
            int row = idx >> 3, c8 = (idx & 7) * 8;
            int qrow = q0A + row;
            if (qrow < T_)
                *(i32x4*)&obf[(bT + qrow) * D_ + h * 64 + c8] =
                    *(const i32x4*)&Olds[(16 + row) * 72 + c8];
        }
    }
}

// ---------------- cov (bf16 Z in; row mean computed inline per wave) ----------------
__global__ __launch_bounds__(512) void cov_mfma(const unsigned short* __restrict__ Z,
                                                float* __restrict__ cm) {
    __shared__ unsigned short Zb[208 * ZS_];
    int b = blockIdx.x;
    int tid = threadIdx.x, lane = tid & 63, wv = tid >> 6;
    int l15 = lane & 15, l4 = lane >> 4;

    for (int i = tid; i < T_ * 64; i += 512) {
        int t = i >> 6, c4 = (i & 63) << 2;
        i32x2 z = *(const i32x2*)(Z + ((size_t)b * T_ + t) * D_ + c4);
        float z0 = bflo((unsigned)z[0]), z1 = bfhi((unsigned)z[0]);
        float z2 = bflo((unsigned)z[1]), z3 = bfhi((unsigned)z[1]);
        float mean = wave_sum(z0 + z1 + z2 + z3) * (1.f / D_);
        unsigned* p = (unsigned*)&Zb[t * ZS_ + c4];
        p[0] = pk2(z0 - mean, z1 - mean);
        p[1] = pk2(z2 - mean, z3 - mean);
    }
    for (int i = tid; i < 8 * ZS_; i += 512) Zb[T_ * ZS_ + i] = 0;
    __syncthreads();

    for (int job = wv; job < 91; job += 8) {
        int ti = 0;
        while ((ti + 1) * (ti + 2) / 2 <= job) ++ti;
        int tj = job - ti * (ti + 1) / 2;
        f32x4 acc = {0.f, 0.f, 0.f, 0.f};
#pragma unroll
        for (int s = 0; s < 8; ++s) {
            bf16x8 a  = *(const bf16x8*)&Zb[(ti * 16 + l15) * ZS_ + s * 32 + l4 * 8];
            bf16x8 bb = *(const bf16x8*)&Zb[(tj * 16 + l15) * ZS_ + s * 32 + l4 * 8];
            acc = __builtin_amdgcn_mfma_f32_16x16x32_bf16(a, bb, acc, 0, 0, 0);
        }
#pragma unroll
        for (int i = 0; i < 4; ++i) {
            int t = ti * 16 + l4 * 4 + i, s2 = tj * 16 + l15;
            float vv = fminf(acc[i] * (1.f / 255.f), 3.0f);
            if (t < T_ && s2 < T_) {
                cm[((size_t)b * T_ + t) * T_ + s2] = vv;
                cm[((size_t)b * T_ + s2) * T_ + t] = vv;
            }
        }
    }
}

extern "C" void kernel_launch(void* const* d_in, const int* in_sizes, int n_in,
                              void* d_out, int out_size, void* d_ws, size_t ws_size,
                              hipStream_t stream) {
    const int*   log_seqs = (const int*)  d_in[0];
    const float* item_tab = (const float*)d_in[1];
    const float* pos_tab  = (const float*)d_in[2];
    const float* ln1_s = (const float*)d_in[3];
    const float* ln1_b = (const float*)d_in[4];
    const float* Wq = (const float*)d_in[5];
    const float* bq = (const float*)d_in[6];
    const float* Wk = (const float*)d_in[7];
    const float* bk = (const float*)d_in[8];
    const float* Wv = (const float*)d_in[9];
    const float* bv = (const float*)d_in[10];
    const float* Wo = (const float*)d_in[11];
    const float* bo = (const float*)d_in[12];
    const float* ln2_s = (const float*)d_in[13];
    const float* ln2_b = (const float*)d_in[14];
    const float* W1 = (const float*)d_in[15];
    const float* b1 = (const float*)d_in[16];
    const float* W2 = (const float*)d_in[17];
    const float* b2 = (const float*)d_in[18];
    const float* last_s = (const float*)d_in[19];
    const float* last_b = (const float*)d_in[20];

    const size_t NTD = (size_t)BT_ * D_;
    float* cmask = (float*)d_ws;                               // B*T*T fp32
    unsigned short* act = (unsigned short*)(cmask + (size_t)B_ * T_ * T_);
    unsigned short* s0   = act;              // seqs / layer-3 out
    unsigned short* s1   = s0 + NTD;         // causal_z / layer-2 out
    unsigned short* Qn   = s1 + NTD;         // ln1 out, then s (in-place)
    unsigned short* vb   = Qn + NTD;         // obf
    unsigned short* qbf  = vb + NTD;                         // [B][208][256]
    unsigned short* kbf  = qbf + (size_t)B_ * TP_ * D_;      // [B][208][256]
    unsigned short* vtbf = kbf + (size_t)B_ * TP_ * D_;      // [B*H][64][224]
    unsigned short* wtb  = vtbf + (size_t)B_ * H_ * 64 * VTP_;

    unsigned short* wtq = wtb;
    unsigned short* wtk = wtb + 4 * (size_t)DD_;
    unsigned short* wtv = wtb + 8 * (size_t)DD_;
    unsigned short* wto = wtb + 12 * (size_t)DD_;
    unsigned short* wt1 = wtb + 16 * (size_t)DD_;
    unsigned short* wt2 = wtb + 20 * (size_t)DD_;

    dim3 tg(4, 4, 4);
    wtrans_kernel<<<tg, 256, 0, stream>>>(Wq, wtq);
    wtrans_kernel<<<tg, 256, 0, stream>>>(Wk, wtk);
    wtrans_kernel<<<tg, 256, 0, stream>>>(Wv, wtv);
    wtrans_kernel<<<tg, 256, 0, stream>>>(Wo, wto);
    wtrans_kernel<<<tg, 256, 0, stream>>>(W1, wt1);
    wtrans_kernel<<<tg, 256, 0, stream>>>(W2, wt2);
    vtpad_kernel<<<B_ * H_ * 64, 32, 0, stream>>>(vtbf);

    dim3 gg(2, 400);   // N/128, M/128

    auto encoder = [&](const unsigned short* X, unsigned short* OUT, int i, const float* cmp) {
        ln_kernel<false><<<BT_/4, 256, 0, stream>>>(X, ln1_s + i*D_, ln1_b + i*D_, Qn);
        gemm_mfma<1,false><<<gg, 512, 0, stream>>>(Qn, wtq + (size_t)i*DD_, bq + i*D_, nullptr, qbf);
        gemm_kv<<<gg, 512, 0, stream>>>(X, wtk + (size_t)i*DD_, wtv + (size_t)i*DD_,
                                        bk + i*D_, bv + i*D_, kbf, vtbf);
        if (cmp) attn_mfma<true ><<<7168, 64, 0, stream>>>(qbf, kbf, vtbf, cmp, vb);
        else     attn_mfma<false><<<7168, 64, 0, stream>>>(qbf, kbf, vtbf, nullptr, vb);
        // s = Qn + vb @ Wo + bo  (in-place into Qn; element-exclusive)
        gemm_mfma<0,true><<<gg, 512, 0, stream>>>(vb, wto + (size_t)i*DD_, bo + i*D_, Qn, Qn);
        // OUT = relu(LN2(s)@W1+b1)@W2 + b2 + LN2(s)
        ffn_fused<<<BT_/32, 256, 0, stream>>>(Qn, ln2_s + i*D_, ln2_b + i*D_,
                                              wt1 + (size_t)i*DD_, b1 + i*D_,
                                              wt2 + (size_t)i*DD_, b2 + i*D_, OUT);
    };

    embed_kernel<<<BT_, 64, 0, stream>>>(log_seqs, item_tab, pos_tab, s0);

    // causal loop applies each layer to ORIGINAL seqs -> only layer 1 survives
    encoder(s0, s1, 1, nullptr);

    cov_mfma<<<B_, 512, 0, stream>>>(s1, cmask);

    encoder(s0, s1, 2, cmask);
    encoder(s1, s0, 3, cmask);

    ln_kernel<true><<<BT_/4, 256, 0, stream>>>(s0, last_s, last_b, (float*)d_out);
}